// Round 1
// baseline (10255.514 us; speedup 1.0000x reference)
//
#include <hip/hip_runtime.h>
#include <cstdint>
#include <cstddef>

// ---------------- constants (match reference) ----------------
static constexpr int DIMc = 512;
static constexpr int DHc  = 64;
static constexpr int CHc  = 2;
static constexpr int SHc  = 8;
static constexpr int Bc   = 8;
static constexpr int Tc   = 1024;
static constexpr int Nc   = 2048;
static constexpr int CIc  = CHc * DHc;    // 128
static constexpr int SIc  = SHc * DHc;    // 512
static constexpr int FFc  = 4 * DIMc;     // 2048
static constexpr int RQ   = Bc * Tc;      // 8192 query rows
static constexpr int RL   = Bc * Nc;      // 16384 latent rows

typedef short bf16x8 __attribute__((ext_vector_type(8)));
typedef float f32x4  __attribute__((ext_vector_type(4)));

__device__ __forceinline__ ushort f2bf(float f) {
  uint32_t u = __builtin_bit_cast(uint32_t, f);
  u += 0x7fffu + ((u >> 16) & 1u);
  return (ushort)(u >> 16);
}
__device__ __forceinline__ float bf2f(ushort h) {
  uint32_t u = ((uint32_t)h) << 16;
  return __builtin_bit_cast(float, u);
}

// ---------------- LayerNorm: one wave per 512-col row, fp32 in -> bf16 out ----
__global__ __launch_bounds__(256) void ln_rows(const float* __restrict__ X,
    const float* __restrict__ w, const float* __restrict__ b,
    ushort* __restrict__ out, int rows) {
  int gw = (int)((blockIdx.x * 256 + threadIdx.x) >> 6);
  int lane = threadIdx.x & 63;
  if (gw >= rows) return;
  const float* xr = X + (size_t)gw * DIMc;
  float4 v0 = *(const float4*)(xr + lane * 8);
  float4 v1 = *(const float4*)(xr + lane * 8 + 4);
  float xv[8] = {v0.x, v0.y, v0.z, v0.w, v1.x, v1.y, v1.z, v1.w};
  float s = 0.f, ss = 0.f;
#pragma unroll
  for (int i = 0; i < 8; i++) { s += xv[i]; ss += xv[i] * xv[i]; }
#pragma unroll
  for (int off = 32; off; off >>= 1) { s += __shfl_xor(s, off); ss += __shfl_xor(ss, off); }
  float mean = s * (1.f / DIMc);
  float var = ss * (1.f / DIMc) - mean * mean;
  float r = rsqrtf(var + 1e-5f);
  int c = lane * 8;
  ushort o[8] __attribute__((aligned(16)));
#pragma unroll
  for (int i = 0; i < 8; i++) o[i] = f2bf((xv[i] - mean) * r * w[c + i] + b[c + i]);
  *(uint4*)(out + (size_t)gw * DIMc + c) = *(const uint4*)o;
}

// ---------------- weight transpose + fp32->bf16: W(K,N) -> Wt(N,K) ----------
__global__ __launch_bounds__(256) void wtrans(const float* __restrict__ W,
    ushort* __restrict__ Wt, int K, int N) {
  __shared__ float tile[32][33];
  int n0 = blockIdx.x * 32, k0 = blockIdx.y * 32;
  int tx = threadIdx.x & 31, ty = threadIdx.x >> 5;  // 32 x 8
#pragma unroll
  for (int i = 0; i < 32; i += 8)
    tile[ty + i][tx] = W[(size_t)(k0 + ty + i) * N + n0 + tx];
  __syncthreads();
#pragma unroll
  for (int i = 0; i < 32; i += 8)
    Wt[(size_t)(n0 + ty + i) * K + k0 + tx] = f2bf(tile[tx][ty + i]);
}

// ---------------- bf16 MFMA GEMM, 64x64 tile, BK=32, 4 waves -----------------
// A: M x K bf16 row-major.  Bt: N x K bf16 row-major (i.e. W^T).
// MODE 0: outB[gr*N+gc] = bf16(acc + bias)
// MODE 1: resF[gr*N+gc] += acc + bias   (fp32 residual update, in place)
template<int MODE>
__global__ __launch_bounds__(256) void gemm64(const ushort* __restrict__ A,
    const ushort* __restrict__ Bt, const float* __restrict__ bias,
    float* __restrict__ resF, ushort* __restrict__ outB,
    int M, int N, int K) {
  __shared__ __align__(16) ushort As[64][40];  // pad 40 -> 2-way LDS conflicts only
  __shared__ __align__(16) ushort Bs[64][40];
  int t = threadIdx.x;
  int bm = blockIdx.y, bn = blockIdx.x;
  int row = t >> 2, kc = (t & 3) << 3;
  const ushort* aG = A + (size_t)(bm * 64 + row) * K + kc;
  const ushort* bG = Bt + (size_t)(bn * 64 + row) * K + kc;
  int wv = t >> 6, lane = t & 63;
  int wr = (wv >> 1) * 32, wc = (wv & 1) * 32;
  int fr = lane & 15, fk = (lane >> 4) << 3;
  f32x4 acc[2][2] = {};
  for (int k0 = 0; k0 < K; k0 += 32) {
    *(uint4*)&As[row][kc] = *(const uint4*)(aG + k0);
    *(uint4*)&Bs[row][kc] = *(const uint4*)(bG + k0);
    __syncthreads();
    bf16x8 a0 = *(const bf16x8*)&As[wr + fr][fk];
    bf16x8 a1 = *(const bf16x8*)&As[wr + 16 + fr][fk];
    bf16x8 b0 = *(const bf16x8*)&Bs[wc + fr][fk];
    bf16x8 b1 = *(const bf16x8*)&Bs[wc + 16 + fr][fk];
    acc[0][0] = __builtin_amdgcn_mfma_f32_16x16x32_bf16(a0, b0, acc[0][0], 0, 0, 0);
    acc[0][1] = __builtin_amdgcn_mfma_f32_16x16x32_bf16(a0, b1, acc[0][1], 0, 0, 0);
    acc[1][0] = __builtin_amdgcn_mfma_f32_16x16x32_bf16(a1, b0, acc[1][0], 0, 0, 0);
    acc[1][1] = __builtin_amdgcn_mfma_f32_16x16x32_bf16(a1, b1, acc[1][1], 0, 0, 0);
    __syncthreads();
  }
  int cr0 = wr + ((lane >> 4) << 2);
  int cc0 = wc + fr;
#pragma unroll
  for (int mm = 0; mm < 2; mm++)
#pragma unroll
    for (int nn = 0; nn < 2; nn++)
#pragma unroll
      for (int i = 0; i < 4; i++) {
        int gr = bm * 64 + cr0 + mm * 16 + i;
        int gc = bn * 64 + cc0 + nn * 16;
        float val = acc[mm][nn][i] + (bias ? bias[gc] : 0.f);
        if (MODE == 0) outB[(size_t)gr * N + gc] = f2bf(val);
        else resF[(size_t)gr * N + gc] = resF[(size_t)gr * N + gc] + val;
      }
}

// ---------------- elementwise rotary (in place on bf16 buffer) ---------------
// out[2i]   = x[2i]*cos(f[2i]) - x[2i+1]*sin(f[2i])
// out[2i+1] = x[2i+1]*cos(f[2i+1]) + x[2i]*sin(f[2i+1]);  then * scale
__global__ __launch_bounds__(256) void rope_apply(ushort* __restrict__ buf,
    const float* __restrict__ fr, int rows, int stride, int colOff, int H, float scale) {
  int idx = blockIdx.x * 256 + threadIdx.x;
  int total = rows * H * 32;
  if (idx >= total) return;
  int p = idx & 31;
  int h = (idx >> 5) % H;
  int r = idx / (32 * H);
  float f0 = fr[(size_t)r * DHc + 2 * p];
  float f1 = fr[(size_t)r * DHc + 2 * p + 1];
  ushort* bp = buf + (size_t)r * stride + colOff + h * DHc + 2 * p;
  float x0 = bf2f(bp[0]), x1 = bf2f(bp[1]);
  float o0 = (x0 * __cosf(f0) - x1 * __sinf(f0)) * scale;
  float o1 = (x1 * __cosf(f1) + x0 * __sinf(f1)) * scale;
  bp[0] = f2bf(o0); bp[1] = f2bf(o1);
}

// ---------------- flash attention, one wave per (b,h,query-row) --------------
// lane = head-dim index.  q pre-scaled by DH^-0.5 and pre-rotated.
__global__ __launch_bounds__(256) void attn_row(const ushort* __restrict__ Q,
    const ushort* __restrict__ KV, ushort* __restrict__ O,
    int qStride, int kvStride, int kOff, int vOff, int oStride,
    int T, int NK, int H, int causal, int totalWaves) {
  int gw = (int)((blockIdx.x * 256 + threadIdx.x) >> 6);
  int lane = threadIdx.x & 63;
  if (gw >= totalWaves) return;
  int tq = gw % T;
  int h = (gw / T) % H;
  int b = gw / (T * H);
  const ushort* q = Q + (size_t)(b * T + tq) * qStride + h * DHc;
  const ushort* kbase = KV + (size_t)b * NK * kvStride + kOff + h * DHc + lane;
  const ushort* vbase = KV + (size_t)b * NK * kvStride + vOff + h * DHc + lane;
  float qd = bf2f(q[lane]);
  int nk = causal ? tq + 1 : NK;
  float m = -1e30f, l = 0.f, acc = 0.f;
  for (int j = 0; j < nk; j++) {
    float s = qd * bf2f(kbase[(size_t)j * kvStride]);
#pragma unroll
    for (int off = 32; off; off >>= 1) s += __shfl_xor(s, off);
    float mn = fmaxf(m, s);
    float corr = __expf(m - mn);
    float p = __expf(s - mn);
    l = l * corr + p;
    acc = acc * corr + p * bf2f(vbase[(size_t)j * kvStride]);
    m = mn;
  }
  O[(size_t)(b * T + tq) * oStride + h * DHc + lane] = f2bf(acc / l);
}

// ---------------- a * gelu(g), exact erf --------------------------------------
__global__ __launch_bounds__(256) void mulgelu(const ushort* __restrict__ F1,
    ushort* __restrict__ AG, int rows) {
  int idx = blockIdx.x * 256 + threadIdx.x;
  if (idx >= rows * FFc) return;
  int r = idx >> 11, c = idx & (FFc - 1);
  float a = bf2f(F1[(size_t)r * (2 * FFc) + c]);
  float g = bf2f(F1[(size_t)r * (2 * FFc) + FFc + c]);
  float gg = 0.5f * g * (1.f + erff(g * 0.70710678118f));
  AG[idx] = f2bf(a * gg);
}

// ---------------- orchestration ----------------------------------------------
extern "C" void kernel_launch(void* const* d_in, const int* in_sizes, int n_in,
                              void* d_out, int out_size, void* d_ws, size_t ws_size,
                              hipStream_t stream) {
  const float* bin_queries = (const float*)d_in[0];
  const float* bin_time    = (const float*)d_in[1];
  const float* latents     = (const float*)d_in[2];
  const float* lat_time    = (const float*)d_in[3];
  const float* ca_lnq_w = (const float*)d_in[4];
  const float* ca_lnq_b = (const float*)d_in[5];
  const float* ca_lnc_w = (const float*)d_in[6];
  const float* ca_lnc_b = (const float*)d_in[7];
  const float* ca_wq  = (const float*)d_in[8];
  const float* ca_wkv = (const float*)d_in[9];
  const float* ca_wo  = (const float*)d_in[10];
  const float* ca_bo  = (const float*)d_in[11];
  const float* sa_ln_w = (const float*)d_in[12];
  const float* sa_ln_b = (const float*)d_in[13];
  const float* sa_wqkv = (const float*)d_in[14];
  const float* sa_wo   = (const float*)d_in[15];
  const float* sa_bo   = (const float*)d_in[16];
  const float* ffn_ln_w = (const float*)d_in[17];
  const float* ffn_ln_b = (const float*)d_in[18];
  const float* ffn_w1 = (const float*)d_in[19];
  const float* ffn_b1 = (const float*)d_in[20];
  const float* ffn_w2 = (const float*)d_in[21];
  const float* ffn_b2 = (const float*)d_in[22];

  // ---- workspace layout (bytes) ----
  constexpr size_t X_BYTES = (size_t)RQ * DIMc * 4;            // 16,777,216
  char* ws = (char*)d_ws;
  float* x = (float*)ws;
  char* A0 = ws + X_BYTES;
  // cross-attn phase
  ushort* cn     = (ushort*)(A0);                              // 16,777,216
  ushort* ca_xn  = (ushort*)(A0 + 16777216);                   //  8,388,608
  ushort* qbuf   = (ushort*)(A0 + 25165824);                   //  2,097,152
  ushort* kv     = (ushort*)(A0 + 27262976);                   //  8,388,608
  ushort* ca_att = (ushort*)(A0 + 35651584);                   //  2,097,152
  // self-attn phase (reuses arena)
  ushort* sa_xn  = (ushort*)(A0);                              //  8,388,608
  ushort* qkv    = (ushort*)(A0 + 8388608);                    // 25,165,824
  ushort* sa_att = (ushort*)(A0 + 33554432);                   //  8,388,608
  // ffn phase (reuses arena)
  ushort* hb     = (ushort*)(A0);                              //  8,388,608
  ushort* f1     = (ushort*)(A0 + 8388608);                    // 67,108,864
  ushort* ag     = (ushort*)(A0 + 75497472);                   // 33,554,432
  // bf16 transposed weights for the current layer
  char* W0 = A0 + 109051904;
  ushort* wqT  = (ushort*)(W0);
  ushort* wkvT = (ushort*)(W0 + 131072);
  ushort* woT  = (ushort*)(W0 + 393216);
  ushort* qkvT = (ushort*)(W0 + 524288);
  ushort* swoT = (ushort*)(W0 + 2097152);
  ushort* w1T  = (ushort*)(W0 + 2621440);
  ushort* w2T  = (ushort*)(W0 + 6815744);

  hipMemcpyAsync(x, bin_queries, X_BYTES, hipMemcpyDeviceToDevice, stream);

  for (int l = 0; l < 2; l++) {
    // ---- per-layer weight transpose+cast ----
    wtrans<<<dim3(CIc / 32, DIMc / 32), 256, 0, stream>>>(ca_wq + (size_t)l * DIMc * CIc, wqT, DIMc, CIc);
    wtrans<<<dim3(2 * CIc / 32, DIMc / 32), 256, 0, stream>>>(ca_wkv + (size_t)l * DIMc * 2 * CIc, wkvT, DIMc, 2 * CIc);
    wtrans<<<dim3(DIMc / 32, CIc / 32), 256, 0, stream>>>(ca_wo + (size_t)l * CIc * DIMc, woT, CIc, DIMc);
    wtrans<<<dim3(3 * SIc / 32, DIMc / 32), 256, 0, stream>>>(sa_wqkv + (size_t)l * DIMc * 3 * SIc, qkvT, DIMc, 3 * SIc);
    wtrans<<<dim3(DIMc / 32, SIc / 32), 256, 0, stream>>>(sa_wo + (size_t)l * SIc * DIMc, swoT, SIc, DIMc);
    wtrans<<<dim3(2 * FFc / 32, DIMc / 32), 256, 0, stream>>>(ffn_w1 + (size_t)l * DIMc * 2 * FFc, w1T, DIMc, 2 * FFc);
    wtrans<<<dim3(DIMc / 32, FFc / 32), 256, 0, stream>>>(ffn_w2 + (size_t)l * FFc * DIMc, w2T, FFc, DIMc);

    // ---- cross attention ----
    ln_rows<<<RQ / 4, 256, 0, stream>>>(x, ca_lnq_w + l * DIMc, ca_lnq_b + l * DIMc, ca_xn, RQ);
    ln_rows<<<RL / 4, 256, 0, stream>>>(latents, ca_lnc_w + l * DIMc, ca_lnc_b + l * DIMc, cn, RL);
    gemm64<0><<<dim3(CIc / 64, RQ / 64), 256, 0, stream>>>(ca_xn, wqT, nullptr, nullptr, qbuf, RQ, CIc, DIMc);
    gemm64<0><<<dim3(2 * CIc / 64, RL / 64), 256, 0, stream>>>(cn, wkvT, nullptr, nullptr, kv, RL, 2 * CIc, DIMc);
    rope_apply<<<(RQ * CHc * 32) / 256, 256, 0, stream>>>(qbuf, bin_time, RQ, CIc, 0, CHc, 0.125f);
    rope_apply<<<(RL * CHc * 32) / 256, 256, 0, stream>>>(kv, lat_time, RL, 2 * CIc, 0, CHc, 1.f);
    attn_row<<<(RQ * CHc) / 4, 256, 0, stream>>>(qbuf, kv, ca_att, CIc, 2 * CIc, 0, CIc, CIc,
                                                 Tc, Nc, CHc, 0, RQ * CHc);
    gemm64<1><<<dim3(DIMc / 64, RQ / 64), 256, 0, stream>>>(ca_att, woT, ca_bo + l * DIMc, x, nullptr, RQ, DIMc, CIc);

    // ---- self attention (causal) ----
    ln_rows<<<RQ / 4, 256, 0, stream>>>(x, sa_ln_w + l * DIMc, sa_ln_b + l * DIMc, sa_xn, RQ);
    gemm64<0><<<dim3(3 * SIc / 64, RQ / 64), 256, 0, stream>>>(sa_xn, qkvT, nullptr, nullptr, qkv, RQ, 3 * SIc, DIMc);
    rope_apply<<<(RQ * SHc * 32) / 256, 256, 0, stream>>>(qkv, bin_time, RQ, 3 * SIc, 0, SHc, 0.125f);
    rope_apply<<<(RQ * SHc * 32) / 256, 256, 0, stream>>>(qkv, bin_time, RQ, 3 * SIc, SIc, SHc, 1.f);
    attn_row<<<(RQ * SHc) / 4, 256, 0, stream>>>(qkv, qkv, sa_att, 3 * SIc, 3 * SIc, SIc, 2 * SIc, SIc,
                                                 Tc, Tc, SHc, 1, RQ * SHc);
    gemm64<1><<<dim3(DIMc / 64, RQ / 64), 256, 0, stream>>>(sa_att, swoT, sa_bo + l * DIMc, x, nullptr, RQ, DIMc, SIc);

    // ---- FFN ----
    ln_rows<<<RQ / 4, 256, 0, stream>>>(x, ffn_ln_w + l * DIMc, ffn_ln_b + l * DIMc, hb, RQ);
    gemm64<0><<<dim3(2 * FFc / 64, RQ / 64), 256, 0, stream>>>(hb, w1T, ffn_b1 + (size_t)l * 2 * FFc, nullptr, f1, RQ, 2 * FFc, DIMc);
    mulgelu<<<(RQ * FFc) / 256, 256, 0, stream>>>(f1, ag, RQ);
    gemm64<1><<<dim3(DIMc / 64, RQ / 64), 256, 0, stream>>>(ag, w2T, ffn_b2 + l * DIMc, x, nullptr, RQ, DIMc, FFc);
  }

  hipMemcpyAsync(d_out, x, X_BYTES, hipMemcpyDeviceToDevice, stream);
}

// Round 2
// 870.587 us; speedup vs baseline: 11.7800x; 11.7800x over previous
//
#include <hip/hip_runtime.h>
#include <cstdint>
#include <cstddef>

// ---------------- constants (match reference) ----------------
static constexpr int DIMc = 512;
static constexpr int DHc  = 64;
static constexpr int CHc  = 2;
static constexpr int SHc  = 8;
static constexpr int Bc   = 8;
static constexpr int Tc   = 1024;
static constexpr int Nc   = 2048;
static constexpr int CIc  = CHc * DHc;    // 128
static constexpr int SIc  = SHc * DHc;    // 512
static constexpr int FFc  = 4 * DIMc;     // 2048
static constexpr int RQ   = Bc * Tc;      // 8192 query rows
static constexpr int RL   = Bc * Nc;      // 16384 latent rows

typedef short bf16x8 __attribute__((ext_vector_type(8)));
typedef float f32x4  __attribute__((ext_vector_type(4)));

__device__ __forceinline__ ushort f2bf(float f) {
  uint32_t u = __builtin_bit_cast(uint32_t, f);
  u += 0x7fffu + ((u >> 16) & 1u);
  return (ushort)(u >> 16);
}
__device__ __forceinline__ float bf2f(ushort h) {
  uint32_t u = ((uint32_t)h) << 16;
  return __builtin_bit_cast(float, u);
}

// ---------------- LayerNorm: one wave per 512-col row, fp32 in -> bf16 out ----
__global__ __launch_bounds__(256) void ln_rows(const float* __restrict__ X,
    const float* __restrict__ w, const float* __restrict__ b,
    ushort* __restrict__ out, int rows) {
  int gw = (int)((blockIdx.x * 256 + threadIdx.x) >> 6);
  int lane = threadIdx.x & 63;
  if (gw >= rows) return;
  const float* xr = X + (size_t)gw * DIMc;
  float4 v0 = *(const float4*)(xr + lane * 8);
  float4 v1 = *(const float4*)(xr + lane * 8 + 4);
  float xv[8] = {v0.x, v0.y, v0.z, v0.w, v1.x, v1.y, v1.z, v1.w};
  float s = 0.f, ss = 0.f;
#pragma unroll
  for (int i = 0; i < 8; i++) { s += xv[i]; ss += xv[i] * xv[i]; }
#pragma unroll
  for (int off = 32; off; off >>= 1) { s += __shfl_xor(s, off); ss += __shfl_xor(ss, off); }
  float mean = s * (1.f / DIMc);
  float var = ss * (1.f / DIMc) - mean * mean;
  float r = rsqrtf(var + 1e-5f);
  int c = lane * 8;
  ushort o[8] __attribute__((aligned(16)));
#pragma unroll
  for (int i = 0; i < 8; i++) o[i] = f2bf((xv[i] - mean) * r * w[c + i] + b[c + i]);
  *(uint4*)(out + (size_t)gw * DIMc + c) = *(const uint4*)o;
}

// ---------------- weight transpose + fp32->bf16: W(K,N) -> Wt(N,K) ----------
__global__ __launch_bounds__(256) void wtrans(const float* __restrict__ W,
    ushort* __restrict__ Wt, int K, int N) {
  __shared__ float tile[32][33];
  int n0 = blockIdx.x * 32, k0 = blockIdx.y * 32;
  int tx = threadIdx.x & 31, ty = threadIdx.x >> 5;  // 32 x 8
#pragma unroll
  for (int i = 0; i < 32; i += 8)
    tile[ty + i][tx] = W[(size_t)(k0 + ty + i) * N + n0 + tx];
  __syncthreads();
#pragma unroll
  for (int i = 0; i < 32; i += 8)
    Wt[(size_t)(n0 + ty + i) * K + k0 + tx] = f2bf(tile[tx][ty + i]);
}

// ---------------- bf16 V transpose: src rows (b*NK+key, stride, colOff) ------
// dst[b][hd][key]  where hd = 0 .. gridDim.y*32-1
__global__ __launch_bounds__(256) void vtrans(const ushort* __restrict__ src,
    ushort* __restrict__ dst, int NK, int stride, int colOff) {
  __shared__ ushort tile[32][33];
  int b = blockIdx.z;
  int key0 = blockIdx.x * 32, hd0 = blockIdx.y * 32;
  int HD = gridDim.y * 32;
  int tx = threadIdx.x & 31, ty = threadIdx.x >> 5;
#pragma unroll
  for (int i = 0; i < 32; i += 8)
    tile[ty + i][tx] = src[(size_t)(b * NK + key0 + ty + i) * stride + colOff + hd0 + tx];
  __syncthreads();
#pragma unroll
  for (int i = 0; i < 32; i += 8)
    dst[((size_t)b * HD + hd0 + ty + i) * NK + key0 + tx] = tile[tx][ty + i];
}

// ---------------- bf16 MFMA GEMM, 64x64 tile, BK=32, 4 waves -----------------
template<int MODE>
__global__ __launch_bounds__(256) void gemm64(const ushort* __restrict__ A,
    const ushort* __restrict__ Bt, const float* __restrict__ bias,
    float* __restrict__ resF, ushort* __restrict__ outB,
    int M, int N, int K) {
  __shared__ __align__(16) ushort As[64][40];
  __shared__ __align__(16) ushort Bs[64][40];
  int t = threadIdx.x;
  int bm = blockIdx.y, bn = blockIdx.x;
  int row = t >> 2, kc = (t & 3) << 3;
  const ushort* aG = A + (size_t)(bm * 64 + row) * K + kc;
  const ushort* bG = Bt + (size_t)(bn * 64 + row) * K + kc;
  int wv = t >> 6, lane = t & 63;
  int wr = (wv >> 1) * 32, wc = (wv & 1) * 32;
  int fr = lane & 15, fk = (lane >> 4) << 3;
  f32x4 acc[2][2] = {};
  for (int k0 = 0; k0 < K; k0 += 32) {
    *(uint4*)&As[row][kc] = *(const uint4*)(aG + k0);
    *(uint4*)&Bs[row][kc] = *(const uint4*)(bG + k0);
    __syncthreads();
    bf16x8 a0 = *(const bf16x8*)&As[wr + fr][fk];
    bf16x8 a1 = *(const bf16x8*)&As[wr + 16 + fr][fk];
    bf16x8 b0 = *(const bf16x8*)&Bs[wc + fr][fk];
    bf16x8 b1 = *(const bf16x8*)&Bs[wc + 16 + fr][fk];
    acc[0][0] = __builtin_amdgcn_mfma_f32_16x16x32_bf16(a0, b0, acc[0][0], 0, 0, 0);
    acc[0][1] = __builtin_amdgcn_mfma_f32_16x16x32_bf16(a0, b1, acc[0][1], 0, 0, 0);
    acc[1][0] = __builtin_amdgcn_mfma_f32_16x16x32_bf16(a1, b0, acc[1][0], 0, 0, 0);
    acc[1][1] = __builtin_amdgcn_mfma_f32_16x16x32_bf16(a1, b1, acc[1][1], 0, 0, 0);
    __syncthreads();
  }
  int cr0 = wr + ((lane >> 4) << 2);
  int cc0 = wc + fr;
#pragma unroll
  for (int mm = 0; mm < 2; mm++)
#pragma unroll
    for (int nn = 0; nn < 2; nn++)
#pragma unroll
      for (int i = 0; i < 4; i++) {
        int gr = bm * 64 + cr0 + mm * 16 + i;
        int gc = bn * 64 + cc0 + nn * 16;
        float val = acc[mm][nn][i] + (bias ? bias[gc] : 0.f);
        if (MODE == 0) outB[(size_t)gr * N + gc] = f2bf(val);
        else resF[(size_t)gr * N + gc] = resF[(size_t)gr * N + gc] + val;
      }
}

// ---------------- elementwise rotary (in place on bf16 buffer) ---------------
__global__ __launch_bounds__(256) void rope_apply(ushort* __restrict__ buf,
    const float* __restrict__ fr, int rows, int stride, int colOff, int H, float scale) {
  int idx = blockIdx.x * 256 + threadIdx.x;
  int total = rows * H * 32;
  if (idx >= total) return;
  int p = idx & 31;
  int h = (idx >> 5) % H;
  int r = idx / (32 * H);
  float f0 = fr[(size_t)r * DHc + 2 * p];
  float f1 = fr[(size_t)r * DHc + 2 * p + 1];
  ushort* bp = buf + (size_t)r * stride + colOff + h * DHc + 2 * p;
  float x0 = bf2f(bp[0]), x1 = bf2f(bp[1]);
  float o0 = (x0 * __cosf(f0) - x1 * __sinf(f0)) * scale;
  float o1 = (x1 * __cosf(f1) + x0 * __sinf(f1)) * scale;
  bp[0] = f2bf(o0); bp[1] = f2bf(o1);
}

// ---------------- MFMA flash attention -----------------------------------------
// Block: 4 waves, 64 q-rows (16/wave) for one (b,h). KV tiles of 64 keys in LDS.
// Q pre-rotated and pre-scaled; K pre-rotated; Vt is [b][h*64+d][key].
template<int CAUSAL>
__global__ __launch_bounds__(256) void attn_mfma(
    const ushort* __restrict__ Q, const ushort* __restrict__ K,
    const ushort* __restrict__ Vt, ushort* __restrict__ O,
    int qStride, int kStride, int kOff, int oStride,
    int Tq, int NK, int H) {
  __shared__ __align__(16) ushort Ks[64 * 64];   // [key][d], 16B-chunk XOR swizzled
  __shared__ __align__(16) ushort Vs[64 * 64];   // [d][key], 16B-chunk XOR swizzled
  __shared__ __align__(16) ushort Ps[4][16 * 72];
  int b = blockIdx.z, h = blockIdx.y, qt = blockIdx.x;
  int t = threadIdx.x, wv = t >> 6, lane = t & 63;
  int g = lane >> 4, fr = lane & 15;
  int q0 = qt * 64, qw = q0 + wv * 16;
  int HD = H * 64;

  const ushort* qrow = Q + (size_t)(b * Tq + qw + fr) * qStride + h * 64;
  bf16x8 qlo = *(const bf16x8*)(qrow + g * 8);        // d 0..31 slice
  bf16x8 qhi = *(const bf16x8*)(qrow + 32 + g * 8);   // d 32..63 slice

  f32x4 o_acc[4] = {};
  float m_run[4], l_run[4];
#pragma unroll
  for (int i = 0; i < 4; i++) { m_run[i] = -1e30f; l_run[i] = 0.f; }

  ushort* Pw = &Ps[wv][0];
  int ntiles = CAUSAL ? (qt + 1) : (NK / 64);
  for (int kt = 0; kt < ntiles; kt++) {
    int k0 = kt * 64;
    __syncthreads();
#pragma unroll
    for (int i = 0; i < 2; i++) {
      int id = t + i * 256;
      int r = id >> 3, c = id & 7;
      uint4 kval = *(const uint4*)(K + (size_t)(b * NK + k0 + r) * kStride + kOff + h * 64 + c * 8);
      *(uint4*)(Ks + r * 64 + ((c ^ (r & 7)) * 8)) = kval;
      uint4 vval = *(const uint4*)(Vt + ((size_t)b * HD + h * 64 + r) * NK + k0 + c * 8);
      *(uint4*)(Vs + r * 64 + ((c ^ (r & 7)) * 8)) = vval;
    }
    __syncthreads();

    // S = Q K^T : 16 q-rows x 64 keys, fp32
    f32x4 s[4];
#pragma unroll
    for (int nn = 0; nn < 4; nn++) {
      int row = nn * 16 + fr;
      bf16x8 kf0 = *(const bf16x8*)(Ks + row * 64 + ((g ^ (fr & 7)) * 8));
      bf16x8 kf1 = *(const bf16x8*)(Ks + row * 64 + (((4 + g) ^ (fr & 7)) * 8));
      f32x4 z = {};
      z = __builtin_amdgcn_mfma_f32_16x16x32_bf16(qlo, kf0, z, 0, 0, 0);
      z = __builtin_amdgcn_mfma_f32_16x16x32_bf16(qhi, kf1, z, 0, 0, 0);
      s[nn] = z;
    }
    if (CAUSAL && (k0 + 63 > qw)) {
#pragma unroll
      for (int nn = 0; nn < 4; nn++)
#pragma unroll
        for (int i = 0; i < 4; i++)
          if (k0 + nn * 16 + fr > qw + g * 4 + i) s[nn][i] = -1e30f;
    }
    // online softmax (rows live in 16-lane groups: row = g*4+i, col = fr)
#pragma unroll
    for (int i = 0; i < 4; i++) {
      float tm = fmaxf(fmaxf(s[0][i], s[1][i]), fmaxf(s[2][i], s[3][i]));
#pragma unroll
      for (int off = 8; off; off >>= 1) tm = fmaxf(tm, __shfl_xor(tm, off));
      float mnew = fmaxf(m_run[i], tm);
      float corr = __expf(m_run[i] - mnew);
      float ps = 0.f;
#pragma unroll
      for (int nn = 0; nn < 4; nn++) {
        float p = __expf(s[nn][i] - mnew);
        s[nn][i] = p;
        ps += p;
      }
#pragma unroll
      for (int off = 8; off; off >>= 1) ps += __shfl_xor(ps, off);
      l_run[i] = l_run[i] * corr + ps;
      m_run[i] = mnew;
#pragma unroll
      for (int dd = 0; dd < 4; dd++) o_acc[dd][i] *= corr;
    }
    // P (C-layout) -> per-wave LDS -> A-fragment layout
#pragma unroll
    for (int nn = 0; nn < 4; nn++)
#pragma unroll
      for (int i = 0; i < 4; i++)
        Pw[(g * 4 + i) * 72 + nn * 16 + fr] = f2bf(s[nn][i]);
    bf16x8 pa0 = *(const bf16x8*)(Pw + fr * 72 + g * 8);
    bf16x8 pa1 = *(const bf16x8*)(Pw + fr * 72 + 32 + g * 8);
#pragma unroll
    for (int dd = 0; dd < 4; dd++) {
      int row = dd * 16 + fr;
      bf16x8 vf0 = *(const bf16x8*)(Vs + row * 64 + ((g ^ (fr & 7)) * 8));
      bf16x8 vf1 = *(const bf16x8*)(Vs + row * 64 + (((4 + g) ^ (fr & 7)) * 8));
      o_acc[dd] = __builtin_amdgcn_mfma_f32_16x16x32_bf16(pa0, vf0, o_acc[dd], 0, 0, 0);
      o_acc[dd] = __builtin_amdgcn_mfma_f32_16x16x32_bf16(pa1, vf1, o_acc[dd], 0, 0, 0);
    }
  }
#pragma unroll
  for (int dd = 0; dd < 4; dd++)
#pragma unroll
    for (int i = 0; i < 4; i++) {
      size_t oidx = (size_t)(b * Tq + qw + g * 4 + i) * oStride + h * 64 + dd * 16 + fr;
      O[oidx] = f2bf(o_acc[dd][i] / l_run[i]);
    }
}

// ---------------- a * gelu(g), exact erf --------------------------------------
__global__ __launch_bounds__(256) void mulgelu(const ushort* __restrict__ F1,
    ushort* __restrict__ AG, int rows) {
  int idx = blockIdx.x * 256 + threadIdx.x;
  if (idx >= rows * FFc) return;
  int r = idx >> 11, c = idx & (FFc - 1);
  float a = bf2f(F1[(size_t)r * (2 * FFc) + c]);
  float g = bf2f(F1[(size_t)r * (2 * FFc) + FFc + c]);
  float gg = 0.5f * g * (1.f + erff(g * 0.70710678118f));
  AG[idx] = f2bf(a * gg);
}

// ---------------- orchestration ----------------------------------------------
extern "C" void kernel_launch(void* const* d_in, const int* in_sizes, int n_in,
                              void* d_out, int out_size, void* d_ws, size_t ws_size,
                              hipStream_t stream) {
  const float* bin_queries = (const float*)d_in[0];
  const float* bin_time    = (const float*)d_in[1];
  const float* latents     = (const float*)d_in[2];
  const float* lat_time    = (const float*)d_in[3];
  const float* ca_lnq_w = (const float*)d_in[4];
  const float* ca_lnq_b = (const float*)d_in[5];
  const float* ca_lnc_w = (const float*)d_in[6];
  const float* ca_lnc_b = (const float*)d_in[7];
  const float* ca_wq  = (const float*)d_in[8];
  const float* ca_wkv = (const float*)d_in[9];
  const float* ca_wo  = (const float*)d_in[10];
  const float* ca_bo  = (const float*)d_in[11];
  const float* sa_ln_w = (const float*)d_in[12];
  const float* sa_ln_b = (const float*)d_in[13];
  const float* sa_wqkv = (const float*)d_in[14];
  const float* sa_wo   = (const float*)d_in[15];
  const float* sa_bo   = (const float*)d_in[16];
  const float* ffn_ln_w = (const float*)d_in[17];
  const float* ffn_ln_b = (const float*)d_in[18];
  const float* ffn_w1 = (const float*)d_in[19];
  const float* ffn_b1 = (const float*)d_in[20];
  const float* ffn_w2 = (const float*)d_in[21];
  const float* ffn_b2 = (const float*)d_in[22];

  constexpr size_t X_BYTES = (size_t)RQ * DIMc * 4;
  char* ws = (char*)d_ws;
  float* x = (float*)ws;
  char* A0 = ws + X_BYTES;
  // cross-attn phase
  ushort* cn     = (ushort*)(A0);
  ushort* ca_xn  = (ushort*)(A0 + 16777216);
  ushort* qbuf   = (ushort*)(A0 + 25165824);
  ushort* kv     = (ushort*)(A0 + 27262976);
  ushort* ca_att = (ushort*)(A0 + 35651584);
  ushort* vt_c   = (ushort*)(A0 + 37748736);   // 4 MB, cross phase only
  // self-attn phase (reuses arena)
  ushort* sa_xn  = (ushort*)(A0);
  ushort* qkv    = (ushort*)(A0 + 8388608);
  ushort* sa_att = (ushort*)(A0 + 33554432);
  ushort* vt_s   = (ushort*)(A0 + 41943040);   // 8 MB, self phase only
  // ffn phase (reuses arena)
  ushort* hb     = (ushort*)(A0);
  ushort* f1     = (ushort*)(A0 + 8388608);
  ushort* ag     = (ushort*)(A0 + 75497472);
  // bf16 transposed weights for the current layer
  char* W0 = A0 + 109051904;
  ushort* wqT  = (ushort*)(W0);
  ushort* wkvT = (ushort*)(W0 + 131072);
  ushort* woT  = (ushort*)(W0 + 393216);
  ushort* qkvT = (ushort*)(W0 + 524288);
  ushort* swoT = (ushort*)(W0 + 2097152);
  ushort* w1T  = (ushort*)(W0 + 2621440);
  ushort* w2T  = (ushort*)(W0 + 6815744);

  hipMemcpyAsync(x, bin_queries, X_BYTES, hipMemcpyDeviceToDevice, stream);

  for (int l = 0; l < 2; l++) {
    wtrans<<<dim3(CIc / 32, DIMc / 32), 256, 0, stream>>>(ca_wq + (size_t)l * DIMc * CIc, wqT, DIMc, CIc);
    wtrans<<<dim3(2 * CIc / 32, DIMc / 32), 256, 0, stream>>>(ca_wkv + (size_t)l * DIMc * 2 * CIc, wkvT, DIMc, 2 * CIc);
    wtrans<<<dim3(DIMc / 32, CIc / 32), 256, 0, stream>>>(ca_wo + (size_t)l * CIc * DIMc, woT, CIc, DIMc);
    wtrans<<<dim3(3 * SIc / 32, DIMc / 32), 256, 0, stream>>>(sa_wqkv + (size_t)l * DIMc * 3 * SIc, qkvT, DIMc, 3 * SIc);
    wtrans<<<dim3(DIMc / 32, SIc / 32), 256, 0, stream>>>(sa_wo + (size_t)l * SIc * DIMc, swoT, SIc, DIMc);
    wtrans<<<dim3(2 * FFc / 32, DIMc / 32), 256, 0, stream>>>(ffn_w1 + (size_t)l * DIMc * 2 * FFc, w1T, DIMc, 2 * FFc);
    wtrans<<<dim3(DIMc / 32, FFc / 32), 256, 0, stream>>>(ffn_w2 + (size_t)l * FFc * DIMc, w2T, FFc, DIMc);

    // ---- cross attention ----
    ln_rows<<<RQ / 4, 256, 0, stream>>>(x, ca_lnq_w + l * DIMc, ca_lnq_b + l * DIMc, ca_xn, RQ);
    ln_rows<<<RL / 4, 256, 0, stream>>>(latents, ca_lnc_w + l * DIMc, ca_lnc_b + l * DIMc, cn, RL);
    gemm64<0><<<dim3(CIc / 64, RQ / 64), 256, 0, stream>>>(ca_xn, wqT, nullptr, nullptr, qbuf, RQ, CIc, DIMc);
    gemm64<0><<<dim3(2 * CIc / 64, RL / 64), 256, 0, stream>>>(cn, wkvT, nullptr, nullptr, kv, RL, 2 * CIc, DIMc);
    rope_apply<<<(RQ * CHc * 32) / 256, 256, 0, stream>>>(qbuf, bin_time, RQ, CIc, 0, CHc, 0.125f);
    rope_apply<<<(RL * CHc * 32) / 256, 256, 0, stream>>>(kv, lat_time, RL, 2 * CIc, 0, CHc, 1.f);
    vtrans<<<dim3(Nc / 32, CHc * 64 / 32, Bc), 256, 0, stream>>>(kv, vt_c, Nc, 2 * CIc, CIc);
    attn_mfma<0><<<dim3(Tc / 64, CHc, Bc), 256, 0, stream>>>(qbuf, kv, vt_c, ca_att,
        CIc, 2 * CIc, 0, CIc, Tc, Nc, CHc);
    gemm64<1><<<dim3(DIMc / 64, RQ / 64), 256, 0, stream>>>(ca_att, woT, ca_bo + l * DIMc, x, nullptr, RQ, DIMc, CIc);

    // ---- self attention (causal) ----
    ln_rows<<<RQ / 4, 256, 0, stream>>>(x, sa_ln_w + l * DIMc, sa_ln_b + l * DIMc, sa_xn, RQ);
    gemm64<0><<<dim3(3 * SIc / 64, RQ / 64), 256, 0, stream>>>(sa_xn, qkvT, nullptr, nullptr, qkv, RQ, 3 * SIc, DIMc);
    rope_apply<<<(RQ * SHc * 32) / 256, 256, 0, stream>>>(qkv, bin_time, RQ, 3 * SIc, 0, SHc, 0.125f);
    rope_apply<<<(RQ * SHc * 32) / 256, 256, 0, stream>>>(qkv, bin_time, RQ, 3 * SIc, SIc, SHc, 1.f);
    vtrans<<<dim3(Tc / 32, SHc * 64 / 32, Bc), 256, 0, stream>>>(qkv, vt_s, Tc, 3 * SIc, 2 * SIc);
    attn_mfma<1><<<dim3(Tc / 64, SHc, Bc), 256, 0, stream>>>(qkv, qkv, vt_s, sa_att,
        3 * SIc, 3 * SIc, SIc, SIc, Tc, Tc, SHc);
    gemm64<1><<<dim3(DIMc / 64, RQ / 64), 256, 0, stream>>>(sa_att, swoT, sa_bo + l * DIMc, x, nullptr, RQ, DIMc, SIc);

    // ---- FFN ----
    ln_rows<<<RQ / 4, 256, 0, stream>>>(x, ffn_ln_w + l * DIMc, ffn_ln_b + l * DIMc, hb, RQ);
    gemm64<0><<<dim3(2 * FFc / 64, RQ / 64), 256, 0, stream>>>(hb, w1T, ffn_b1 + (size_t)l * 2 * FFc, nullptr, f1, RQ, 2 * FFc, DIMc);
    mulgelu<<<(RQ * FFc) / 256, 256, 0, stream>>>(f1, ag, RQ);
    gemm64<1><<<dim3(DIMc / 64, RQ / 64), 256, 0, stream>>>(ag, w2T, ffn_b2 + l * DIMc, x, nullptr, RQ, DIMc, FFc);
  }

  hipMemcpyAsync(d_out, x, X_BYTES, hipMemcpyDeviceToDevice, stream);
}

// Round 3
// 851.987 us; speedup vs baseline: 12.0372x; 1.0218x over previous
//
#include <hip/hip_runtime.h>
#include <cstdint>
#include <cstddef>

// ---------------- constants (match reference) ----------------
static constexpr int DIMc = 512;
static constexpr int DHc  = 64;
static constexpr int CHc  = 2;
static constexpr int SHc  = 8;
static constexpr int Bc   = 8;
static constexpr int Tc   = 1024;
static constexpr int Nc   = 2048;
static constexpr int CIc  = CHc * DHc;    // 128
static constexpr int SIc  = SHc * DHc;    // 512
static constexpr int FFc  = 4 * DIMc;     // 2048
static constexpr int RQ   = Bc * Tc;      // 8192 query rows
static constexpr int RL   = Bc * Nc;      // 16384 latent rows

typedef short bf16x8 __attribute__((ext_vector_type(8)));
typedef float f32x4  __attribute__((ext_vector_type(4)));

__device__ __forceinline__ ushort f2bf(float f) {
  uint32_t u = __builtin_bit_cast(uint32_t, f);
  u += 0x7fffu + ((u >> 16) & 1u);
  return (ushort)(u >> 16);
}
__device__ __forceinline__ float bf2f(ushort h) {
  uint32_t u = ((uint32_t)h) << 16;
  return __builtin_bit_cast(float, u);
}

__device__ __forceinline__ void gload_lds16(const ushort* g, ushort* lds) {
  __builtin_amdgcn_global_load_lds(
      (const __attribute__((address_space(1))) void*)g,
      (__attribute__((address_space(3))) void*)lds, 16, 0, 0);
}

// ---------------- LayerNorm: one wave per 512-col row, fp32 in -> bf16 out ----
__global__ __launch_bounds__(256) void ln_rows(const float* __restrict__ X,
    const float* __restrict__ w, const float* __restrict__ b,
    ushort* __restrict__ out, int rows) {
  int gw = (int)((blockIdx.x * 256 + threadIdx.x) >> 6);
  int lane = threadIdx.x & 63;
  if (gw >= rows) return;
  const float* xr = X + (size_t)gw * DIMc;
  float4 v0 = *(const float4*)(xr + lane * 8);
  float4 v1 = *(const float4*)(xr + lane * 8 + 4);
  float xv[8] = {v0.x, v0.y, v0.z, v0.w, v1.x, v1.y, v1.z, v1.w};
  float s = 0.f, ss = 0.f;
#pragma unroll
  for (int i = 0; i < 8; i++) { s += xv[i]; ss += xv[i] * xv[i]; }
#pragma unroll
  for (int off = 32; off; off >>= 1) { s += __shfl_xor(s, off); ss += __shfl_xor(ss, off); }
  float mean = s * (1.f / DIMc);
  float var = ss * (1.f / DIMc) - mean * mean;
  float r = rsqrtf(var + 1e-5f);
  int c = lane * 8;
  ushort o[8] __attribute__((aligned(16)));
#pragma unroll
  for (int i = 0; i < 8; i++) o[i] = f2bf((xv[i] - mean) * r * w[c + i] + b[c + i]);
  *(uint4*)(out + (size_t)gw * DIMc + c) = *(const uint4*)o;
}

// ------------- ALL weight transposes for one layer, one launch ----------------
// flattened grid of 32x32 tiles over the 7 weight matrices
__global__ __launch_bounds__(256) void wtrans_all(
    const float* __restrict__ wq, const float* __restrict__ wkv,
    const float* __restrict__ wo, const float* __restrict__ qkv,
    const float* __restrict__ swo, const float* __restrict__ w1,
    const float* __restrict__ w2, ushort* __restrict__ dst, int layer) {
  constexpr int Ks[7]   = {512, 512, 128, 512, 512, 512, 2048};
  constexpr int Ns[7]   = {128, 256, 512, 1536, 512, 4096, 512};
  constexpr int pre[8]  = {0, 64, 192, 256, 1024, 1280, 3328, 4352};
  constexpr int dOff[7] = {0, 65536, 196608, 262144, 1048576, 1310720, 3407872};
  int bid = blockIdx.x;
  int wid = 0;
#pragma unroll
  for (int i = 1; i < 7; i++) wid += (bid >= pre[i]);
  int tileIdx = bid - pre[wid];
  int K = Ks[wid], N = Ns[wid];
  const float* srcs[7] = {wq, wkv, wo, qkv, swo, w1, w2};
  const float* W = srcs[wid] + (size_t)layer * K * N;
  ushort* Wt = dst + dOff[wid];
  int ntx = N / 32;
  int n0 = (tileIdx % ntx) * 32, k0 = (tileIdx / ntx) * 32;
  __shared__ float tile[32][33];
  int tx = threadIdx.x & 31, ty = threadIdx.x >> 5;
#pragma unroll
  for (int i = 0; i < 32; i += 8)
    tile[ty + i][tx] = W[(size_t)(k0 + ty + i) * N + n0 + tx];
  __syncthreads();
#pragma unroll
  for (int i = 0; i < 32; i += 8)
    Wt[(size_t)(n0 + ty + i) * K + k0 + tx] = f2bf(tile[tx][ty + i]);
}

// ---------------- bf16 V transpose: dst[b][hd][key] --------------------------
__global__ __launch_bounds__(256) void vtrans(const ushort* __restrict__ src,
    ushort* __restrict__ dst, int NK, int stride, int colOff) {
  __shared__ ushort tile[32][33];
  int b = blockIdx.z;
  int key0 = blockIdx.x * 32, hd0 = blockIdx.y * 32;
  int HD = gridDim.y * 32;
  int tx = threadIdx.x & 31, ty = threadIdx.x >> 5;
#pragma unroll
  for (int i = 0; i < 32; i += 8)
    tile[ty + i][tx] = src[(size_t)(b * NK + key0 + ty + i) * stride + colOff + hd0 + tx];
  __syncthreads();
#pragma unroll
  for (int i = 0; i < 32; i += 8)
    dst[((size_t)b * HD + hd0 + ty + i) * NK + key0 + tx] = tile[tx][ty + i];
}

// ------------- m97-style 128x128 GEMM, BK=64, global_load_lds, swizzled ------
// A: M x K bf16 row-major.  Bt: N x K bf16 row-major.
// LDS layout: row stride 64 bf16; 16B chunk at slot s of row r holds logical
// k-chunk (s ^ (r&7))  -> ds_read 2-way bank aliasing only (free).
template<int MODE>
__global__ __launch_bounds__(256) void gemm128(const ushort* __restrict__ A,
    const ushort* __restrict__ Bt, const float* __restrict__ bias,
    float* __restrict__ resF, ushort* __restrict__ outB,
    int M, int N, int K) {
  __shared__ __align__(16) ushort As[128 * 64];
  __shared__ __align__(16) ushort Bs[128 * 64];
  int t = threadIdx.x, wv = t >> 6, lane = t & 63;
  int bm = blockIdx.y, bn = blockIdx.x;
  int fr = lane & 15, g = lane >> 4;
  int wr = (wv >> 1) * 64, wc = (wv & 1) * 64;

  // staging geometry: wave wv covers tile rows [wv*32, wv*32+32); 4 issues of
  // 64 chunks (16B).  chunk c = j*64+lane -> row wv*32+(c>>3), slot c&7,
  // global k-chunk = slot ^ (row&7).
  int srow = wv * 32 + (lane >> 3);
  int sslot = lane & 7;
  const ushort* aRow = A + (size_t)(bm * 128 + srow) * K;
  const ushort* bRow = Bt + (size_t)(bn * 128 + srow) * K;

  f32x4 acc[4][4] = {};
  for (int k0 = 0; k0 < K; k0 += 64) {
#pragma unroll
    for (int j = 0; j < 4; j++) {
      int r = srow + j * 8;                 // rows advance by 8 per issue
      int kc = sslot ^ (r & 7);
      gload_lds16(A + (size_t)(bm * 128 + r) * K + k0 + kc * 8,
                  As + (wv * 256 + j * 64) * 8);
      gload_lds16(Bt + (size_t)(bn * 128 + r) * K + k0 + kc * 8,
                  Bs + (wv * 256 + j * 64) * 8);
    }
    __syncthreads();
#pragma unroll
    for (int ks = 0; ks < 2; ks++) {
      bf16x8 af[4], bf[4];
#pragma unroll
      for (int mm = 0; mm < 4; mm++) {
        int row = wr + mm * 16 + fr;
        af[mm] = *(const bf16x8*)(As + row * 64 + (((ks * 4 + g) ^ (row & 7)) * 8));
      }
#pragma unroll
      for (int nn = 0; nn < 4; nn++) {
        int row = wc + nn * 16 + fr;
        bf[nn] = *(const bf16x8*)(Bs + row * 64 + (((ks * 4 + g) ^ (row & 7)) * 8));
      }
#pragma unroll
      for (int mm = 0; mm < 4; mm++)
#pragma unroll
        for (int nn = 0; nn < 4; nn++)
          acc[mm][nn] = __builtin_amdgcn_mfma_f32_16x16x32_bf16(af[mm], bf[nn], acc[mm][nn], 0, 0, 0);
    }
    __syncthreads();
  }
#pragma unroll
  for (int mm = 0; mm < 4; mm++)
#pragma unroll
    for (int nn = 0; nn < 4; nn++)
#pragma unroll
      for (int i = 0; i < 4; i++) {
        int gr = bm * 128 + wr + mm * 16 + g * 4 + i;
        int gc = bn * 128 + wc + nn * 16 + fr;
        float val = acc[mm][nn][i] + (bias ? bias[gc] : 0.f);
        if (MODE == 0) outB[(size_t)gr * N + gc] = f2bf(val);
        else resF[(size_t)gr * N + gc] = resF[(size_t)gr * N + gc] + val;
      }
}

// ---------------- bf16 MFMA GEMM, 64x64 tile (small-N shapes) ----------------
template<int MODE>
__global__ __launch_bounds__(256) void gemm64(const ushort* __restrict__ A,
    const ushort* __restrict__ Bt, const float* __restrict__ bias,
    float* __restrict__ resF, ushort* __restrict__ outB,
    int M, int N, int K) {
  __shared__ __align__(16) ushort As[64][40];
  __shared__ __align__(16) ushort Bs[64][40];
  int t = threadIdx.x;
  int bm = blockIdx.y, bn = blockIdx.x;
  int row = t >> 2, kc = (t & 3) << 3;
  const ushort* aG = A + (size_t)(bm * 64 + row) * K + kc;
  const ushort* bG = Bt + (size_t)(bn * 64 + row) * K + kc;
  int wv = t >> 6, lane = t & 63;
  int wr = (wv >> 1) * 32, wc = (wv & 1) * 32;
  int fr = lane & 15, fk = (lane >> 4) << 3;
  f32x4 acc[2][2] = {};
  for (int k0 = 0; k0 < K; k0 += 32) {
    *(uint4*)&As[row][kc] = *(const uint4*)(aG + k0);
    *(uint4*)&Bs[row][kc] = *(const uint4*)(bG + k0);
    __syncthreads();
    bf16x8 a0 = *(const bf16x8*)&As[wr + fr][fk];
    bf16x8 a1 = *(const bf16x8*)&As[wr + 16 + fr][fk];
    bf16x8 b0 = *(const bf16x8*)&Bs[wc + fr][fk];
    bf16x8 b1 = *(const bf16x8*)&Bs[wc + 16 + fr][fk];
    acc[0][0] = __builtin_amdgcn_mfma_f32_16x16x32_bf16(a0, b0, acc[0][0], 0, 0, 0);
    acc[0][1] = __builtin_amdgcn_mfma_f32_16x16x32_bf16(a0, b1, acc[0][1], 0, 0, 0);
    acc[1][0] = __builtin_amdgcn_mfma_f32_16x16x32_bf16(a1, b0, acc[1][0], 0, 0, 0);
    acc[1][1] = __builtin_amdgcn_mfma_f32_16x16x32_bf16(a1, b1, acc[1][1], 0, 0, 0);
    __syncthreads();
  }
  int cr0 = wr + ((lane >> 4) << 2);
  int cc0 = wc + fr;
#pragma unroll
  for (int mm = 0; mm < 2; mm++)
#pragma unroll
    for (int nn = 0; nn < 2; nn++)
#pragma unroll
      for (int i = 0; i < 4; i++) {
        int gr = bm * 64 + cr0 + mm * 16 + i;
        int gc = bn * 64 + cc0 + nn * 16;
        float val = acc[mm][nn][i] + (bias ? bias[gc] : 0.f);
        if (MODE == 0) outB[(size_t)gr * N + gc] = f2bf(val);
        else resF[(size_t)gr * N + gc] = resF[(size_t)gr * N + gc] + val;
      }
}

// ---------------- elementwise rotary (in place on bf16 buffer) ---------------
__global__ __launch_bounds__(256) void rope_apply(ushort* __restrict__ buf,
    const float* __restrict__ fr, int rows, int stride, int colOff, int H, float scale) {
  int idx = blockIdx.x * 256 + threadIdx.x;
  int total = rows * H * 32;
  if (idx >= total) return;
  int p = idx & 31;
  int h = (idx >> 5) % H;
  int r = idx / (32 * H);
  float f0 = fr[(size_t)r * DHc + 2 * p];
  float f1 = fr[(size_t)r * DHc + 2 * p + 1];
  ushort* bp = buf + (size_t)r * stride + colOff + h * DHc + 2 * p;
  float x0 = bf2f(bp[0]), x1 = bf2f(bp[1]);
  float o0 = (x0 * __cosf(f0) - x1 * __sinf(f0)) * scale;
  float o1 = (x1 * __cosf(f1) + x0 * __sinf(f1)) * scale;
  bp[0] = f2bf(o0); bp[1] = f2bf(o1);
}

// ---------------- MFMA flash attention ---------------------------------------
template<int CAUSAL>
__global__ __launch_bounds__(256) void attn_mfma(
    const ushort* __restrict__ Q, const ushort* __restrict__ K,
    const ushort* __restrict__ Vt, ushort* __restrict__ O,
    int qStride, int kStride, int kOff, int oStride,
    int Tq, int NK, int H) {
  __shared__ __align__(16) ushort Ks[64 * 64];
  __shared__ __align__(16) ushort Vs[64 * 64];
  __shared__ __align__(16) ushort Ps[4][16 * 72];
  int b = blockIdx.z, h = blockIdx.y, qt = blockIdx.x;
  int t = threadIdx.x, wv = t >> 6, lane = t & 63;
  int g = lane >> 4, fr = lane & 15;
  int qw = qt * 64 + wv * 16;
  int HD = H * 64;

  const ushort* qrow = Q + (size_t)(b * Tq + qw + fr) * qStride + h * 64;
  bf16x8 qlo = *(const bf16x8*)(qrow + g * 8);
  bf16x8 qhi = *(const bf16x8*)(qrow + 32 + g * 8);

  f32x4 o_acc[4] = {};
  float m_run[4], l_run[4];
#pragma unroll
  for (int i = 0; i < 4; i++) { m_run[i] = -1e30f; l_run[i] = 0.f; }

  ushort* Pw = &Ps[wv][0];
  int ntiles = CAUSAL ? (qt + 1) : (NK / 64);
  for (int kt = 0; kt < ntiles; kt++) {
    int k0 = kt * 64;
    __syncthreads();
#pragma unroll
    for (int i = 0; i < 2; i++) {
      int id = t + i * 256;
      int r = id >> 3, c = id & 7;
      uint4 kval = *(const uint4*)(K + (size_t)(b * NK + k0 + r) * kStride + kOff + h * 64 + c * 8);
      *(uint4*)(Ks + r * 64 + ((c ^ (r & 7)) * 8)) = kval;
      uint4 vval = *(const uint4*)(Vt + ((size_t)b * HD + h * 64 + r) * NK + k0 + c * 8);
      *(uint4*)(Vs + r * 64 + ((c ^ (r & 7)) * 8)) = vval;
    }
    __syncthreads();

    f32x4 s[4];
#pragma unroll
    for (int nn = 0; nn < 4; nn++) {
      int row = nn * 16 + fr;
      bf16x8 kf0 = *(const bf16x8*)(Ks + row * 64 + ((g ^ (fr & 7)) * 8));
      bf16x8 kf1 = *(const bf16x8*)(Ks + row * 64 + (((4 + g) ^ (fr & 7)) * 8));
      f32x4 z = {};
      z = __builtin_amdgcn_mfma_f32_16x16x32_bf16(qlo, kf0, z, 0, 0, 0);
      z = __builtin_amdgcn_mfma_f32_16x16x32_bf16(qhi, kf1, z, 0, 0, 0);
      s[nn] = z;
    }
    if (CAUSAL && (k0 + 63 > qw)) {
#pragma unroll
      for (int nn = 0; nn < 4; nn++)
#pragma unroll
        for (int i = 0; i < 4; i++)
          if (k0 + nn * 16 + fr > qw + g * 4 + i) s[nn][i] = -1e30f;
    }
#pragma unroll
    for (int i = 0; i < 4; i++) {
      float tm = fmaxf(fmaxf(s[0][i], s[1][i]), fmaxf(s[2][i], s[3][i]));
#pragma unroll
      for (int off = 8; off; off >>= 1) tm = fmaxf(tm, __shfl_xor(tm, off));
      float mnew = fmaxf(m_run[i], tm);
      float corr = __expf(m_run[i] - mnew);
      float ps = 0.f;
#pragma unroll
      for (int nn = 0; nn < 4; nn++) {
        float p = __expf(s[nn][i] - mnew);
        s[nn][i] = p;
        ps += p;
      }
#pragma unroll
      for (int off = 8; off; off >>= 1) ps += __shfl_xor(ps, off);
      l_run[i] = l_run[i] * corr + ps;
      m_run[i] = mnew;
#pragma unroll
      for (int dd = 0; dd < 4; dd++) o_acc[dd][i] *= corr;
    }
#pragma unroll
    for (int nn = 0; nn < 4; nn++)
#pragma unroll
      for (int i = 0; i < 4; i++)
        Pw[(g * 4 + i) * 72 + nn * 16 + fr] = f2bf(s[nn][i]);
    bf16x8 pa0 = *(const bf16x8*)(Pw + fr * 72 + g * 8);
    bf16x8 pa1 = *(const bf16x8*)(Pw + fr * 72 + 32 + g * 8);
#pragma unroll
    for (int dd = 0; dd < 4; dd++) {
      int row = dd * 16 + fr;
      bf16x8 vf0 = *(const bf16x8*)(Vs + row * 64 + ((g ^ (fr & 7)) * 8));
      bf16x8 vf1 = *(const bf16x8*)(Vs + row * 64 + (((4 + g) ^ (fr & 7)) * 8));
      o_acc[dd] = __builtin_amdgcn_mfma_f32_16x16x32_bf16(pa0, vf0, o_acc[dd], 0, 0, 0);
      o_acc[dd] = __builtin_amdgcn_mfma_f32_16x16x32_bf16(pa1, vf1, o_acc[dd], 0, 0, 0);
    }
  }
#pragma unroll
  for (int dd = 0; dd < 4; dd++)
#pragma unroll
    for (int i = 0; i < 4; i++) {
      size_t oidx = (size_t)(b * Tq + qw + g * 4 + i) * oStride + h * 64 + dd * 16 + fr;
      O[oidx] = f2bf(o_acc[dd][i] / l_run[i]);
    }
}

// ---------------- a * gelu(g), exact erf --------------------------------------
__global__ __launch_bounds__(256) void mulgelu(const ushort* __restrict__ F1,
    ushort* __restrict__ AG, int rows) {
  int idx = blockIdx.x * 256 + threadIdx.x;
  if (idx >= rows * FFc) return;
  int r = idx >> 11, c = idx & (FFc - 1);
  float a = bf2f(F1[(size_t)r * (2 * FFc) + c]);
  float g = bf2f(F1[(size_t)r * (2 * FFc) + FFc + c]);
  float gg = 0.5f * g * (1.f + erff(g * 0.70710678118f));
  AG[idx] = f2bf(a * gg);
}

// ---------------- orchestration ----------------------------------------------
extern "C" void kernel_launch(void* const* d_in, const int* in_sizes, int n_in,
                              void* d_out, int out_size, void* d_ws, size_t ws_size,
                              hipStream_t stream) {
  const float* bin_queries = (const float*)d_in[0];
  const float* bin_time    = (const float*)d_in[1];
  const float* latents     = (const float*)d_in[2];
  const float* lat_time    = (const float*)d_in[3];
  const float* ca_lnq_w = (const float*)d_in[4];
  const float* ca_lnq_b = (const float*)d_in[5];
  const float* ca_lnc_w = (const float*)d_in[6];
  const float* ca_lnc_b = (const float*)d_in[7];
  const float* ca_wq  = (const float*)d_in[8];
  const float* ca_wkv = (const float*)d_in[9];
  const float* ca_wo  = (const float*)d_in[10];
  const float* ca_bo  = (const float*)d_in[11];
  const float* sa_ln_w = (const float*)d_in[12];
  const float* sa_ln_b = (const float*)d_in[13];
  const float* sa_wqkv = (const float*)d_in[14];
  const float* sa_wo   = (const float*)d_in[15];
  const float* sa_bo   = (const float*)d_in[16];
  const float* ffn_ln_w = (const float*)d_in[17];
  const float* ffn_ln_b = (const float*)d_in[18];
  const float* ffn_w1 = (const float*)d_in[19];
  const float* ffn_b1 = (const float*)d_in[20];
  const float* ffn_w2 = (const float*)d_in[21];
  const float* ffn_b2 = (const float*)d_in[22];

  constexpr size_t X_BYTES = (size_t)RQ * DIMc * 4;
  char* ws = (char*)d_ws;
  float* x = (float*)ws;
  char* A0 = ws + X_BYTES;
  // cross-attn phase
  ushort* cn     = (ushort*)(A0);
  ushort* ca_xn  = (ushort*)(A0 + 16777216);
  ushort* qbuf   = (ushort*)(A0 + 25165824);
  ushort* kv     = (ushort*)(A0 + 27262976);
  ushort* ca_att = (ushort*)(A0 + 35651584);
  ushort* vt_c   = (ushort*)(A0 + 37748736);
  // self-attn phase (reuses arena)
  ushort* sa_xn  = (ushort*)(A0);
  ushort* qkv    = (ushort*)(A0 + 8388608);
  ushort* sa_att = (ushort*)(A0 + 33554432);
  ushort* vt_s   = (ushort*)(A0 + 41943040);
  // ffn phase (reuses arena)
  ushort* hb     = (ushort*)(A0);
  ushort* f1     = (ushort*)(A0 + 8388608);
  ushort* ag     = (ushort*)(A0 + 75497472);
  // bf16 transposed weights for the current layer
  char* W0 = A0 + 109051904;
  ushort* wbase = (ushort*)W0;
  ushort* wqT  = wbase;
  ushort* wkvT = wbase + 65536;
  ushort* woT  = wbase + 196608;
  ushort* qkvT = wbase + 262144;
  ushort* swoT = wbase + 1048576;
  ushort* w1T  = wbase + 1310720;
  ushort* w2T  = wbase + 3407872;

  hipMemcpyAsync(x, bin_queries, X_BYTES, hipMemcpyDeviceToDevice, stream);

  for (int l = 0; l < 2; l++) {
    wtrans_all<<<4352, 256, 0, stream>>>(ca_wq, ca_wkv, ca_wo, sa_wqkv, sa_wo,
                                         ffn_w1, ffn_w2, wbase, l);

    // ---- cross attention ----
    ln_rows<<<RQ / 4, 256, 0, stream>>>(x, ca_lnq_w + l * DIMc, ca_lnq_b + l * DIMc, ca_xn, RQ);
    ln_rows<<<RL / 4, 256, 0, stream>>>(latents, ca_lnc_w + l * DIMc, ca_lnc_b + l * DIMc, cn, RL);
    gemm64<0><<<dim3(CIc / 64, RQ / 64), 256, 0, stream>>>(ca_xn, wqT, nullptr, nullptr, qbuf, RQ, CIc, DIMc);
    gemm64<0><<<dim3(2 * CIc / 64, RL / 64), 256, 0, stream>>>(cn, wkvT, nullptr, nullptr, kv, RL, 2 * CIc, DIMc);
    rope_apply<<<(RQ * CHc * 32) / 256, 256, 0, stream>>>(qbuf, bin_time, RQ, CIc, 0, CHc, 0.125f);
    rope_apply<<<(RL * CHc * 32) / 256, 256, 0, stream>>>(kv, lat_time, RL, 2 * CIc, 0, CHc, 1.f);
    vtrans<<<dim3(Nc / 32, CHc * 64 / 32, Bc), 256, 0, stream>>>(kv, vt_c, Nc, 2 * CIc, CIc);
    attn_mfma<0><<<dim3(Tc / 64, CHc, Bc), 256, 0, stream>>>(qbuf, kv, vt_c, ca_att,
        CIc, 2 * CIc, 0, CIc, Tc, Nc, CHc);
    gemm128<1><<<dim3(DIMc / 128, RQ / 128), 256, 0, stream>>>(ca_att, woT, ca_bo + l * DIMc, x, nullptr, RQ, DIMc, CIc);

    // ---- self attention (causal) ----
    ln_rows<<<RQ / 4, 256, 0, stream>>>(x, sa_ln_w + l * DIMc, sa_ln_b + l * DIMc, sa_xn, RQ);
    gemm128<0><<<dim3(3 * SIc / 128, RQ / 128), 256, 0, stream>>>(sa_xn, qkvT, nullptr, nullptr, qkv, RQ, 3 * SIc, DIMc);
    rope_apply<<<(RQ * SHc * 32) / 256, 256, 0, stream>>>(qkv, bin_time, RQ, 3 * SIc, 0, SHc, 0.125f);
    rope_apply<<<(RQ * SHc * 32) / 256, 256, 0, stream>>>(qkv, bin_time, RQ, 3 * SIc, SIc, SHc, 1.f);
    vtrans<<<dim3(Tc / 32, SHc * 64 / 32, Bc), 256, 0, stream>>>(qkv, vt_s, Tc, 3 * SIc, 2 * SIc);
    attn_mfma<1><<<dim3(Tc / 64, SHc, Bc), 256, 0, stream>>>(qkv, qkv, vt_s, sa_att,
        3 * SIc, 3 * SIc, SIc, SIc, Tc, Tc, SHc);
    gemm128<1><<<dim3(DIMc / 128, RQ / 128), 256, 0, stream>>>(sa_att, swoT, sa_bo + l * DIMc, x, nullptr, RQ, DIMc, SIc);

    // ---- FFN ----
    ln_rows<<<RQ / 4, 256, 0, stream>>>(x, ffn_ln_w + l * DIMc, ffn_ln_b + l * DIMc, hb, RQ);
    gemm128<0><<<dim3(2 * FFc / 128, RQ / 128), 256, 0, stream>>>(hb, w1T, ffn_b1 + (size_t)l * 2 * FFc, nullptr, f1, RQ, 2 * FFc, DIMc);
    mulgelu<<<(RQ * FFc) / 256, 256, 0, stream>>>(f1, ag, RQ);
    gemm128<1><<<dim3(DIMc / 128, RQ / 128), 256, 0, stream>>>(ag, w2T, ffn_b2 + l * DIMc, x, nullptr, RQ, DIMc, FFc);
  }

  hipMemcpyAsync(d_out, x, X_BYTES, hipMemcpyDeviceToDevice, stream);
}

// Round 4
// 816.788 us; speedup vs baseline: 12.5559x; 1.0431x over previous
//
#include <hip/hip_runtime.h>
#include <cstdint>
#include <cstddef>

// ---------------- constants (match reference) ----------------
static constexpr int DIMc = 512;
static constexpr int DHc  = 64;
static constexpr int CHc  = 2;
static constexpr int SHc  = 8;
static constexpr int Bc   = 8;
static constexpr int Tc   = 1024;
static constexpr int Nc   = 2048;
static constexpr int CIc  = CHc * DHc;    // 128
static constexpr int SIc  = SHc * DHc;    // 512
static constexpr int FFc  = 4 * DIMc;     // 2048
static constexpr int RQ   = Bc * Tc;      // 8192 query rows
static constexpr int RL   = Bc * Nc;      // 16384 latent rows

typedef short bf16x8 __attribute__((ext_vector_type(8)));
typedef float f32x4  __attribute__((ext_vector_type(4)));

__device__ __forceinline__ ushort f2bf(float f) {
  uint32_t u = __builtin_bit_cast(uint32_t, f);
  u += 0x7fffu + ((u >> 16) & 1u);
  return (ushort)(u >> 16);
}
__device__ __forceinline__ float bf2f(ushort h) {
  uint32_t u = ((uint32_t)h) << 16;
  return __builtin_bit_cast(float, u);
}

__device__ __forceinline__ void gload_lds16(const ushort* g, ushort* lds) {
  __builtin_amdgcn_global_load_lds(
      (const __attribute__((address_space(1))) void*)g,
      (__attribute__((address_space(3))) void*)lds, 16, 0, 0);
}

// ---------------- LayerNorm: one wave per 512-col row, fp32 in -> bf16 out ----
__global__ __launch_bounds__(256) void ln_rows(const float* __restrict__ X,
    const float* __restrict__ w, const float* __restrict__ b,
    ushort* __restrict__ out, int rows) {
  int gw = (int)((blockIdx.x * 256 + threadIdx.x) >> 6);
  int lane = threadIdx.x & 63;
  if (gw >= rows) return;
  const float* xr = X + (size_t)gw * DIMc;
  float4 v0 = *(const float4*)(xr + lane * 8);
  float4 v1 = *(const float4*)(xr + lane * 8 + 4);
  float xv[8] = {v0.x, v0.y, v0.z, v0.w, v1.x, v1.y, v1.z, v1.w};
  float s = 0.f, ss = 0.f;
#pragma unroll
  for (int i = 0; i < 8; i++) { s += xv[i]; ss += xv[i] * xv[i]; }
#pragma unroll
  for (int off = 32; off; off >>= 1) { s += __shfl_xor(s, off); ss += __shfl_xor(ss, off); }
  float mean = s * (1.f / DIMc);
  float var = ss * (1.f / DIMc) - mean * mean;
  float r = rsqrtf(var + 1e-5f);
  int c = lane * 8;
  ushort o[8] __attribute__((aligned(16)));
#pragma unroll
  for (int i = 0; i < 8; i++) o[i] = f2bf((xv[i] - mean) * r * w[c + i] + b[c + i]);
  *(uint4*)(out + (size_t)gw * DIMc + c) = *(const uint4*)o;
}

// ------------- ALL weight transposes for one layer, one launch ----------------
// wid 5 (ffn_w1): output rows interleaved (a0,g0,a1,g1,...) for the fused
// gelu epilogue:  srcN n -> rowT = n<2048 ? 2n : 2(n-2048)+1
__global__ __launch_bounds__(256) void wtrans_all(
    const float* __restrict__ wq, const float* __restrict__ wkv,
    const float* __restrict__ wo, const float* __restrict__ qkv,
    const float* __restrict__ swo, const float* __restrict__ w1,
    const float* __restrict__ w2, ushort* __restrict__ dst, int layer) {
  constexpr int Ks[7]   = {512, 512, 128, 512, 512, 512, 2048};
  constexpr int Ns[7]   = {128, 256, 512, 1536, 512, 4096, 512};
  constexpr int pre[8]  = {0, 64, 192, 256, 1024, 1280, 3328, 4352};
  constexpr int dOff[7] = {0, 65536, 196608, 262144, 1048576, 1310720, 3407872};
  int bid = blockIdx.x;
  int wid = 0;
#pragma unroll
  for (int i = 1; i < 7; i++) wid += (bid >= pre[i]);
  int tileIdx = bid - pre[wid];
  int K = Ks[wid], N = Ns[wid];
  const float* srcs[7] = {wq, wkv, wo, qkv, swo, w1, w2};
  const float* W = srcs[wid] + (size_t)layer * K * N;
  ushort* Wt = dst + dOff[wid];
  int ntx = N / 32;
  int n0 = (tileIdx % ntx) * 32, k0 = (tileIdx / ntx) * 32;
  __shared__ float tile[32][33];
  int tx = threadIdx.x & 31, ty = threadIdx.x >> 5;
#pragma unroll
  for (int i = 0; i < 32; i += 8)
    tile[ty + i][tx] = W[(size_t)(k0 + ty + i) * N + n0 + tx];
  __syncthreads();
  if (wid == 5) {
#pragma unroll
    for (int i = 0; i < 32; i += 8) {
      int nrow = n0 + ty + i;
      int rowT = (nrow < 2048) ? (nrow * 2) : ((nrow - 2048) * 2 + 1);
      Wt[(size_t)rowT * K + k0 + tx] = f2bf(tile[tx][ty + i]);
    }
  } else {
#pragma unroll
    for (int i = 0; i < 32; i += 8)
      Wt[(size_t)(n0 + ty + i) * K + k0 + tx] = f2bf(tile[tx][ty + i]);
  }
}

// ---------------- bf16 V transpose: dst[b][hd][key] --------------------------
__global__ __launch_bounds__(256) void vtrans(const ushort* __restrict__ src,
    ushort* __restrict__ dst, int NK, int stride, int colOff) {
  __shared__ ushort tile[32][33];
  int b = blockIdx.z;
  int key0 = blockIdx.x * 32, hd0 = blockIdx.y * 32;
  int HD = gridDim.y * 32;
  int tx = threadIdx.x & 31, ty = threadIdx.x >> 5;
#pragma unroll
  for (int i = 0; i < 32; i += 8)
    tile[ty + i][tx] = src[(size_t)(b * NK + key0 + ty + i) * stride + colOff + hd0 + tx];
  __syncthreads();
#pragma unroll
  for (int i = 0; i < 32; i += 8)
    dst[((size_t)b * HD + hd0 + ty + i) * NK + key0 + tx] = tile[tx][ty + i];
}

// ------------- 128x128 GEMM, BK=64, 2-phase dbuf global_load_lds, swizzled ---
// A: M x K bf16 row-major.  Bt: N x K bf16 row-major.
// LDS: row stride 64 bf16; 16B chunk at slot s of row r holds k-chunk s^(r&7).
// MODE 0: outB = bf16(acc + bias)
// MODE 1: resOut = resIn + acc + bias   (fp32)
// MODE 2: fused FFN gate: Bt rows interleaved (a,g); even-fr lanes write
//         bf16( a * 0.5*g*(1+erf(g/sqrt2)) ) to outB with row stride N/2.
template<int MODE>
__global__ __launch_bounds__(256) void gemm128(const ushort* __restrict__ A,
    const ushort* __restrict__ Bt, const float* __restrict__ bias,
    const float* __restrict__ resIn, float* __restrict__ resOut,
    ushort* __restrict__ outB, int M, int N, int K) {
  __shared__ __align__(16) ushort As[2][128 * 64];
  __shared__ __align__(16) ushort Bs[2][128 * 64];
  int t = threadIdx.x, wv = t >> 6, lane = t & 63;
  int bm = blockIdx.y, bn = blockIdx.x;
  int fr = lane & 15, g = lane >> 4;
  int wr = (wv >> 1) * 64, wc = (wv & 1) * 64;
  int srow = wv * 32 + (lane >> 3);
  int sslot = lane & 7;
  const ushort* Abase = A + (size_t)(bm * 128) * K;
  const ushort* Bbase = Bt + (size_t)(bn * 128) * K;

  f32x4 acc[4][4] = {};
  int nt = K >> 6;

#define STAGE(buf, k0)                                                        \
  {                                                                           \
    _Pragma("unroll")                                                         \
    for (int j = 0; j < 4; j++) {                                             \
      int r = srow + j * 8;                                                   \
      int kc = sslot ^ (r & 7);                                               \
      gload_lds16(Abase + (size_t)r * K + (k0) + kc * 8,                      \
                  &As[buf][(wv * 256 + j * 64) * 8]);                         \
      gload_lds16(Bbase + (size_t)r * K + (k0) + kc * 8,                      \
                  &Bs[buf][(wv * 256 + j * 64) * 8]);                         \
    }                                                                         \
  }

  STAGE(0, 0);
  __syncthreads();
  for (int tt = 0; tt < nt; tt++) {
    int cur = tt & 1;
    if (tt + 1 < nt) STAGE(cur ^ 1, (tt + 1) * 64);
    const ushort* Ac = As[cur];
    const ushort* Bc = Bs[cur];
#pragma unroll
    for (int ks = 0; ks < 2; ks++) {
      bf16x8 af[4], bf[4];
#pragma unroll
      for (int mm = 0; mm < 4; mm++) {
        int row = wr + mm * 16 + fr;
        af[mm] = *(const bf16x8*)(Ac + row * 64 + (((ks * 4 + g) ^ (row & 7)) * 8));
      }
#pragma unroll
      for (int nn = 0; nn < 4; nn++) {
        int row = wc + nn * 16 + fr;
        bf[nn] = *(const bf16x8*)(Bc + row * 64 + (((ks * 4 + g) ^ (row & 7)) * 8));
      }
#pragma unroll
      for (int mm = 0; mm < 4; mm++)
#pragma unroll
        for (int nn = 0; nn < 4; nn++)
          acc[mm][nn] = __builtin_amdgcn_mfma_f32_16x16x32_bf16(af[mm], bf[nn], acc[mm][nn], 0, 0, 0);
    }
    __syncthreads();   // drains this iter's STAGE (vmcnt0) + protects overwrite
  }
#undef STAGE

  int NH = N >> 1;
#pragma unroll
  for (int mm = 0; mm < 4; mm++)
#pragma unroll
    for (int nn = 0; nn < 4; nn++)
#pragma unroll
      for (int i = 0; i < 4; i++) {
        int gr = bm * 128 + wr + mm * 16 + g * 4 + i;
        int gc = bn * 128 + wc + nn * 16 + fr;
        if (MODE == 2) {
          // bias index back to original (non-interleaved) b1 layout
          float v = acc[mm][nn][i] + bias[(gc & 1) ? (NH + (gc >> 1)) : (gc >> 1)];
          float gv = __shfl_down(v, 1);
          if (!(fr & 1)) {
            float res = v * 0.5f * gv * (1.f + erff(gv * 0.70710678f));
            outB[(size_t)gr * NH + (gc >> 1)] = f2bf(res);
          }
        } else {
          float val = acc[mm][nn][i] + (bias ? bias[gc] : 0.f);
          if (MODE == 0) outB[(size_t)gr * N + gc] = f2bf(val);
          else resOut[(size_t)gr * N + gc] = resIn[(size_t)gr * N + gc] + val;
        }
      }
}

// ---------------- bf16 MFMA GEMM, 64x64 tile (small-N shapes) ----------------
template<int MODE>
__global__ __launch_bounds__(256) void gemm64(const ushort* __restrict__ A,
    const ushort* __restrict__ Bt, const float* __restrict__ bias,
    float* __restrict__ resF, ushort* __restrict__ outB,
    int M, int N, int K) {
  __shared__ __align__(16) ushort As[64][40];
  __shared__ __align__(16) ushort Bs[64][40];
  int t = threadIdx.x;
  int bm = blockIdx.y, bn = blockIdx.x;
  int row = t >> 2, kc = (t & 3) << 3;
  const ushort* aG = A + (size_t)(bm * 64 + row) * K + kc;
  const ushort* bG = Bt + (size_t)(bn * 64 + row) * K + kc;
  int wv = t >> 6, lane = t & 63;
  int wr = (wv >> 1) * 32, wc = (wv & 1) * 32;
  int fr = lane & 15, fk = (lane >> 4) << 3;
  f32x4 acc[2][2] = {};
  for (int k0 = 0; k0 < K; k0 += 32) {
    *(uint4*)&As[row][kc] = *(const uint4*)(aG + k0);
    *(uint4*)&Bs[row][kc] = *(const uint4*)(bG + k0);
    __syncthreads();
    bf16x8 a0 = *(const bf16x8*)&As[wr + fr][fk];
    bf16x8 a1 = *(const bf16x8*)&As[wr + 16 + fr][fk];
    bf16x8 b0 = *(const bf16x8*)&Bs[wc + fr][fk];
    bf16x8 b1 = *(const bf16x8*)&Bs[wc + 16 + fr][fk];
    acc[0][0] = __builtin_amdgcn_mfma_f32_16x16x32_bf16(a0, b0, acc[0][0], 0, 0, 0);
    acc[0][1] = __builtin_amdgcn_mfma_f32_16x16x32_bf16(a0, b1, acc[0][1], 0, 0, 0);
    acc[1][0] = __builtin_amdgcn_mfma_f32_16x16x32_bf16(a1, b0, acc[1][0], 0, 0, 0);
    acc[1][1] = __builtin_amdgcn_mfma_f32_16x16x32_bf16(a1, b1, acc[1][1], 0, 0, 0);
    __syncthreads();
  }
  int cr0 = wr + ((lane >> 4) << 2);
  int cc0 = wc + fr;
#pragma unroll
  for (int mm = 0; mm < 2; mm++)
#pragma unroll
    for (int nn = 0; nn < 2; nn++)
#pragma unroll
      for (int i = 0; i < 4; i++) {
        int gr = bm * 64 + cr0 + mm * 16 + i;
        int gc = bn * 64 + cc0 + nn * 16;
        float val = acc[mm][nn][i] + (bias ? bias[gc] : 0.f);
        if (MODE == 0) outB[(size_t)gr * N + gc] = f2bf(val);
        else resF[(size_t)gr * N + gc] = resF[(size_t)gr * N + gc] + val;
      }
}

// ---------------- elementwise rotary (in place on bf16 buffer) ---------------
__global__ __launch_bounds__(256) void rope_apply(ushort* __restrict__ buf,
    const float* __restrict__ fr, int rows, int stride, int colOff, int H, float scale) {
  int idx = blockIdx.x * 256 + threadIdx.x;
  int total = rows * H * 32;
  if (idx >= total) return;
  int p = idx & 31;
  int h = (idx >> 5) % H;
  int r = idx / (32 * H);
  float f0 = fr[(size_t)r * DHc + 2 * p];
  float f1 = fr[(size_t)r * DHc + 2 * p + 1];
  ushort* bp = buf + (size_t)r * stride + colOff + h * DHc + 2 * p;
  float x0 = bf2f(bp[0]), x1 = bf2f(bp[1]);
  float o0 = (x0 * __cosf(f0) - x1 * __sinf(f0)) * scale;
  float o1 = (x1 * __cosf(f1) + x0 * __sinf(f1)) * scale;
  bp[0] = f2bf(o0); bp[1] = f2bf(o1);
}

// ---------------- MFMA flash attention ---------------------------------------
template<int CAUSAL>
__global__ __launch_bounds__(256) void attn_mfma(
    const ushort* __restrict__ Q, const ushort* __restrict__ K,
    const ushort* __restrict__ Vt, ushort* __restrict__ O,
    int qStride, int kStride, int kOff, int oStride,
    int Tq, int NK, int H) {
  __shared__ __align__(16) ushort Ks[64 * 64];
  __shared__ __align__(16) ushort Vs[64 * 64];
  __shared__ __align__(16) ushort Ps[4][16 * 72];
  int b = blockIdx.z, h = blockIdx.y, qt = blockIdx.x;
  int t = threadIdx.x, wv = t >> 6, lane = t & 63;
  int g = lane >> 4, fr = lane & 15;
  int qw = qt * 64 + wv * 16;
  int HD = H * 64;

  const ushort* qrow = Q + (size_t)(b * Tq + qw + fr) * qStride + h * 64;
  bf16x8 qlo = *(const bf16x8*)(qrow + g * 8);
  bf16x8 qhi = *(const bf16x8*)(qrow + 32 + g * 8);

  f32x4 o_acc[4] = {};
  float m_run[4], l_run[4];
#pragma unroll
  for (int i = 0; i < 4; i++) { m_run[i] = -1e30f; l_run[i] = 0.f; }

  ushort* Pw = &Ps[wv][0];
  int ntiles = CAUSAL ? (qt + 1) : (NK / 64);
  for (int kt = 0; kt < ntiles; kt++) {
    int k0 = kt * 64;
    __syncthreads();
#pragma unroll
    for (int i = 0; i < 2; i++) {
      int id = t + i * 256;
      int r = id >> 3, c = id & 7;
      uint4 kval = *(const uint4*)(K + (size_t)(b * NK + k0 + r) * kStride + kOff + h * 64 + c * 8);
      *(uint4*)(Ks + r * 64 + ((c ^ (r & 7)) * 8)) = kval;
      uint4 vval = *(const uint4*)(Vt + ((size_t)b * HD + h * 64 + r) * NK + k0 + c * 8);
      *(uint4*)(Vs + r * 64 + ((c ^ (r & 7)) * 8)) = vval;
    }
    __syncthreads();

    f32x4 s[4];
#pragma unroll
    for (int nn = 0; nn < 4; nn++) {
      int row = nn * 16 + fr;
      bf16x8 kf0 = *(const bf16x8*)(Ks + row * 64 + ((g ^ (fr & 7)) * 8));
      bf16x8 kf1 = *(const bf16x8*)(Ks + row * 64 + (((4 + g) ^ (fr & 7)) * 8));
      f32x4 z = {};
      z = __builtin_amdgcn_mfma_f32_16x16x32_bf16(qlo, kf0, z, 0, 0, 0);
      z = __builtin_amdgcn_mfma_f32_16x16x32_bf16(qhi, kf1, z, 0, 0, 0);
      s[nn] = z;
    }
    if (CAUSAL && (k0 + 63 > qw)) {
#pragma unroll
      for (int nn = 0; nn < 4; nn++)
#pragma unroll
        for (int i = 0; i < 4; i++)
          if (k0 + nn * 16 + fr > qw + g * 4 + i) s[nn][i] = -1e30f;
    }
#pragma unroll
    for (int i = 0; i < 4; i++) {
      float tm = fmaxf(fmaxf(s[0][i], s[1][i]), fmaxf(s[2][i], s[3][i]));
#pragma unroll
      for (int off = 8; off; off >>= 1) tm = fmaxf(tm, __shfl_xor(tm, off));
      float mnew = fmaxf(m_run[i], tm);
      float corr = __expf(m_run[i] - mnew);
      float ps = 0.f;
#pragma unroll
      for (int nn = 0; nn < 4; nn++) {
        float p = __expf(s[nn][i] - mnew);
        s[nn][i] = p;
        ps += p;
      }
#pragma unroll
      for (int off = 8; off; off >>= 1) ps += __shfl_xor(ps, off);
      l_run[i] = l_run[i] * corr + ps;
      m_run[i] = mnew;
#pragma unroll
      for (int dd = 0; dd < 4; dd++) o_acc[dd][i] *= corr;
    }
#pragma unroll
    for (int nn = 0; nn < 4; nn++)
#pragma unroll
      for (int i = 0; i < 4; i++)
        Pw[(g * 4 + i) * 72 + nn * 16 + fr] = f2bf(s[nn][i]);
    bf16x8 pa0 = *(const bf16x8*)(Pw + fr * 72 + g * 8);
    bf16x8 pa1 = *(const bf16x8*)(Pw + fr * 72 + 32 + g * 8);
#pragma unroll
    for (int dd = 0; dd < 4; dd++) {
      int row = dd * 16 + fr;
      bf16x8 vf0 = *(const bf16x8*)(Vs + row * 64 + ((g ^ (fr & 7)) * 8));
      bf16x8 vf1 = *(const bf16x8*)(Vs + row * 64 + (((4 + g) ^ (fr & 7)) * 8));
      o_acc[dd] = __builtin_amdgcn_mfma_f32_16x16x32_bf16(pa0, vf0, o_acc[dd], 0, 0, 0);
      o_acc[dd] = __builtin_amdgcn_mfma_f32_16x16x32_bf16(pa1, vf1, o_acc[dd], 0, 0, 0);
    }
  }
#pragma unroll
  for (int dd = 0; dd < 4; dd++)
#pragma unroll
    for (int i = 0; i < 4; i++) {
      size_t oidx = (size_t)(b * Tq + qw + g * 4 + i) * oStride + h * 64 + dd * 16 + fr;
      O[oidx] = f2bf(o_acc[dd][i] / l_run[i]);
    }
}

// ---------------- orchestration ----------------------------------------------
extern "C" void kernel_launch(void* const* d_in, const int* in_sizes, int n_in,
                              void* d_out, int out_size, void* d_ws, size_t ws_size,
                              hipStream_t stream) {
  const float* bin_queries = (const float*)d_in[0];
  const float* bin_time    = (const float*)d_in[1];
  const float* latents     = (const float*)d_in[2];
  const float* lat_time    = (const float*)d_in[3];
  const float* ca_lnq_w = (const float*)d_in[4];
  const float* ca_lnq_b = (const float*)d_in[5];
  const float* ca_lnc_w = (const float*)d_in[6];
  const float* ca_lnc_b = (const float*)d_in[7];
  const float* ca_wq  = (const float*)d_in[8];
  const float* ca_wkv = (const float*)d_in[9];
  const float* ca_wo  = (const float*)d_in[10];
  const float* ca_bo  = (const float*)d_in[11];
  const float* sa_ln_w = (const float*)d_in[12];
  const float* sa_ln_b = (const float*)d_in[13];
  const float* sa_wqkv = (const float*)d_in[14];
  const float* sa_wo   = (const float*)d_in[15];
  const float* sa_bo   = (const float*)d_in[16];
  const float* ffn_ln_w = (const float*)d_in[17];
  const float* ffn_ln_b = (const float*)d_in[18];
  const float* ffn_w1 = (const float*)d_in[19];
  const float* ffn_b1 = (const float*)d_in[20];
  const float* ffn_w2 = (const float*)d_in[21];
  const float* ffn_b2 = (const float*)d_in[22];

  constexpr size_t X_BYTES = (size_t)RQ * DIMc * 4;
  char* ws = (char*)d_ws;
  float* x = (float*)ws;
  char* A0 = ws + X_BYTES;
  // cross-attn phase
  ushort* cn     = (ushort*)(A0);
  ushort* ca_xn  = (ushort*)(A0 + 16777216);
  ushort* qbuf   = (ushort*)(A0 + 25165824);
  ushort* kv     = (ushort*)(A0 + 27262976);
  ushort* ca_att = (ushort*)(A0 + 35651584);
  ushort* vt_c   = (ushort*)(A0 + 37748736);
  // self-attn phase (reuses arena)
  ushort* sa_xn  = (ushort*)(A0);
  ushort* qkv    = (ushort*)(A0 + 8388608);
  ushort* sa_att = (ushort*)(A0 + 33554432);
  ushort* vt_s   = (ushort*)(A0 + 41943040);
  // ffn phase (reuses arena)
  ushort* hb     = (ushort*)(A0);
  ushort* ag     = (ushort*)(A0 + 8388608);   // 32 MB (fused gelu output)
  // bf16 transposed weights for the current layer
  char* W0 = A0 + 109051904;
  ushort* wbase = (ushort*)W0;
  ushort* wqT  = wbase;
  ushort* wkvT = wbase + 65536;
  ushort* woT  = wbase + 196608;
  ushort* qkvT = wbase + 262144;
  ushort* swoT = wbase + 1048576;
  ushort* w1T  = wbase + 1310720;
  ushort* w2T  = wbase + 3407872;

  hipMemcpyAsync(x, bin_queries, X_BYTES, hipMemcpyDeviceToDevice, stream);

  for (int l = 0; l < 2; l++) {
    wtrans_all<<<4352, 256, 0, stream>>>(ca_wq, ca_wkv, ca_wo, sa_wqkv, sa_wo,
                                         ffn_w1, ffn_w2, wbase, l);

    // ---- cross attention ----
    ln_rows<<<RQ / 4, 256, 0, stream>>>(x, ca_lnq_w + l * DIMc, ca_lnq_b + l * DIMc, ca_xn, RQ);
    ln_rows<<<RL / 4, 256, 0, stream>>>(latents, ca_lnc_w + l * DIMc, ca_lnc_b + l * DIMc, cn, RL);
    gemm64<0><<<dim3(CIc / 64, RQ / 64), 256, 0, stream>>>(ca_xn, wqT, nullptr, nullptr, qbuf, RQ, CIc, DIMc);
    gemm64<0><<<dim3(2 * CIc / 64, RL / 64), 256, 0, stream>>>(cn, wkvT, nullptr, nullptr, kv, RL, 2 * CIc, DIMc);
    rope_apply<<<(RQ * CHc * 32) / 256, 256, 0, stream>>>(qbuf, bin_time, RQ, CIc, 0, CHc, 0.125f);
    rope_apply<<<(RL * CHc * 32) / 256, 256, 0, stream>>>(kv, lat_time, RL, 2 * CIc, 0, CHc, 1.f);
    vtrans<<<dim3(Nc / 32, CHc * 64 / 32, Bc), 256, 0, stream>>>(kv, vt_c, Nc, 2 * CIc, CIc);
    attn_mfma<0><<<dim3(Tc / 64, CHc, Bc), 256, 0, stream>>>(qbuf, kv, vt_c, ca_att,
        CIc, 2 * CIc, 0, CIc, Tc, Nc, CHc);
    gemm128<1><<<dim3(DIMc / 128, RQ / 128), 256, 0, stream>>>(ca_att, woT, ca_bo + l * DIMc,
        x, x, nullptr, RQ, DIMc, CIc);

    // ---- self attention (causal) ----
    ln_rows<<<RQ / 4, 256, 0, stream>>>(x, sa_ln_w + l * DIMc, sa_ln_b + l * DIMc, sa_xn, RQ);
    gemm128<0><<<dim3(3 * SIc / 128, RQ / 128), 256, 0, stream>>>(sa_xn, qkvT, nullptr,
        nullptr, nullptr, qkv, RQ, 3 * SIc, DIMc);
    rope_apply<<<(RQ * SHc * 32) / 256, 256, 0, stream>>>(qkv, bin_time, RQ, 3 * SIc, 0, SHc, 0.125f);
    rope_apply<<<(RQ * SHc * 32) / 256, 256, 0, stream>>>(qkv, bin_time, RQ, 3 * SIc, SIc, SHc, 1.f);
    vtrans<<<dim3(Tc / 32, SHc * 64 / 32, Bc), 256, 0, stream>>>(qkv, vt_s, Tc, 3 * SIc, 2 * SIc);
    attn_mfma<1><<<dim3(Tc / 64, SHc, Bc), 256, 0, stream>>>(qkv, qkv, vt_s, sa_att,
        3 * SIc, 3 * SIc, SIc, SIc, Tc, Tc, SHc);
    gemm128<1><<<dim3(DIMc / 128, RQ / 128), 256, 0, stream>>>(sa_att, swoT, sa_bo + l * DIMc,
        x, x, nullptr, RQ, DIMc, SIc);

    // ---- FFN (w1 with fused bias + a*gelu(g) epilogue) ----
    ln_rows<<<RQ / 4, 256, 0, stream>>>(x, ffn_ln_w + l * DIMc, ffn_ln_b + l * DIMc, hb, RQ);
    gemm128<2><<<dim3(2 * FFc / 128, RQ / 128), 256, 0, stream>>>(hb, w1T,
        ffn_b1 + (size_t)l * 2 * FFc, nullptr, nullptr, ag, RQ, 2 * FFc, DIMc);
    float* resOut = (l == 1) ? (float*)d_out : x;
    gemm128<1><<<dim3(DIMc / 128, RQ / 128), 256, 0, stream>>>(ag, w2T, ffn_b2 + l * DIMc,
        x, resOut, nullptr, RQ, DIMc, FFc);
  }
}

// Round 5
// 798.480 us; speedup vs baseline: 12.8438x; 1.0229x over previous
//
#include <hip/hip_runtime.h>
#include <cstdint>
#include <cstddef>

// ---------------- constants (match reference) ----------------
static constexpr int DIMc = 512;
static constexpr int DHc  = 64;
static constexpr int CHc  = 2;
static constexpr int SHc  = 8;
static constexpr int Bc   = 8;
static constexpr int Tc   = 1024;
static constexpr int Nc   = 2048;
static constexpr int CIc  = CHc * DHc;    // 128
static constexpr int SIc  = SHc * DHc;    // 512
static constexpr int FFc  = 4 * DIMc;     // 2048
static constexpr int RQ   = Bc * Tc;      // 8192 query rows
static constexpr int RL   = Bc * Nc;      // 16384 latent rows

typedef short bf16x8 __attribute__((ext_vector_type(8)));
typedef float f32x4  __attribute__((ext_vector_type(4)));

__device__ __forceinline__ ushort f2bf(float f) {
  uint32_t u = __builtin_bit_cast(uint32_t, f);
  u += 0x7fffu + ((u >> 16) & 1u);
  return (ushort)(u >> 16);
}
__device__ __forceinline__ float bf2f(ushort h) {
  uint32_t u = ((uint32_t)h) << 16;
  return __builtin_bit_cast(float, u);
}

__device__ __forceinline__ void gload_lds16(const ushort* g, ushort* lds) {
  __builtin_amdgcn_global_load_lds(
      (const __attribute__((address_space(1))) void*)g,
      (__attribute__((address_space(3))) void*)lds, 16, 0, 0);
}

// asm ds_read_b128: invisible to compiler's vmcnt/lgkm tracking -> no
// compiler-inserted vmcnt(0) serialization against in-flight global_load_lds.
__device__ __forceinline__ bf16x8 ds_read8(const ushort* p) {
  bf16x8 d;
  asm volatile("ds_read_b128 %0, %1"
               : "=v"(d)
               : "v"((const __attribute__((address_space(3))) ushort*)p));
  return d;
}

// ---------------- LayerNorm: one wave per 512-col row, fp32 in -> bf16 out ----
__global__ __launch_bounds__(256) void ln_rows(const float* __restrict__ X,
    const float* __restrict__ w, const float* __restrict__ b,
    ushort* __restrict__ out, int rows) {
  int gw = (int)((blockIdx.x * 256 + threadIdx.x) >> 6);
  int lane = threadIdx.x & 63;
  if (gw >= rows) return;
  const float* xr = X + (size_t)gw * DIMc;
  float4 v0 = *(const float4*)(xr + lane * 8);
  float4 v1 = *(const float4*)(xr + lane * 8 + 4);
  float xv[8] = {v0.x, v0.y, v0.z, v0.w, v1.x, v1.y, v1.z, v1.w};
  float s = 0.f, ss = 0.f;
#pragma unroll
  for (int i = 0; i < 8; i++) { s += xv[i]; ss += xv[i] * xv[i]; }
#pragma unroll
  for (int off = 32; off; off >>= 1) { s += __shfl_xor(s, off); ss += __shfl_xor(ss, off); }
  float mean = s * (1.f / DIMc);
  float var = ss * (1.f / DIMc) - mean * mean;
  float r = rsqrtf(var + 1e-5f);
  int c = lane * 8;
  ushort o[8] __attribute__((aligned(16)));
#pragma unroll
  for (int i = 0; i < 8; i++) o[i] = f2bf((xv[i] - mean) * r * w[c + i] + b[c + i]);
  *(uint4*)(out + (size_t)gw * DIMc + c) = *(const uint4*)o;
}

// ------------- ALL weight transposes for one layer, one launch ----------------
// wid 5 (ffn_w1): output rows interleaved (a0,g0,a1,g1,...) for the fused
// gelu epilogue:  srcN n -> rowT = n<2048 ? 2n : 2(n-2048)+1
__global__ __launch_bounds__(256) void wtrans_all(
    const float* __restrict__ wq, const float* __restrict__ wkv,
    const float* __restrict__ wo, const float* __restrict__ qkv,
    const float* __restrict__ swo, const float* __restrict__ w1,
    const float* __restrict__ w2, ushort* __restrict__ dst, int layer) {
  constexpr int Ks[7]   = {512, 512, 128, 512, 512, 512, 2048};
  constexpr int Ns[7]   = {128, 256, 512, 1536, 512, 4096, 512};
  constexpr int pre[8]  = {0, 64, 192, 256, 1024, 1280, 3328, 4352};
  constexpr int dOff[7] = {0, 65536, 196608, 262144, 1048576, 1310720, 3407872};
  int bid = blockIdx.x;
  int wid = 0;
#pragma unroll
  for (int i = 1; i < 7; i++) wid += (bid >= pre[i]);
  int tileIdx = bid - pre[wid];
  int K = Ks[wid], N = Ns[wid];
  const float* srcs[7] = {wq, wkv, wo, qkv, swo, w1, w2};
  const float* W = srcs[wid] + (size_t)layer * K * N;
  ushort* Wt = dst + dOff[wid];
  int ntx = N / 32;
  int n0 = (tileIdx % ntx) * 32, k0 = (tileIdx / ntx) * 32;
  __shared__ float tile[32][33];
  int tx = threadIdx.x & 31, ty = threadIdx.x >> 5;
#pragma unroll
  for (int i = 0; i < 32; i += 8)
    tile[ty + i][tx] = W[(size_t)(k0 + ty + i) * N + n0 + tx];
  __syncthreads();
  if (wid == 5) {
#pragma unroll
    for (int i = 0; i < 32; i += 8) {
      int nrow = n0 + ty + i;
      int rowT = (nrow < 2048) ? (nrow * 2) : ((nrow - 2048) * 2 + 1);
      Wt[(size_t)rowT * K + k0 + tx] = f2bf(tile[tx][ty + i]);
    }
  } else {
#pragma unroll
    for (int i = 0; i < 32; i += 8)
      Wt[(size_t)(n0 + ty + i) * K + k0 + tx] = f2bf(tile[tx][ty + i]);
  }
}

// ---------------- bf16 V transpose: dst[b][hd][key] --------------------------
__global__ __launch_bounds__(256) void vtrans(const ushort* __restrict__ src,
    ushort* __restrict__ dst, int NK, int stride, int colOff) {
  __shared__ ushort tile[32][33];
  int b = blockIdx.z;
  int key0 = blockIdx.x * 32, hd0 = blockIdx.y * 32;
  int HD = gridDim.y * 32;
  int tx = threadIdx.x & 31, ty = threadIdx.x >> 5;
#pragma unroll
  for (int i = 0; i < 32; i += 8)
    tile[ty + i][tx] = src[(size_t)(b * NK + key0 + ty + i) * stride + colOff + hd0 + tx];
  __syncthreads();
#pragma unroll
  for (int i = 0; i < 32; i += 8)
    dst[((size_t)b * HD + hd0 + ty + i) * NK + key0 + tx] = tile[tx][ty + i];
}

// ------- 128x128 GEMM, BK=64, asm-controlled 2-phase dbuf (T3-minimum) -------
// A: M x K bf16 row-major.  Bt: N x K bf16 row-major.
// LDS: row stride 64 bf16; 16B chunk at slot s of row r holds k-chunk s^(r&7).
// Pipeline per K-step: STAGE(next) || asm ds_read(cur) -> lgkmcnt(0) ->
// MFMA -> vmcnt(0)+s_barrier.  Compiler never sees the ds_reads, so the
// prefetch stays in flight across the compute phase.
// MODE 0: outB = bf16(acc + bias)
// MODE 1: resOut = resIn + acc + bias   (fp32)
// MODE 2: fused FFN gate (Bt rows interleaved a,g): even lanes write
//         bf16( a * 0.5*g*(1+erf(g/sqrt2)) ), row stride N/2.
template<int MODE>
__global__ __launch_bounds__(256) void gemm128(const ushort* __restrict__ A,
    const ushort* __restrict__ Bt, const float* __restrict__ bias,
    const float* __restrict__ resIn, float* __restrict__ resOut,
    ushort* __restrict__ outB, int M, int N, int K) {
  __shared__ __align__(16) ushort As[2][128 * 64];
  __shared__ __align__(16) ushort Bs[2][128 * 64];
  int t = threadIdx.x, wv = t >> 6, lane = t & 63;
  int bm = blockIdx.y, bn = blockIdx.x;
  int fr = lane & 15, g = lane >> 4;
  int wr = (wv >> 1) * 64, wc = (wv & 1) * 64;
  int srow = wv * 32 + (lane >> 3);
  int sslot = lane & 7;
  const ushort* Abase = A + (size_t)(bm * 128) * K;
  const ushort* Bbase = Bt + (size_t)(bn * 128) * K;

  f32x4 acc[4][4] = {};
  int nt = K >> 6;

#define STAGE(buf, k0)                                                        \
  {                                                                           \
    _Pragma("unroll")                                                         \
    for (int j = 0; j < 4; j++) {                                             \
      int r = srow + j * 8;                                                   \
      int kc = sslot ^ (r & 7);                                               \
      gload_lds16(Abase + (size_t)r * K + (k0) + kc * 8,                      \
                  &As[buf][(wv * 256 + j * 64) * 8]);                         \
      gload_lds16(Bbase + (size_t)r * K + (k0) + kc * 8,                      \
                  &Bs[buf][(wv * 256 + j * 64) * 8]);                         \
    }                                                                         \
  }

  STAGE(0, 0);
  __builtin_amdgcn_sched_barrier(0);
  asm volatile("s_waitcnt vmcnt(0)\n\ts_barrier" ::: "memory");
  __builtin_amdgcn_sched_barrier(0);

  for (int tt = 0; tt < nt; tt++) {
    int cur = tt & 1;
    if (tt + 1 < nt) STAGE(cur ^ 1, (tt + 1) * 64);
    __builtin_amdgcn_sched_barrier(0);
    const ushort* Ac = As[cur];
    const ushort* Bc = Bs[cur];
    bf16x8 af[2][4], bfr[2][4];
#pragma unroll
    for (int ks = 0; ks < 2; ks++)
#pragma unroll
      for (int mm = 0; mm < 4; mm++) {
        int rowa = wr + mm * 16 + fr;
        af[ks][mm] = ds_read8(Ac + rowa * 64 + (((ks * 4 + g) ^ (rowa & 7)) * 8));
        int rowb = wc + mm * 16 + fr;
        bfr[ks][mm] = ds_read8(Bc + rowb * 64 + (((ks * 4 + g) ^ (rowb & 7)) * 8));
      }
    asm volatile("s_waitcnt lgkmcnt(0)" ::: "memory");
    __builtin_amdgcn_sched_barrier(0);
#pragma unroll
    for (int ks = 0; ks < 2; ks++)
#pragma unroll
      for (int mm = 0; mm < 4; mm++)
#pragma unroll
        for (int nn = 0; nn < 4; nn++)
          acc[mm][nn] = __builtin_amdgcn_mfma_f32_16x16x32_bf16(af[ks][mm], bfr[ks][nn], acc[mm][nn], 0, 0, 0);
    __builtin_amdgcn_sched_barrier(0);
    asm volatile("s_waitcnt vmcnt(0)\n\ts_barrier" ::: "memory");
    __builtin_amdgcn_sched_barrier(0);
  }
#undef STAGE

  int NH = N >> 1;
#pragma unroll
  for (int mm = 0; mm < 4; mm++)
#pragma unroll
    for (int nn = 0; nn < 4; nn++)
#pragma unroll
      for (int i = 0; i < 4; i++) {
        int gr = bm * 128 + wr + mm * 16 + g * 4 + i;
        int gc = bn * 128 + wc + nn * 16 + fr;
        if (MODE == 2) {
          float v = acc[mm][nn][i] + bias[(gc & 1) ? (NH + (gc >> 1)) : (gc >> 1)];
          float gv = __shfl_down(v, 1);
          if (!(fr & 1)) {
            float res = v * 0.5f * gv * (1.f + erff(gv * 0.70710678f));
            outB[(size_t)gr * NH + (gc >> 1)] = f2bf(res);
          }
        } else {
          float val = acc[mm][nn][i] + (bias ? bias[gc] : 0.f);
          if (MODE == 0) outB[(size_t)gr * N + gc] = f2bf(val);
          else resOut[(size_t)gr * N + gc] = resIn[(size_t)gr * N + gc] + val;
        }
      }
}

// ---------------- bf16 MFMA GEMM, 64x64 tile (small-N shapes) ----------------
template<int MODE>
__global__ __launch_bounds__(256) void gemm64(const ushort* __restrict__ A,
    const ushort* __restrict__ Bt, const float* __restrict__ bias,
    float* __restrict__ resF, ushort* __restrict__ outB,
    int M, int N, int K) {
  __shared__ __align__(16) ushort As[64][40];
  __shared__ __align__(16) ushort Bs[64][40];
  int t = threadIdx.x;
  int bm = blockIdx.y, bn = blockIdx.x;
  int row = t >> 2, kc = (t & 3) << 3;
  const ushort* aG = A + (size_t)(bm * 64 + row) * K + kc;
  const ushort* bG = Bt + (size_t)(bn * 64 + row) * K + kc;
  int wv = t >> 6, lane = t & 63;
  int wr = (wv >> 1) * 32, wc = (wv & 1) * 32;
  int fr = lane & 15, fk = (lane >> 4) << 3;
  f32x4 acc[2][2] = {};
  for (int k0 = 0; k0 < K; k0 += 32) {
    *(uint4*)&As[row][kc] = *(const uint4*)(aG + k0);
    *(uint4*)&Bs[row][kc] = *(const uint4*)(bG + k0);
    __syncthreads();
    bf16x8 a0 = *(const bf16x8*)&As[wr + fr][fk];
    bf16x8 a1 = *(const bf16x8*)&As[wr + 16 + fr][fk];
    bf16x8 b0 = *(const bf16x8*)&Bs[wc + fr][fk];
    bf16x8 b1 = *(const bf16x8*)&Bs[wc + 16 + fr][fk];
    acc[0][0] = __builtin_amdgcn_mfma_f32_16x16x32_bf16(a0, b0, acc[0][0], 0, 0, 0);
    acc[0][1] = __builtin_amdgcn_mfma_f32_16x16x32_bf16(a0, b1, acc[0][1], 0, 0, 0);
    acc[1][0] = __builtin_amdgcn_mfma_f32_16x16x32_bf16(a1, b0, acc[1][0], 0, 0, 0);
    acc[1][1] = __builtin_amdgcn_mfma_f32_16x16x32_bf16(a1, b1, acc[1][1], 0, 0, 0);
    __syncthreads();
  }
  int cr0 = wr + ((lane >> 4) << 2);
  int cc0 = wc + fr;
#pragma unroll
  for (int mm = 0; mm < 2; mm++)
#pragma unroll
    for (int nn = 0; nn < 2; nn++)
#pragma unroll
      for (int i = 0; i < 4; i++) {
        int gr = bm * 64 + cr0 + mm * 16 + i;
        int gc = bn * 64 + cc0 + nn * 16;
        float val = acc[mm][nn][i] + (bias ? bias[gc] : 0.f);
        if (MODE == 0) outB[(size_t)gr * N + gc] = f2bf(val);
        else resF[(size_t)gr * N + gc] = resF[(size_t)gr * N + gc] + val;
      }
}

// ---------------- elementwise rotary (in place on bf16 buffer) ---------------
__global__ __launch_bounds__(256) void rope_apply(ushort* __restrict__ buf,
    const float* __restrict__ fr, int rows, int stride, int colOff, int H, float scale) {
  int idx = blockIdx.x * 256 + threadIdx.x;
  int total = rows * H * 32;
  if (idx >= total) return;
  int p = idx & 31;
  int h = (idx >> 5) % H;
  int r = idx / (32 * H);
  float f0 = fr[(size_t)r * DHc + 2 * p];
  float f1 = fr[(size_t)r * DHc + 2 * p + 1];
  ushort* bp = buf + (size_t)r * stride + colOff + h * DHc + 2 * p;
  float x0 = bf2f(bp[0]), x1 = bf2f(bp[1]);
  float o0 = (x0 * __cosf(f0) - x1 * __sinf(f0)) * scale;
  float o1 = (x1 * __cosf(f1) + x0 * __sinf(f1)) * scale;
  bp[0] = f2bf(o0); bp[1] = f2bf(o1);
}

// ---------------- MFMA flash attention ---------------------------------------
template<int CAUSAL>
__global__ __launch_bounds__(256) void attn_mfma(
    const ushort* __restrict__ Q, const ushort* __restrict__ K,
    const ushort* __restrict__ Vt, ushort* __restrict__ O,
    int qStride, int kStride, int kOff, int oStride,
    int Tq, int NK, int H) {
  __shared__ __align__(16) ushort Ks[64 * 64];
  __shared__ __align__(16) ushort Vs[64 * 64];
  __shared__ __align__(16) ushort Ps[4][16 * 72];
  int b = blockIdx.z, h = blockIdx.y, qt = blockIdx.x;
  int t = threadIdx.x, wv = t >> 6, lane = t & 63;
  int g = lane >> 4, fr = lane & 15;
  int qw = qt * 64 + wv * 16;
  int HD = H * 64;

  const ushort* qrow = Q + (size_t)(b * Tq + qw + fr) * qStride + h * 64;
  bf16x8 qlo = *(const bf16x8*)(qrow + g * 8);
  bf16x8 qhi = *(const bf16x8*)(qrow + 32 + g * 8);

  f32x4 o_acc[4] = {};
  float m_run[4], l_run[4];
#pragma unroll
  for (int i = 0; i < 4; i++) { m_run[i] = -1e30f; l_run[i] = 0.f; }

  ushort* Pw = &Ps[wv][0];
  int ntiles = CAUSAL ? (qt + 1) : (NK / 64);
  for (int kt = 0; kt < ntiles; kt++) {
    int k0 = kt * 64;
    __syncthreads();
#pragma unroll
    for (int i = 0; i < 2; i++) {
      int id = t + i * 256;
      int r = id >> 3, c = id & 7;
      uint4 kval = *(const uint4*)(K + (size_t)(b * NK + k0 + r) * kStride + kOff + h * 64 + c * 8);
      *(uint4*)(Ks + r * 64 + ((c ^ (r & 7)) * 8)) = kval;
      uint4 vval = *(const uint4*)(Vt + ((size_t)b * HD + h * 64 + r) * NK + k0 + c * 8);
      *(uint4*)(Vs + r * 64 + ((c ^ (r & 7)) * 8)) = vval;
    }
    __syncthreads();

    f32x4 s[4];
#pragma unroll
    for (int nn = 0; nn < 4; nn++) {
      int row = nn * 16 + fr;
      bf16x8 kf0 = *(const bf16x8*)(Ks + row * 64 + ((g ^ (fr & 7)) * 8));
      bf16x8 kf1 = *(const bf16x8*)(Ks + row * 64 + (((4 + g) ^ (fr & 7)) * 8));
      f32x4 z = {};
      z = __builtin_amdgcn_mfma_f32_16x16x32_bf16(qlo, kf0, z, 0, 0, 0);
      z = __builtin_amdgcn_mfma_f32_16x16x32_bf16(qhi, kf1, z, 0, 0, 0);
      s[nn] = z;
    }
    if (CAUSAL && (k0 + 63 > qw)) {
#pragma unroll
      for (int nn = 0; nn < 4; nn++)
#pragma unroll
        for (int i = 0; i < 4; i++)
          if (k0 + nn * 16 + fr > qw + g * 4 + i) s[nn][i] = -1e30f;
    }
#pragma unroll
    for (int i = 0; i < 4; i++) {
      float tm = fmaxf(fmaxf(s[0][i], s[1][i]), fmaxf(s[2][i], s[3][i]));
#pragma unroll
      for (int off = 8; off; off >>= 1) tm = fmaxf(tm, __shfl_xor(tm, off));
      float mnew = fmaxf(m_run[i], tm);
      float corr = __expf(m_run[i] - mnew);
      float ps = 0.f;
#pragma unroll
      for (int nn = 0; nn < 4; nn++) {
        float p = __expf(s[nn][i] - mnew);
        s[nn][i] = p;
        ps += p;
      }
#pragma unroll
      for (int off = 8; off; off >>= 1) ps += __shfl_xor(ps, off);
      l_run[i] = l_run[i] * corr + ps;
      m_run[i] = mnew;
#pragma unroll
      for (int dd = 0; dd < 4; dd++) o_acc[dd][i] *= corr;
    }
#pragma unroll
    for (int nn = 0; nn < 4; nn++)
#pragma unroll
      for (int i = 0; i < 4; i++)
        Pw[(g * 4 + i) * 72 + nn * 16 + fr] = f2bf(s[nn][i]);
    bf16x8 pa0 = *(const bf16x8*)(Pw + fr * 72 + g * 8);
    bf16x8 pa1 = *(const bf16x8*)(Pw + fr * 72 + 32 + g * 8);
#pragma unroll
    for (int dd = 0; dd < 4; dd++) {
      int row = dd * 16 + fr;
      bf16x8 vf0 = *(const bf16x8*)(Vs + row * 64 + ((g ^ (fr & 7)) * 8));
      bf16x8 vf1 = *(const bf16x8*)(Vs + row * 64 + (((4 + g) ^ (fr & 7)) * 8));
      o_acc[dd] = __builtin_amdgcn_mfma_f32_16x16x32_bf16(pa0, vf0, o_acc[dd], 0, 0, 0);
      o_acc[dd] = __builtin_amdgcn_mfma_f32_16x16x32_bf16(pa1, vf1, o_acc[dd], 0, 0, 0);
    }
  }
#pragma unroll
  for (int dd = 0; dd < 4; dd++)
#pragma unroll
    for (int i = 0; i < 4; i++) {
      size_t oidx = (size_t)(b * Tq + qw + g * 4 + i) * oStride + h * 64 + dd * 16 + fr;
      O[oidx] = f2bf(o_acc[dd][i] / l_run[i]);
    }
}

// ---------------- orchestration ----------------------------------------------
extern "C" void kernel_launch(void* const* d_in, const int* in_sizes, int n_in,
                              void* d_out, int out_size, void* d_ws, size_t ws_size,
                              hipStream_t stream) {
  const float* bin_queries = (const float*)d_in[0];
  const float* bin_time    = (const float*)d_in[1];
  const float* latents     = (const float*)d_in[2];
  const float* lat_time    = (const float*)d_in[3];
  const float* ca_lnq_w = (const float*)d_in[4];
  const float* ca_lnq_b = (const float*)d_in[5];
  const float* ca_lnc_w = (const float*)d_in[6];
  const float* ca_lnc_b = (const float*)d_in[7];
  const float* ca_wq  = (const float*)d_in[8];
  const float* ca_wkv = (const float*)d_in[9];
  const float* ca_wo  = (const float*)d_in[10];
  const float* ca_bo  = (const float*)d_in[11];
  const float* sa_ln_w = (const float*)d_in[12];
  const float* sa_ln_b = (const float*)d_in[13];
  const float* sa_wqkv = (const float*)d_in[14];
  const float* sa_wo   = (const float*)d_in[15];
  const float* sa_bo   = (const float*)d_in[16];
  const float* ffn_ln_w = (const float*)d_in[17];
  const float* ffn_ln_b = (const float*)d_in[18];
  const float* ffn_w1 = (const float*)d_in[19];
  const float* ffn_b1 = (const float*)d_in[20];
  const float* ffn_w2 = (const float*)d_in[21];
  const float* ffn_b2 = (const float*)d_in[22];

  constexpr size_t X_BYTES = (size_t)RQ * DIMc * 4;
  char* ws = (char*)d_ws;
  float* x = (float*)ws;
  char* A0 = ws + X_BYTES;
  // cross-attn phase
  ushort* cn     = (ushort*)(A0);
  ushort* ca_xn  = (ushort*)(A0 + 16777216);
  ushort* qbuf   = (ushort*)(A0 + 25165824);
  ushort* kv     = (ushort*)(A0 + 27262976);
  ushort* ca_att = (ushort*)(A0 + 35651584);
  ushort* vt_c   = (ushort*)(A0 + 37748736);
  // self-attn phase (reuses arena)
  ushort* sa_xn  = (ushort*)(A0);
  ushort* qkv    = (ushort*)(A0 + 8388608);
  ushort* sa_att = (ushort*)(A0 + 33554432);
  ushort* vt_s   = (ushort*)(A0 + 41943040);
  // ffn phase (reuses arena)
  ushort* hb     = (ushort*)(A0);
  ushort* ag     = (ushort*)(A0 + 8388608);   // 32 MB (fused gelu output)
  // bf16 transposed weights for the current layer
  char* W0 = A0 + 109051904;
  ushort* wbase = (ushort*)W0;
  ushort* wqT  = wbase;
  ushort* wkvT = wbase + 65536;
  ushort* woT  = wbase + 196608;
  ushort* qkvT = wbase + 262144;
  ushort* swoT = wbase + 1048576;
  ushort* w1T  = wbase + 1310720;
  ushort* w2T  = wbase + 3407872;

  hipMemcpyAsync(x, bin_queries, X_BYTES, hipMemcpyDeviceToDevice, stream);

  for (int l = 0; l < 2; l++) {
    wtrans_all<<<4352, 256, 0, stream>>>(ca_wq, ca_wkv, ca_wo, sa_wqkv, sa_wo,
                                         ffn_w1, ffn_w2, wbase, l);

    // ---- cross attention ----
    ln_rows<<<RQ / 4, 256, 0, stream>>>(x, ca_lnq_w + l * DIMc, ca_lnq_b + l * DIMc, ca_xn, RQ);
    ln_rows<<<RL / 4, 256, 0, stream>>>(latents, ca_lnc_w + l * DIMc, ca_lnc_b + l * DIMc, cn, RL);
    gemm64<0><<<dim3(CIc / 64, RQ / 64), 256, 0, stream>>>(ca_xn, wqT, nullptr, nullptr, qbuf, RQ, CIc, DIMc);
    gemm64<0><<<dim3(2 * CIc / 64, RL / 64), 256, 0, stream>>>(cn, wkvT, nullptr, nullptr, kv, RL, 2 * CIc, DIMc);
    rope_apply<<<(RQ * CHc * 32) / 256, 256, 0, stream>>>(qbuf, bin_time, RQ, CIc, 0, CHc, 0.125f);
    rope_apply<<<(RL * CHc * 32) / 256, 256, 0, stream>>>(kv, lat_time, RL, 2 * CIc, 0, CHc, 1.f);
    vtrans<<<dim3(Nc / 32, CHc * 64 / 32, Bc), 256, 0, stream>>>(kv, vt_c, Nc, 2 * CIc, CIc);
    attn_mfma<0><<<dim3(Tc / 64, CHc, Bc), 256, 0, stream>>>(qbuf, kv, vt_c, ca_att,
        CIc, 2 * CIc, 0, CIc, Tc, Nc, CHc);
    gemm128<1><<<dim3(DIMc / 128, RQ / 128), 256, 0, stream>>>(ca_att, woT, ca_bo + l * DIMc,
        x, x, nullptr, RQ, DIMc, CIc);

    // ---- self attention (causal) ----
    ln_rows<<<RQ / 4, 256, 0, stream>>>(x, sa_ln_w + l * DIMc, sa_ln_b + l * DIMc, sa_xn, RQ);
    gemm128<0><<<dim3(3 * SIc / 128, RQ / 128), 256, 0, stream>>>(sa_xn, qkvT, nullptr,
        nullptr, nullptr, qkv, RQ, 3 * SIc, DIMc);
    rope_apply<<<(RQ * SHc * 32) / 256, 256, 0, stream>>>(qkv, bin_time, RQ, 3 * SIc, 0, SHc, 0.125f);
    rope_apply<<<(RQ * SHc * 32) / 256, 256, 0, stream>>>(qkv, bin_time, RQ, 3 * SIc, SIc, SHc, 1.f);
    vtrans<<<dim3(Tc / 32, SHc * 64 / 32, Bc), 256, 0, stream>>>(qkv, vt_s, Tc, 3 * SIc, 2 * SIc);
    attn_mfma<1><<<dim3(Tc / 64, SHc, Bc), 256, 0, stream>>>(qkv, qkv, vt_s, sa_att,
        3 * SIc, 3 * SIc, SIc, SIc, Tc, Tc, SHc);
    gemm128<1><<<dim3(DIMc / 128, RQ / 128), 256, 0, stream>>>(sa_att, swoT, sa_bo + l * DIMc,
        x, x, nullptr, RQ, DIMc, SIc);

    // ---- FFN (w1 with fused bias + a*gelu(g) epilogue) ----
    ln_rows<<<RQ / 4, 256, 0, stream>>>(x, ffn_ln_w + l * DIMc, ffn_ln_b + l * DIMc, hb, RQ);
    gemm128<2><<<dim3(2 * FFc / 128, RQ / 128), 256, 0, stream>>>(hb, w1T,
        ffn_b1 + (size_t)l * 2 * FFc, nullptr, nullptr, ag, RQ, 2 * FFc, DIMc);
    float* resOut = (l == 1) ? (float*)d_out : x;
    gemm128<1><<<dim3(DIMc / 128, RQ / 128), 256, 0, stream>>>(ag, w2T, ffn_b2 + l * DIMc,
        x, resOut, nullptr, RQ, DIMc, FFc);
  }
}

// Round 6
// 793.354 us; speedup vs baseline: 12.9268x; 1.0065x over previous
//
#include <hip/hip_runtime.h>
#include <cstdint>
#include <cstddef>

// ---------------- constants (match reference) ----------------
static constexpr int DIMc = 512;
static constexpr int DHc  = 64;
static constexpr int CHc  = 2;
static constexpr int SHc  = 8;
static constexpr int Bc   = 8;
static constexpr int Tc   = 1024;
static constexpr int Nc   = 2048;
static constexpr int CIc  = CHc * DHc;    // 128
static constexpr int SIc  = SHc * DHc;    // 512
static constexpr int FFc  = 4 * DIMc;     // 2048
static constexpr int RQ   = Bc * Tc;      // 8192 query rows
static constexpr int RL   = Bc * Nc;      // 16384 latent rows

typedef short bf16x8 __attribute__((ext_vector_type(8)));
typedef float f32x4  __attribute__((ext_vector_type(4)));

__device__ __forceinline__ ushort f2bf(float f) {
  uint32_t u = __builtin_bit_cast(uint32_t, f);
  u += 0x7fffu + ((u >> 16) & 1u);
  return (ushort)(u >> 16);
}
__device__ __forceinline__ float bf2f(ushort h) {
  uint32_t u = ((uint32_t)h) << 16;
  return __builtin_bit_cast(float, u);
}

__device__ __forceinline__ void gload_lds16(const ushort* g, ushort* lds) {
  __builtin_amdgcn_global_load_lds(
      (const __attribute__((address_space(1))) void*)g,
      (__attribute__((address_space(3))) void*)lds, 16, 0, 0);
}

// asm ds_read_b128: invisible to compiler's counters; waits are manual.
__device__ __forceinline__ bf16x8 ds_read8(const ushort* p) {
  bf16x8 d;
  asm volatile("ds_read_b128 %0, %1"
               : "=v"(d)
               : "v"((const __attribute__((address_space(3))) ushort*)p));
  return d;
}

// ---------------- LayerNorm: one wave per 512-col row, fp32 in -> bf16 out ----
__global__ __launch_bounds__(256) void ln_rows(const float* __restrict__ X,
    const float* __restrict__ w, const float* __restrict__ b,
    ushort* __restrict__ out, int rows) {
  int gw = (int)((blockIdx.x * 256 + threadIdx.x) >> 6);
  int lane = threadIdx.x & 63;
  if (gw >= rows) return;
  const float* xr = X + (size_t)gw * DIMc;
  float4 v0 = *(const float4*)(xr + lane * 8);
  float4 v1 = *(const float4*)(xr + lane * 8 + 4);
  float xv[8] = {v0.x, v0.y, v0.z, v0.w, v1.x, v1.y, v1.z, v1.w};
  float s = 0.f, ss = 0.f;
#pragma unroll
  for (int i = 0; i < 8; i++) { s += xv[i]; ss += xv[i] * xv[i]; }
#pragma unroll
  for (int off = 32; off; off >>= 1) { s += __shfl_xor(s, off); ss += __shfl_xor(ss, off); }
  float mean = s * (1.f / DIMc);
  float var = ss * (1.f / DIMc) - mean * mean;
  float r = rsqrtf(var + 1e-5f);
  int c = lane * 8;
  ushort o[8] __attribute__((aligned(16)));
#pragma unroll
  for (int i = 0; i < 8; i++) o[i] = f2bf((xv[i] - mean) * r * w[c + i] + b[c + i]);
  *(uint4*)(out + (size_t)gw * DIMc + c) = *(const uint4*)o;
}

// ------------- ALL weight transposes for one layer, one launch ----------------
// wid 5 (ffn_w1): output rows interleaved (a0,g0,a1,g1,...) for the fused
// gelu epilogue:  srcN n -> rowT = n<2048 ? 2n : 2(n-2048)+1
__global__ __launch_bounds__(256) void wtrans_all(
    const float* __restrict__ wq, const float* __restrict__ wkv,
    const float* __restrict__ wo, const float* __restrict__ qkv,
    const float* __restrict__ swo, const float* __restrict__ w1,
    const float* __restrict__ w2, ushort* __restrict__ dst, int layer) {
  constexpr int Ks[7]   = {512, 512, 128, 512, 512, 512, 2048};
  constexpr int Ns[7]   = {128, 256, 512, 1536, 512, 4096, 512};
  constexpr int pre[8]  = {0, 64, 192, 256, 1024, 1280, 3328, 4352};
  constexpr int dOff[7] = {0, 65536, 196608, 262144, 1048576, 1310720, 3407872};
  int bid = blockIdx.x;
  int wid = 0;
#pragma unroll
  for (int i = 1; i < 7; i++) wid += (bid >= pre[i]);
  int tileIdx = bid - pre[wid];
  int K = Ks[wid], N = Ns[wid];
  const float* srcs[7] = {wq, wkv, wo, qkv, swo, w1, w2};
  const float* W = srcs[wid] + (size_t)layer * K * N;
  ushort* Wt = dst + dOff[wid];
  int ntx = N / 32;
  int n0 = (tileIdx % ntx) * 32, k0 = (tileIdx / ntx) * 32;
  __shared__ float tile[32][33];
  int tx = threadIdx.x & 31, ty = threadIdx.x >> 5;
#pragma unroll
  for (int i = 0; i < 32; i += 8)
    tile[ty + i][tx] = W[(size_t)(k0 + ty + i) * N + n0 + tx];
  __syncthreads();
  if (wid == 5) {
#pragma unroll
    for (int i = 0; i < 32; i += 8) {
      int nrow = n0 + ty + i;
      int rowT = (nrow < 2048) ? (nrow * 2) : ((nrow - 2048) * 2 + 1);
      Wt[(size_t)rowT * K + k0 + tx] = f2bf(tile[tx][ty + i]);
    }
  } else {
#pragma unroll
    for (int i = 0; i < 32; i += 8)
      Wt[(size_t)(n0 + ty + i) * K + k0 + tx] = f2bf(tile[tx][ty + i]);
  }
}

// ---------------- bf16 V transpose: dst[b][hd][key] --------------------------
__global__ __launch_bounds__(256) void vtrans(const ushort* __restrict__ src,
    ushort* __restrict__ dst, int NK, int stride, int colOff) {
  __shared__ ushort tile[32][33];
  int b = blockIdx.z;
  int key0 = blockIdx.x * 32, hd0 = blockIdx.y * 32;
  int HD = gridDim.y * 32;
  int tx = threadIdx.x & 31, ty = threadIdx.x >> 5;
#pragma unroll
  for (int i = 0; i < 32; i += 8)
    tile[ty + i][tx] = src[(size_t)(b * NK + key0 + ty + i) * stride + colOff + hd0 + tx];
  __syncthreads();
#pragma unroll
  for (int i = 0; i < 32; i += 8)
    dst[((size_t)b * HD + hd0 + ty + i) * NK + key0 + tx] = tile[tx][ty + i];
}

// ---- 128x128 GEMM, BK=64, 2-deep pipeline with COUNTED vmcnt (T3+T4) --------
// A: M x K bf16 row-major.  Bt: N x K bf16 row-major.
// LDS: row stride 64 bf16; 16B chunk at slot s of row r holds k-chunk s^(r&7).
// Per K-step: vmcnt(8)+barrier (current tile landed; next tile's 8 loads stay
// in flight) -> asm ds_read -> lgkmcnt(0) -> barrier (all waves done reading)
// -> STAGE(t+2) issued -> 32 MFMA overlap the in-flight loads.  Never vmcnt(0)
// in the main loop (T4).
// MODE 0: outB = bf16(acc + bias)
// MODE 1: resOut = resIn + acc + bias   (fp32)
// MODE 2: fused FFN gate (Bt rows interleaved a,g): even lanes write
//         bf16( a * 0.5*g*(1+erf(g/sqrt2)) ), row stride N/2.
template<int MODE>
__global__ __launch_bounds__(256) void gemm128(const ushort* __restrict__ A,
    const ushort* __restrict__ Bt, const float* __restrict__ bias,
    const float* __restrict__ resIn, float* __restrict__ resOut,
    ushort* __restrict__ outB, int M, int N, int K) {
  __shared__ __align__(16) ushort As[2][128 * 64];
  __shared__ __align__(16) ushort Bs[2][128 * 64];
  int t = threadIdx.x, wv = t >> 6, lane = t & 63;
  int bm = blockIdx.y, bn = blockIdx.x;
  int fr = lane & 15, g = lane >> 4;
  int wr = (wv >> 1) * 64, wc = (wv & 1) * 64;
  int srow = wv * 32 + (lane >> 3);
  int sslot = lane & 7;
  const ushort* Abase = A + (size_t)(bm * 128) * K;
  const ushort* Bbase = Bt + (size_t)(bn * 128) * K;

  f32x4 acc[4][4] = {};
  int nt = K >> 6;

#define STAGE(buf, k0)                                                        \
  {                                                                           \
    _Pragma("unroll")                                                         \
    for (int j = 0; j < 4; j++) {                                             \
      int r = srow + j * 8;                                                   \
      int kc = sslot ^ (r & 7);                                               \
      gload_lds16(Abase + (size_t)r * K + (k0) + kc * 8,                      \
                  &As[buf][(wv * 256 + j * 64) * 8]);                         \
      gload_lds16(Bbase + (size_t)r * K + (k0) + kc * 8,                      \
                  &Bs[buf][(wv * 256 + j * 64) * 8]);                         \
    }                                                                         \
  }

  STAGE(0, 0);
  if (nt > 1) STAGE(1, 64);

  for (int tt = 0; tt < nt; tt++) {
    int cur = tt & 1;
    // current tile's 8 loads (oldest) landed; next tile's 8 stay in flight
    if (tt + 1 < nt)
      asm volatile("s_waitcnt vmcnt(8)\n\ts_barrier" ::: "memory");
    else
      asm volatile("s_waitcnt vmcnt(0)\n\ts_barrier" ::: "memory");
    __builtin_amdgcn_sched_barrier(0);

    const ushort* Ac = As[cur];
    const ushort* Bc = Bs[cur];
    bf16x8 af[2][4], bfr[2][4];
#pragma unroll
    for (int ks = 0; ks < 2; ks++)
#pragma unroll
      for (int mm = 0; mm < 4; mm++) {
        int rowa = wr + mm * 16 + fr;
        af[ks][mm] = ds_read8(Ac + rowa * 64 + (((ks * 4 + g) ^ (rowa & 7)) * 8));
        int rowb = wc + mm * 16 + fr;
        bfr[ks][mm] = ds_read8(Bc + rowb * 64 + (((ks * 4 + g) ^ (rowb & 7)) * 8));
      }
    asm volatile("s_waitcnt lgkmcnt(0)" ::: "memory");
    __builtin_amdgcn_sched_barrier(0);
    // all waves done reading buf[cur]; safe to overwrite it
    asm volatile("s_barrier" ::: "memory");
    if (tt + 2 < nt) STAGE(cur, (tt + 2) * 64);
    // MFMA cluster overlaps the in-flight prefetch
#pragma unroll
    for (int ks = 0; ks < 2; ks++)
#pragma unroll
      for (int mm = 0; mm < 4; mm++)
#pragma unroll
        for (int nn = 0; nn < 4; nn++)
          acc[mm][nn] = __builtin_amdgcn_mfma_f32_16x16x32_bf16(af[ks][mm], bfr[ks][nn], acc[mm][nn], 0, 0, 0);
    __builtin_amdgcn_sched_barrier(0);
  }
#undef STAGE

  int NH = N >> 1;
#pragma unroll
  for (int mm = 0; mm < 4; mm++)
#pragma unroll
    for (int nn = 0; nn < 4; nn++)
#pragma unroll
      for (int i = 0; i < 4; i++) {
        int gr = bm * 128 + wr + mm * 16 + g * 4 + i;
        int gc = bn * 128 + wc + nn * 16 + fr;
        if (MODE == 2) {
          float v = acc[mm][nn][i] + bias[(gc & 1) ? (NH + (gc >> 1)) : (gc >> 1)];
          float gv = __shfl_down(v, 1);
          if (!(fr & 1)) {
            float res = v * 0.5f * gv * (1.f + erff(gv * 0.70710678f));
            outB[(size_t)gr * NH + (gc >> 1)] = f2bf(res);
          }
        } else {
          float val = acc[mm][nn][i] + (bias ? bias[gc] : 0.f);
          if (MODE == 0) outB[(size_t)gr * N + gc] = f2bf(val);
          else resOut[(size_t)gr * N + gc] = resIn[(size_t)gr * N + gc] + val;
        }
      }
}

// ---------------- bf16 MFMA GEMM, 64x64 tile (small-N shapes) ----------------
template<int MODE>
__global__ __launch_bounds__(256) void gemm64(const ushort* __restrict__ A,
    const ushort* __restrict__ Bt, const float* __restrict__ bias,
    float* __restrict__ resF, ushort* __restrict__ outB,
    int M, int N, int K) {
  __shared__ __align__(16) ushort As[64][40];
  __shared__ __align__(16) ushort Bs[64][40];
  int t = threadIdx.x;
  int bm = blockIdx.y, bn = blockIdx.x;
  int row = t >> 2, kc = (t & 3) << 3;
  const ushort* aG = A + (size_t)(bm * 64 + row) * K + kc;
  const ushort* bG = Bt + (size_t)(bn * 64 + row) * K + kc;
  int wv = t >> 6, lane = t & 63;
  int wr = (wv >> 1) * 32, wc = (wv & 1) * 32;
  int fr = lane & 15, fk = (lane >> 4) << 3;
  f32x4 acc[2][2] = {};
  for (int k0 = 0; k0 < K; k0 += 32) {
    *(uint4*)&As[row][kc] = *(const uint4*)(aG + k0);
    *(uint4*)&Bs[row][kc] = *(const uint4*)(bG + k0);
    __syncthreads();
    bf16x8 a0 = *(const bf16x8*)&As[wr + fr][fk];
    bf16x8 a1 = *(const bf16x8*)&As[wr + 16 + fr][fk];
    bf16x8 b0 = *(const bf16x8*)&Bs[wc + fr][fk];
    bf16x8 b1 = *(const bf16x8*)&Bs[wc + 16 + fr][fk];
    acc[0][0] = __builtin_amdgcn_mfma_f32_16x16x32_bf16(a0, b0, acc[0][0], 0, 0, 0);
    acc[0][1] = __builtin_amdgcn_mfma_f32_16x16x32_bf16(a0, b1, acc[0][1], 0, 0, 0);
    acc[1][0] = __builtin_amdgcn_mfma_f32_16x16x32_bf16(a1, b0, acc[1][0], 0, 0, 0);
    acc[1][1] = __builtin_amdgcn_mfma_f32_16x16x32_bf16(a1, b1, acc[1][1], 0, 0, 0);
    __syncthreads();
  }
  int cr0 = wr + ((lane >> 4) << 2);
  int cc0 = wc + fr;
#pragma unroll
  for (int mm = 0; mm < 2; mm++)
#pragma unroll
    for (int nn = 0; nn < 2; nn++)
#pragma unroll
      for (int i = 0; i < 4; i++) {
        int gr = bm * 64 + cr0 + mm * 16 + i;
        int gc = bn * 64 + cc0 + nn * 16;
        float val = acc[mm][nn][i] + (bias ? bias[gc] : 0.f);
        if (MODE == 0) outB[(size_t)gr * N + gc] = f2bf(val);
        else resF[(size_t)gr * N + gc] = resF[(size_t)gr * N + gc] + val;
      }
}

// ---------------- elementwise rotary (in place on bf16 buffer) ---------------
__global__ __launch_bounds__(256) void rope_apply(ushort* __restrict__ buf,
    const float* __restrict__ fr, int rows, int stride, int colOff, int H, float scale) {
  int idx = blockIdx.x * 256 + threadIdx.x;
  int total = rows * H * 32;
  if (idx >= total) return;
  int p = idx & 31;
  int h = (idx >> 5) % H;
  int r = idx / (32 * H);
  float f0 = fr[(size_t)r * DHc + 2 * p];
  float f1 = fr[(size_t)r * DHc + 2 * p + 1];
  ushort* bp = buf + (size_t)r * stride + colOff + h * DHc + 2 * p;
  float x0 = bf2f(bp[0]), x1 = bf2f(bp[1]);
  float o0 = (x0 * __cosf(f0) - x1 * __sinf(f0)) * scale;
  float o1 = (x1 * __cosf(f1) + x0 * __sinf(f1)) * scale;
  bp[0] = f2bf(o0); bp[1] = f2bf(o1);
}

// ---------------- MFMA flash attention ---------------------------------------
template<int CAUSAL>
__global__ __launch_bounds__(256) void attn_mfma(
    const ushort* __restrict__ Q, const ushort* __restrict__ K,
    const ushort* __restrict__ Vt, ushort* __restrict__ O,
    int qStride, int kStride, int kOff, int oStride,
    int Tq, int NK, int H) {
  __shared__ __align__(16) ushort Ks[64 * 64];
  __shared__ __align__(16) ushort Vs[64 * 64];
  __shared__ __align__(16) ushort Ps[4][16 * 72];
  int b = blockIdx.z, h = blockIdx.y, qt = blockIdx.x;
  int t = threadIdx.x, wv = t >> 6, lane = t & 63;
  int g = lane >> 4, fr = lane & 15;
  int qw = qt * 64 + wv * 16;
  int HD = H * 64;

  const ushort* qrow = Q + (size_t)(b * Tq + qw + fr) * qStride + h * 64;
  bf16x8 qlo = *(const bf16x8*)(qrow + g * 8);
  bf16x8 qhi = *(const bf16x8*)(qrow + 32 + g * 8);

  f32x4 o_acc[4] = {};
  float m_run[4], l_run[4];
#pragma unroll
  for (int i = 0; i < 4; i++) { m_run[i] = -1e30f; l_run[i] = 0.f; }

  ushort* Pw = &Ps[wv][0];
  int ntiles = CAUSAL ? (qt + 1) : (NK / 64);
  for (int kt = 0; kt < ntiles; kt++) {
    int k0 = kt * 64;
    __syncthreads();
#pragma unroll
    for (int i = 0; i < 2; i++) {
      int id = t + i * 256;
      int r = id >> 3, c = id & 7;
      uint4 kval = *(const uint4*)(K + (size_t)(b * NK + k0 + r) * kStride + kOff + h * 64 + c * 8);
      *(uint4*)(Ks + r * 64 + ((c ^ (r & 7)) * 8)) = kval;
      uint4 vval = *(const uint4*)(Vt + ((size_t)b * HD + h * 64 + r) * NK + k0 + c * 8);
      *(uint4*)(Vs + r * 64 + ((c ^ (r & 7)) * 8)) = vval;
    }
    __syncthreads();

    f32x4 s[4];
#pragma unroll
    for (int nn = 0; nn < 4; nn++) {
      int row = nn * 16 + fr;
      bf16x8 kf0 = *(const bf16x8*)(Ks + row * 64 + ((g ^ (fr & 7)) * 8));
      bf16x8 kf1 = *(const bf16x8*)(Ks + row * 64 + (((4 + g) ^ (fr & 7)) * 8));
      f32x4 z = {};
      z = __builtin_amdgcn_mfma_f32_16x16x32_bf16(qlo, kf0, z, 0, 0, 0);
      z = __builtin_amdgcn_mfma_f32_16x16x32_bf16(qhi, kf1, z, 0, 0, 0);
      s[nn] = z;
    }
    if (CAUSAL && (k0 + 63 > qw)) {
#pragma unroll
      for (int nn = 0; nn < 4; nn++)
#pragma unroll
        for (int i = 0; i < 4; i++)
          if (k0 + nn * 16 + fr > qw + g * 4 + i) s[nn][i] = -1e30f;
    }
#pragma unroll
    for (int i = 0; i < 4; i++) {
      float tm = fmaxf(fmaxf(s[0][i], s[1][i]), fmaxf(s[2][i], s[3][i]));
#pragma unroll
      for (int off = 8; off; off >>= 1) tm = fmaxf(tm, __shfl_xor(tm, off));
      float mnew = fmaxf(m_run[i], tm);
      float corr = __expf(m_run[i] - mnew);
      float ps = 0.f;
#pragma unroll
      for (int nn = 0; nn < 4; nn++) {
        float p = __expf(s[nn][i] - mnew);
        s[nn][i] = p;
        ps += p;
      }
#pragma unroll
      for (int off = 8; off; off >>= 1) ps += __shfl_xor(ps, off);
      l_run[i] = l_run[i] * corr + ps;
      m_run[i] = mnew;
#pragma unroll
      for (int dd = 0; dd < 4; dd++) o_acc[dd][i] *= corr;
    }
#pragma unroll
    for (int nn = 0; nn < 4; nn++)
#pragma unroll
      for (int i = 0; i < 4; i++)
        Pw[(g * 4 + i) * 72 + nn * 16 + fr] = f2bf(s[nn][i]);
    bf16x8 pa0 = *(const bf16x8*)(Pw + fr * 72 + g * 8);
    bf16x8 pa1 = *(const bf16x8*)(Pw + fr * 72 + 32 + g * 8);
#pragma unroll
    for (int dd = 0; dd < 4; dd++) {
      int row = dd * 16 + fr;
      bf16x8 vf0 = *(const bf16x8*)(Vs + row * 64 + ((g ^ (fr & 7)) * 8));
      bf16x8 vf1 = *(const bf16x8*)(Vs + row * 64 + (((4 + g) ^ (fr & 7)) * 8));
      o_acc[dd] = __builtin_amdgcn_mfma_f32_16x16x32_bf16(pa0, vf0, o_acc[dd], 0, 0, 0);
      o_acc[dd] = __builtin_amdgcn_mfma_f32_16x16x32_bf16(pa1, vf1, o_acc[dd], 0, 0, 0);
    }
  }
#pragma unroll
  for (int dd = 0; dd < 4; dd++)
#pragma unroll
    for (int i = 0; i < 4; i++) {
      size_t oidx = (size_t)(b * Tq + qw + g * 4 + i) * oStride + h * 64 + dd * 16 + fr;
      O[oidx] = f2bf(o_acc[dd][i] / l_run[i]);
    }
}

// ---------------- orchestration ----------------------------------------------
extern "C" void kernel_launch(void* const* d_in, const int* in_sizes, int n_in,
                              void* d_out, int out_size, void* d_ws, size_t ws_size,
                              hipStream_t stream) {
  const float* bin_queries = (const float*)d_in[0];
  const float* bin_time    = (const float*)d_in[1];
  const float* latents     = (const float*)d_in[2];
  const float* lat_time    = (const float*)d_in[3];
  const float* ca_lnq_w = (const float*)d_in[4];
  const float* ca_lnq_b = (const float*)d_in[5];
  const float* ca_lnc_w = (const float*)d_in[6];
  const float* ca_lnc_b = (const float*)d_in[7];
  const float* ca_wq  = (const float*)d_in[8];
  const float* ca_wkv = (const float*)d_in[9];
  const float* ca_wo  = (const float*)d_in[10];
  const float* ca_bo  = (const float*)d_in[11];
  const float* sa_ln_w = (const float*)d_in[12];
  const float* sa_ln_b = (const float*)d_in[13];
  const float* sa_wqkv = (const float*)d_in[14];
  const float* sa_wo   = (const float*)d_in[15];
  const float* sa_bo   = (const float*)d_in[16];
  const float* ffn_ln_w = (const float*)d_in[17];
  const float* ffn_ln_b = (const float*)d_in[18];
  const float* ffn_w1 = (const float*)d_in[19];
  const float* ffn_b1 = (const float*)d_in[20];
  const float* ffn_w2 = (const float*)d_in[21];
  const float* ffn_b2 = (const float*)d_in[22];

  constexpr size_t X_BYTES = (size_t)RQ * DIMc * 4;
  char* ws = (char*)d_ws;
  float* x = (float*)ws;
  char* A0 = ws + X_BYTES;
  // cross-attn phase
  ushort* cn     = (ushort*)(A0);
  ushort* ca_xn  = (ushort*)(A0 + 16777216);
  ushort* qbuf   = (ushort*)(A0 + 25165824);
  ushort* kv     = (ushort*)(A0 + 27262976);
  ushort* ca_att = (ushort*)(A0 + 35651584);
  ushort* vt_c   = (ushort*)(A0 + 37748736);
  // self-attn phase (reuses arena)
  ushort* sa_xn  = (ushort*)(A0);
  ushort* qkv    = (ushort*)(A0 + 8388608);
  ushort* sa_att = (ushort*)(A0 + 33554432);
  ushort* vt_s   = (ushort*)(A0 + 41943040);
  // ffn phase (reuses arena)
  ushort* hb     = (ushort*)(A0);
  ushort* ag     = (ushort*)(A0 + 8388608);   // 32 MB (fused gelu output)
  // bf16 transposed weights for the current layer
  char* W0 = A0 + 109051904;
  ushort* wbase = (ushort*)W0;
  ushort* wqT  = wbase;
  ushort* wkvT = wbase + 65536;
  ushort* woT  = wbase + 196608;
  ushort* qkvT = wbase + 262144;
  ushort* swoT = wbase + 1048576;
  ushort* w1T  = wbase + 1310720;
  ushort* w2T  = wbase + 3407872;

  hipMemcpyAsync(x, bin_queries, X_BYTES, hipMemcpyDeviceToDevice, stream);

  for (int l = 0; l < 2; l++) {
    wtrans_all<<<4352, 256, 0, stream>>>(ca_wq, ca_wkv, ca_wo, sa_wqkv, sa_wo,
                                         ffn_w1, ffn_w2, wbase, l);

    // ---- cross attention ----
    ln_rows<<<RQ / 4, 256, 0, stream>>>(x, ca_lnq_w + l * DIMc, ca_lnq_b + l * DIMc, ca_xn, RQ);
    ln_rows<<<RL / 4, 256, 0, stream>>>(latents, ca_lnc_w + l * DIMc, ca_lnc_b + l * DIMc, cn, RL);
    gemm64<0><<<dim3(CIc / 64, RQ / 64), 256, 0, stream>>>(ca_xn, wqT, nullptr, nullptr, qbuf, RQ, CIc, DIMc);
    gemm64<0><<<dim3(2 * CIc / 64, RL / 64), 256, 0, stream>>>(cn, wkvT, nullptr, nullptr, kv, RL, 2 * CIc, DIMc);
    rope_apply<<<(RQ * CHc * 32) / 256, 256, 0, stream>>>(qbuf, bin_time, RQ, CIc, 0, CHc, 0.125f);
    rope_apply<<<(RL * CHc * 32) / 256, 256, 0, stream>>>(kv, lat_time, RL, 2 * CIc, 0, CHc, 1.f);
    vtrans<<<dim3(Nc / 32, CHc * 64 / 32, Bc), 256, 0, stream>>>(kv, vt_c, Nc, 2 * CIc, CIc);
    attn_mfma<0><<<dim3(Tc / 64, CHc, Bc), 256, 0, stream>>>(qbuf, kv, vt_c, ca_att,
        CIc, 2 * CIc, 0, CIc, Tc, Nc, CHc);
    gemm128<1><<<dim3(DIMc / 128, RQ / 128), 256, 0, stream>>>(ca_att, woT, ca_bo + l * DIMc,
        x, x, nullptr, RQ, DIMc, CIc);

    // ---- self attention (causal) ----
    ln_rows<<<RQ / 4, 256, 0, stream>>>(x, sa_ln_w + l * DIMc, sa_ln_b + l * DIMc, sa_xn, RQ);
    gemm128<0><<<dim3(3 * SIc / 128, RQ / 128), 256, 0, stream>>>(sa_xn, qkvT, nullptr,
        nullptr, nullptr, qkv, RQ, 3 * SIc, DIMc);
    rope_apply<<<(RQ * SHc * 32) / 256, 256, 0, stream>>>(qkv, bin_time, RQ, 3 * SIc, 0, SHc, 0.125f);
    rope_apply<<<(RQ * SHc * 32) / 256, 256, 0, stream>>>(qkv, bin_time, RQ, 3 * SIc, SIc, SHc, 1.f);
    vtrans<<<dim3(Tc / 32, SHc * 64 / 32, Bc), 256, 0, stream>>>(qkv, vt_s, Tc, 3 * SIc, 2 * SIc);
    attn_mfma<1><<<dim3(Tc / 64, SHc, Bc), 256, 0, stream>>>(qkv, qkv, vt_s, sa_att,
        3 * SIc, 3 * SIc, SIc, SIc, Tc, Tc, SHc);
    gemm128<1><<<dim3(DIMc / 128, RQ / 128), 256, 0, stream>>>(sa_att, swoT, sa_bo + l * DIMc,
        x, x, nullptr, RQ, DIMc, SIc);

    // ---- FFN (w1 with fused bias + a*gelu(g) epilogue) ----
    ln_rows<<<RQ / 4, 256, 0, stream>>>(x, ffn_ln_w + l * DIMc, ffn_ln_b + l * DIMc, hb, RQ);
    gemm128<2><<<dim3(2 * FFc / 128, RQ / 128), 256, 0, stream>>>(hb, w1T,
        ffn_b1 + (size_t)l * 2 * FFc, nullptr, nullptr, ag, RQ, 2 * FFc, DIMc);
    float* resOut = (l == 1) ? (float*)d_out : x;
    gemm128<1><<<dim3(DIMc / 128, RQ / 128), 256, 0, stream>>>(ag, w2T, ffn_b2 + l * DIMc,
        x, resOut, nullptr, RQ, DIMc, FFc);
  }
}

// Round 7
// 756.969 us; speedup vs baseline: 13.5481x; 1.0481x over previous
//
#include <hip/hip_runtime.h>
#include <cstdint>
#include <cstddef>

// ---------------- constants (match reference) ----------------
static constexpr int DIMc = 512;
static constexpr int DHc  = 64;
static constexpr int CHc  = 2;
static constexpr int SHc  = 8;
static constexpr int Bc   = 8;
static constexpr int Tc   = 1024;
static constexpr int Nc   = 2048;
static constexpr int CIc  = CHc * DHc;    // 128
static constexpr int SIc  = SHc * DHc;    // 512
static constexpr int FFc  = 4 * DIMc;     // 2048
static constexpr int RQ   = Bc * Tc;      // 8192 query rows
static constexpr int RL   = Bc * Nc;      // 16384 latent rows

typedef short bf16x8 __attribute__((ext_vector_type(8)));
typedef float f32x4  __attribute__((ext_vector_type(4)));

__device__ __forceinline__ ushort f2bf(float f) {
  uint32_t u = __builtin_bit_cast(uint32_t, f);
  u += 0x7fffu + ((u >> 16) & 1u);
  return (ushort)(u >> 16);
}
__device__ __forceinline__ float bf2f(ushort h) {
  uint32_t u = ((uint32_t)h) << 16;
  return __builtin_bit_cast(float, u);
}

__device__ __forceinline__ void gload_lds16(const ushort* g, ushort* lds) {
  __builtin_amdgcn_global_load_lds(
      (const __attribute__((address_space(1))) void*)g,
      (__attribute__((address_space(3))) void*)lds, 16, 0, 0);
}

// ---------------- LayerNorm: one wave per 512-col row, fp32 in -> bf16 out ----
__global__ __launch_bounds__(256) void ln_rows(const float* __restrict__ X,
    const float* __restrict__ w, const float* __restrict__ b,
    ushort* __restrict__ out, int rows) {
  int gw = (int)((blockIdx.x * 256 + threadIdx.x) >> 6);
  int lane = threadIdx.x & 63;
  if (gw >= rows) return;
  const float* xr = X + (size_t)gw * DIMc;
  float4 v0 = *(const float4*)(xr + lane * 8);
  float4 v1 = *(const float4*)(xr + lane * 8 + 4);
  float xv[8] = {v0.x, v0.y, v0.z, v0.w, v1.x, v1.y, v1.z, v1.w};
  float s = 0.f, ss = 0.f;
#pragma unroll
  for (int i = 0; i < 8; i++) { s += xv[i]; ss += xv[i] * xv[i]; }
#pragma unroll
  for (int off = 32; off; off >>= 1) { s += __shfl_xor(s, off); ss += __shfl_xor(ss, off); }
  float mean = s * (1.f / DIMc);
  float var = ss * (1.f / DIMc) - mean * mean;
  float r = rsqrtf(var + 1e-5f);
  int c = lane * 8;
  ushort o[8] __attribute__((aligned(16)));
#pragma unroll
  for (int i = 0; i < 8; i++) o[i] = f2bf((xv[i] - mean) * r * w[c + i] + b[c + i]);
  *(uint4*)(out + (size_t)gw * DIMc + c) = *(const uint4*)o;
}

// ------------- ALL weight transposes for one layer, one launch ----------------
// wid 5 (ffn_w1): output rows interleaved (a0,g0,a1,g1,...) for the fused
// gelu epilogue:  srcN n -> rowT = n<2048 ? 2n : 2(n-2048)+1
__global__ __launch_bounds__(256) void wtrans_all(
    const float* __restrict__ wq, const float* __restrict__ wkv,
    const float* __restrict__ wo, const float* __restrict__ qkv,
    const float* __restrict__ swo, const float* __restrict__ w1,
    const float* __restrict__ w2, ushort* __restrict__ dst, int layer) {
  constexpr int Ks[7]   = {512, 512, 128, 512, 512, 512, 2048};
  constexpr int Ns[7]   = {128, 256, 512, 1536, 512, 4096, 512};
  constexpr int pre[8]  = {0, 64, 192, 256, 1024, 1280, 3328, 4352};
  constexpr int dOff[7] = {0, 65536, 196608, 262144, 1048576, 1310720, 3407872};
  int bid = blockIdx.x;
  int wid = 0;
#pragma unroll
  for (int i = 1; i < 7; i++) wid += (bid >= pre[i]);
  int tileIdx = bid - pre[wid];
  int K = Ks[wid], N = Ns[wid];
  const float* srcs[7] = {wq, wkv, wo, qkv, swo, w1, w2};
  const float* W = srcs[wid] + (size_t)layer * K * N;
  ushort* Wt = dst + dOff[wid];
  int ntx = N / 32;
  int n0 = (tileIdx % ntx) * 32, k0 = (tileIdx / ntx) * 32;
  __shared__ float tile[32][33];
  int tx = threadIdx.x & 31, ty = threadIdx.x >> 5;
#pragma unroll
  for (int i = 0; i < 32; i += 8)
    tile[ty + i][tx] = W[(size_t)(k0 + ty + i) * N + n0 + tx];
  __syncthreads();
  if (wid == 5) {
#pragma unroll
    for (int i = 0; i < 32; i += 8) {
      int nrow = n0 + ty + i;
      int rowT = (nrow < 2048) ? (nrow * 2) : ((nrow - 2048) * 2 + 1);
      Wt[(size_t)rowT * K + k0 + tx] = f2bf(tile[tx][ty + i]);
    }
  } else {
#pragma unroll
    for (int i = 0; i < 32; i += 8)
      Wt[(size_t)(n0 + ty + i) * K + k0 + tx] = f2bf(tile[tx][ty + i]);
  }
}

// ---------------- bf16 V transpose: dst[b][hd][key] --------------------------
__global__ __launch_bounds__(256) void vtrans(const ushort* __restrict__ src,
    ushort* __restrict__ dst, int NK, int stride, int colOff) {
  __shared__ ushort tile[32][33];
  int b = blockIdx.z;
  int key0 = blockIdx.x * 32, hd0 = blockIdx.y * 32;
  int HD = gridDim.y * 32;
  int tx = threadIdx.x & 31, ty = threadIdx.x >> 5;
#pragma unroll
  for (int i = 0; i < 32; i += 8)
    tile[ty + i][tx] = src[(size_t)(b * NK + key0 + ty + i) * stride + colOff + hd0 + tx];
  __syncthreads();
#pragma unroll
  for (int i = 0; i < 32; i += 8)
    dst[((size_t)b * HD + hd0 + ty + i) * NK + key0 + tx] = tile[tx][ty + i];
}

// ------- 128x128 GEMM, BK=64, single-buffer (proven r3 structure) ------------
// A: M x K bf16 row-major.  Bt: N x K bf16 row-major.
// LDS: row stride 64 bf16; 16B chunk at slot s of row r holds k-chunk s^(r&7).
// MODE 0: outB = bf16(acc + bias)
// MODE 1: resOut = resIn + acc + bias   (fp32)
// MODE 2: fused FFN gate (Bt rows interleaved a,g): even lanes write
//         bf16( a * 0.5*g*(1+erf(g/sqrt2)) ), row stride N/2.
template<int MODE>
__global__ __launch_bounds__(256) void gemm128(const ushort* __restrict__ A,
    const ushort* __restrict__ Bt, const float* __restrict__ bias,
    const float* __restrict__ resIn, float* __restrict__ resOut,
    ushort* __restrict__ outB, int M, int N, int K) {
  __shared__ __align__(16) ushort As[128 * 64];
  __shared__ __align__(16) ushort Bs[128 * 64];
  int t = threadIdx.x, wv = t >> 6, lane = t & 63;
  int bm = blockIdx.y, bn = blockIdx.x;
  int fr = lane & 15, g = lane >> 4;
  int wr = (wv >> 1) * 64, wc = (wv & 1) * 64;
  int srow = wv * 32 + (lane >> 3);
  int sslot = lane & 7;
  const ushort* Abase = A + (size_t)(bm * 128) * K;
  const ushort* Bbase = Bt + (size_t)(bn * 128) * K;

  f32x4 acc[4][4] = {};
  for (int k0 = 0; k0 < K; k0 += 64) {
#pragma unroll
    for (int j = 0; j < 4; j++) {
      int r = srow + j * 8;
      int kc = sslot ^ (r & 7);
      gload_lds16(Abase + (size_t)r * K + k0 + kc * 8, As + (wv * 256 + j * 64) * 8);
      gload_lds16(Bbase + (size_t)r * K + k0 + kc * 8, Bs + (wv * 256 + j * 64) * 8);
    }
    __syncthreads();
#pragma unroll
    for (int ks = 0; ks < 2; ks++) {
      bf16x8 af[4], bf[4];
#pragma unroll
      for (int mm = 0; mm < 4; mm++) {
        int row = wr + mm * 16 + fr;
        af[mm] = *(const bf16x8*)(As + row * 64 + (((ks * 4 + g) ^ (row & 7)) * 8));
      }
#pragma unroll
      for (int nn = 0; nn < 4; nn++) {
        int row = wc + nn * 16 + fr;
        bf[nn] = *(const bf16x8*)(Bs + row * 64 + (((ks * 4 + g) ^ (row & 7)) * 8));
      }
#pragma unroll
      for (int mm = 0; mm < 4; mm++)
#pragma unroll
        for (int nn = 0; nn < 4; nn++)
          acc[mm][nn] = __builtin_amdgcn_mfma_f32_16x16x32_bf16(af[mm], bf[nn], acc[mm][nn], 0, 0, 0);
    }
    __syncthreads();
  }

  int NH = N >> 1;
#pragma unroll
  for (int mm = 0; mm < 4; mm++)
#pragma unroll
    for (int nn = 0; nn < 4; nn++)
#pragma unroll
      for (int i = 0; i < 4; i++) {
        int gr = bm * 128 + wr + mm * 16 + g * 4 + i;
        int gc = bn * 128 + wc + nn * 16 + fr;
        if (MODE == 2) {
          float v = acc[mm][nn][i] + bias[(gc & 1) ? (NH + (gc >> 1)) : (gc >> 1)];
          float gv = __shfl_down(v, 1);
          if (!(fr & 1)) {
            float res = v * 0.5f * gv * (1.f + erff(gv * 0.70710678f));
            outB[(size_t)gr * NH + (gc >> 1)] = f2bf(res);
          }
        } else {
          float val = acc[mm][nn][i] + (bias ? bias[gc] : 0.f);
          if (MODE == 0) outB[(size_t)gr * N + gc] = f2bf(val);
          else resOut[(size_t)gr * N + gc] = resIn[(size_t)gr * N + gc] + val;
        }
      }
}

// ------- 128x64 GEMM, BK=64, single-buffer, 24 KB LDS (high occupancy) -------
// For small-N shapes (N=128..512): grid = (N/64, M/128) -> 2-4x more blocks
// than the 128x128 tiling, ~6 blocks/CU for cross-block latency hiding.
// Wave grid 2x2: each wave computes 64x32 (acc[4][2]).
template<int MODE>
__global__ __launch_bounds__(256) void gemm128x64(const ushort* __restrict__ A,
    const ushort* __restrict__ Bt, const float* __restrict__ bias,
    const float* __restrict__ resIn, float* __restrict__ resOut,
    ushort* __restrict__ outB, int M, int N, int K) {
  __shared__ __align__(16) ushort As[128 * 64];   // 16 KB
  __shared__ __align__(16) ushort Bs[64 * 64];    //  8 KB
  int t = threadIdx.x, wv = t >> 6, lane = t & 63;
  int bm = blockIdx.y, bn = blockIdx.x;
  int fr = lane & 15, g = lane >> 4;
  int wr = (wv >> 1) * 64, wc = (wv & 1) * 32;
  const ushort* Abase = A + (size_t)(bm * 128) * K;
  const ushort* Bbase = Bt + (size_t)(bn * 64) * K;

  f32x4 acc[4][2] = {};
  for (int k0 = 0; k0 < K; k0 += 64) {
    // A: 1024 chunks of 16B, 4 per thread; B: 512 chunks, 2 per thread.
#pragma unroll
    for (int j = 0; j < 4; j++) {
      int c = j * 256 + wv * 64 + lane;      // lane-contiguous per wave
      int r = c >> 3, s = c & 7;
      int kc = s ^ (r & 7);
      gload_lds16(Abase + (size_t)r * K + k0 + kc * 8, As + (j * 256 + wv * 64) * 8);
      if (j < 2)
        gload_lds16(Bbase + (size_t)r * K + k0 + kc * 8, Bs + (j * 256 + wv * 64) * 8);
    }
    __syncthreads();
#pragma unroll
    for (int ks = 0; ks < 2; ks++) {
      bf16x8 af[4], bf[2];
#pragma unroll
      for (int mm = 0; mm < 4; mm++) {
        int row = wr + mm * 16 + fr;
        af[mm] = *(const bf16x8*)(As + row * 64 + (((ks * 4 + g) ^ (row & 7)) * 8));
      }
#pragma unroll
      for (int nn = 0; nn < 2; nn++) {
        int row = wc + nn * 16 + fr;
        bf[nn] = *(const bf16x8*)(Bs + row * 64 + (((ks * 4 + g) ^ (row & 7)) * 8));
      }
#pragma unroll
      for (int mm = 0; mm < 4; mm++)
#pragma unroll
        for (int nn = 0; nn < 2; nn++)
          acc[mm][nn] = __builtin_amdgcn_mfma_f32_16x16x32_bf16(af[mm], bf[nn], acc[mm][nn], 0, 0, 0);
    }
    __syncthreads();
  }

#pragma unroll
  for (int mm = 0; mm < 4; mm++)
#pragma unroll
    for (int nn = 0; nn < 2; nn++)
#pragma unroll
      for (int i = 0; i < 4; i++) {
        int gr = bm * 128 + wr + mm * 16 + g * 4 + i;
        int gc = bn * 64 + wc + nn * 16 + fr;
        float val = acc[mm][nn][i] + (bias ? bias[gc] : 0.f);
        if (MODE == 0) outB[(size_t)gr * N + gc] = f2bf(val);
        else resOut[(size_t)gr * N + gc] = resIn[(size_t)gr * N + gc] + val;
      }
}

// ---------------- bf16 MFMA GEMM, 64x64 tile (q-proj only) -------------------
template<int MODE>
__global__ __launch_bounds__(256) void gemm64(const ushort* __restrict__ A,
    const ushort* __restrict__ Bt, const float* __restrict__ bias,
    float* __restrict__ resF, ushort* __restrict__ outB,
    int M, int N, int K) {
  __shared__ __align__(16) ushort As[64][40];
  __shared__ __align__(16) ushort Bs[64][40];
  int t = threadIdx.x;
  int bm = blockIdx.y, bn = blockIdx.x;
  int row = t >> 2, kc = (t & 3) << 3;
  const ushort* aG = A + (size_t)(bm * 64 + row) * K + kc;
  const ushort* bG = Bt + (size_t)(bn * 64 + row) * K + kc;
  int wv = t >> 6, lane = t & 63;
  int wr = (wv >> 1) * 32, wc = (wv & 1) * 32;
  int fr = lane & 15, fk = (lane >> 4) << 3;
  f32x4 acc[2][2] = {};
  for (int k0 = 0; k0 < K; k0 += 32) {
    *(uint4*)&As[row][kc] = *(const uint4*)(aG + k0);
    *(uint4*)&Bs[row][kc] = *(const uint4*)(bG + k0);
    __syncthreads();
    bf16x8 a0 = *(const bf16x8*)&As[wr + fr][fk];
    bf16x8 a1 = *(const bf16x8*)&As[wr + 16 + fr][fk];
    bf16x8 b0 = *(const bf16x8*)&Bs[wc + fr][fk];
    bf16x8 b1 = *(const bf16x8*)&Bs[wc + 16 + fr][fk];
    acc[0][0] = __builtin_amdgcn_mfma_f32_16x16x32_bf16(a0, b0, acc[0][0], 0, 0, 0);
    acc[0][1] = __builtin_amdgcn_mfma_f32_16x16x32_bf16(a0, b1, acc[0][1], 0, 0, 0);
    acc[1][0] = __builtin_amdgcn_mfma_f32_16x16x32_bf16(a1, b0, acc[1][0], 0, 0, 0);
    acc[1][1] = __builtin_amdgcn_mfma_f32_16x16x32_bf16(a1, b1, acc[1][1], 0, 0, 0);
    __syncthreads();
  }
  int cr0 = wr + ((lane >> 4) << 2);
  int cc0 = wc + fr;
#pragma unroll
  for (int mm = 0; mm < 2; mm++)
#pragma unroll
    for (int nn = 0; nn < 2; nn++)
#pragma unroll
      for (int i = 0; i < 4; i++) {
        int gr = bm * 64 + cr0 + mm * 16 + i;
        int gc = bn * 64 + cc0 + nn * 16;
        float val = acc[mm][nn][i] + (bias ? bias[gc] : 0.f);
        if (MODE == 0) outB[(size_t)gr * N + gc] = f2bf(val);
        else resF[(size_t)gr * N + gc] = resF[(size_t)gr * N + gc] + val;
      }
}

// ---------------- elementwise rotary (in place on bf16 buffer) ---------------
__global__ __launch_bounds__(256) void rope_apply(ushort* __restrict__ buf,
    const float* __restrict__ fr, int rows, int stride, int colOff, int H, float scale) {
  int idx = blockIdx.x * 256 + threadIdx.x;
  int total = rows * H * 32;
  if (idx >= total) return;
  int p = idx & 31;
  int h = (idx >> 5) % H;
  int r = idx / (32 * H);
  float f0 = fr[(size_t)r * DHc + 2 * p];
  float f1 = fr[(size_t)r * DHc + 2 * p + 1];
  ushort* bp = buf + (size_t)r * stride + colOff + h * DHc + 2 * p;
  float x0 = bf2f(bp[0]), x1 = bf2f(bp[1]);
  float o0 = (x0 * __cosf(f0) - x1 * __sinf(f0)) * scale;
  float o1 = (x1 * __cosf(f1) + x0 * __sinf(f1)) * scale;
  bp[0] = f2bf(o0); bp[1] = f2bf(o1);
}

// ---------------- MFMA flash attention ---------------------------------------
template<int CAUSAL>
__global__ __launch_bounds__(256) void attn_mfma(
    const ushort* __restrict__ Q, const ushort* __restrict__ K,
    const ushort* __restrict__ Vt, ushort* __restrict__ O,
    int qStride, int kStride, int kOff, int oStride,
    int Tq, int NK, int H) {
  __shared__ __align__(16) ushort Ks[64 * 64];
  __shared__ __align__(16) ushort Vs[64 * 64];
  __shared__ __align__(16) ushort Ps[4][16 * 72];
  int b = blockIdx.z, h = blockIdx.y, qt = blockIdx.x;
  int t = threadIdx.x, wv = t >> 6, lane = t & 63;
  int g = lane >> 4, fr = lane & 15;
  int qw = qt * 64 + wv * 16;
  int HD = H * 64;

  const ushort* qrow = Q + (size_t)(b * Tq + qw + fr) * qStride + h * 64;
  bf16x8 qlo = *(const bf16x8*)(qrow + g * 8);
  bf16x8 qhi = *(const bf16x8*)(qrow + 32 + g * 8);

  f32x4 o_acc[4] = {};
  float m_run[4], l_run[4];
#pragma unroll
  for (int i = 0; i < 4; i++) { m_run[i] = -1e30f; l_run[i] = 0.f; }

  ushort* Pw = &Ps[wv][0];
  int ntiles = CAUSAL ? (qt + 1) : (NK / 64);
  for (int kt = 0; kt < ntiles; kt++) {
    int k0 = kt * 64;
    __syncthreads();
#pragma unroll
    for (int i = 0; i < 2; i++) {
      int id = t + i * 256;
      int r = id >> 3, c = id & 7;
      uint4 kval = *(const uint4*)(K + (size_t)(b * NK + k0 + r) * kStride + kOff + h * 64 + c * 8);
      *(uint4*)(Ks + r * 64 + ((c ^ (r & 7)) * 8)) = kval;
      uint4 vval = *(const uint4*)(Vt + ((size_t)b * HD + h * 64 + r) * NK + k0 + c * 8);
      *(uint4*)(Vs + r * 64 + ((c ^ (r & 7)) * 8)) = vval;
    }
    __syncthreads();

    f32x4 s[4];
#pragma unroll
    for (int nn = 0; nn < 4; nn++) {
      int row = nn * 16 + fr;
      bf16x8 kf0 = *(const bf16x8*)(Ks + row * 64 + ((g ^ (fr & 7)) * 8));
      bf16x8 kf1 = *(const bf16x8*)(Ks + row * 64 + (((4 + g) ^ (fr & 7)) * 8));
      f32x4 z = {};
      z = __builtin_amdgcn_mfma_f32_16x16x32_bf16(qlo, kf0, z, 0, 0, 0);
      z = __builtin_amdgcn_mfma_f32_16x16x32_bf16(qhi, kf1, z, 0, 0, 0);
      s[nn] = z;
    }
    if (CAUSAL && (k0 + 63 > qw)) {
#pragma unroll
      for (int nn = 0; nn < 4; nn++)
#pragma unroll
        for (int i = 0; i < 4; i++)
          if (k0 + nn * 16 + fr > qw + g * 4 + i) s[nn][i] = -1e30f;
    }
#pragma unroll
    for (int i = 0; i < 4; i++) {
      float tm = fmaxf(fmaxf(s[0][i], s[1][i]), fmaxf(s[2][i], s[3][i]));
#pragma unroll
      for (int off = 8; off; off >>= 1) tm = fmaxf(tm, __shfl_xor(tm, off));
      float mnew = fmaxf(m_run[i], tm);
      float corr = __expf(m_run[i] - mnew);
      float ps = 0.f;
#pragma unroll
      for (int nn = 0; nn < 4; nn++) {
        float p = __expf(s[nn][i] - mnew);
        s[nn][i] = p;
        ps += p;
      }
#pragma unroll
      for (int off = 8; off; off >>= 1) ps += __shfl_xor(ps, off);
      l_run[i] = l_run[i] * corr + ps;
      m_run[i] = mnew;
#pragma unroll
      for (int dd = 0; dd < 4; dd++) o_acc[dd][i] *= corr;
    }
#pragma unroll
    for (int nn = 0; nn < 4; nn++)
#pragma unroll
      for (int i = 0; i < 4; i++)
        Pw[(g * 4 + i) * 72 + nn * 16 + fr] = f2bf(s[nn][i]);
    bf16x8 pa0 = *(const bf16x8*)(Pw + fr * 72 + g * 8);
    bf16x8 pa1 = *(const bf16x8*)(Pw + fr * 72 + 32 + g * 8);
#pragma unroll
    for (int dd = 0; dd < 4; dd++) {
      int row = dd * 16 + fr;
      bf16x8 vf0 = *(const bf16x8*)(Vs + row * 64 + ((g ^ (fr & 7)) * 8));
      bf16x8 vf1 = *(const bf16x8*)(Vs + row * 64 + (((4 + g) ^ (fr & 7)) * 8));
      o_acc[dd] = __builtin_amdgcn_mfma_f32_16x16x32_bf16(pa0, vf0, o_acc[dd], 0, 0, 0);
      o_acc[dd] = __builtin_amdgcn_mfma_f32_16x16x32_bf16(pa1, vf1, o_acc[dd], 0, 0, 0);
    }
  }
#pragma unroll
  for (int dd = 0; dd < 4; dd++)
#pragma unroll
    for (int i = 0; i < 4; i++) {
      size_t oidx = (size_t)(b * Tq + qw + g * 4 + i) * oStride + h * 64 + dd * 16 + fr;
      O[oidx] = f2bf(o_acc[dd][i] / l_run[i]);
    }
}

// ---------------- orchestration ----------------------------------------------
extern "C" void kernel_launch(void* const* d_in, const int* in_sizes, int n_in,
                              void* d_out, int out_size, void* d_ws, size_t ws_size,
                              hipStream_t stream) {
  const float* bin_queries = (const float*)d_in[0];
  const float* bin_time    = (const float*)d_in[1];
  const float* latents     = (const float*)d_in[2];
  const float* lat_time    = (const float*)d_in[3];
  const float* ca_lnq_w = (const float*)d_in[4];
  const float* ca_lnq_b = (const float*)d_in[5];
  const float* ca_lnc_w = (const float*)d_in[6];
  const float* ca_lnc_b = (const float*)d_in[7];
  const float* ca_wq  = (const float*)d_in[8];
  const float* ca_wkv = (const float*)d_in[9];
  const float* ca_wo  = (const float*)d_in[10];
  const float* ca_bo  = (const float*)d_in[11];
  const float* sa_ln_w = (const float*)d_in[12];
  const float* sa_ln_b = (const float*)d_in[13];
  const float* sa_wqkv = (const float*)d_in[14];
  const float* sa_wo   = (const float*)d_in[15];
  const float* sa_bo   = (const float*)d_in[16];
  const float* ffn_ln_w = (const float*)d_in[17];
  const float* ffn_ln_b = (const float*)d_in[18];
  const float* ffn_w1 = (const float*)d_in[19];
  const float* ffn_b1 = (const float*)d_in[20];
  const float* ffn_w2 = (const float*)d_in[21];
  const float* ffn_b2 = (const float*)d_in[22];

  constexpr size_t X_BYTES = (size_t)RQ * DIMc * 4;
  char* ws = (char*)d_ws;
  float* x = (float*)ws;
  char* A0 = ws + X_BYTES;
  // cross-attn phase
  ushort* cn     = (ushort*)(A0);
  ushort* ca_xn  = (ushort*)(A0 + 16777216);
  ushort* qbuf   = (ushort*)(A0 + 25165824);
  ushort* kv     = (ushort*)(A0 + 27262976);
  ushort* ca_att = (ushort*)(A0 + 35651584);
  ushort* vt_c   = (ushort*)(A0 + 37748736);
  // self-attn phase (reuses arena)
  ushort* sa_xn  = (ushort*)(A0);
  ushort* qkv    = (ushort*)(A0 + 8388608);
  ushort* sa_att = (ushort*)(A0 + 33554432);
  ushort* vt_s   = (ushort*)(A0 + 41943040);
  // ffn phase (reuses arena)
  ushort* hb     = (ushort*)(A0);
  ushort* ag     = (ushort*)(A0 + 8388608);   // 32 MB (fused gelu output)
  // bf16 transposed weights for the current layer
  char* W0 = A0 + 109051904;
  ushort* wbase = (ushort*)W0;
  ushort* wqT  = wbase;
  ushort* wkvT = wbase + 65536;
  ushort* woT  = wbase + 196608;
  ushort* qkvT = wbase + 262144;
  ushort* swoT = wbase + 1048576;
  ushort* w1T  = wbase + 1310720;
  ushort* w2T  = wbase + 3407872;

  hipMemcpyAsync(x, bin_queries, X_BYTES, hipMemcpyDeviceToDevice, stream);

  for (int l = 0; l < 2; l++) {
    wtrans_all<<<4352, 256, 0, stream>>>(ca_wq, ca_wkv, ca_wo, sa_wqkv, sa_wo,
                                         ffn_w1, ffn_w2, wbase, l);

    // ---- cross attention ----
    ln_rows<<<RQ / 4, 256, 0, stream>>>(x, ca_lnq_w + l * DIMc, ca_lnq_b + l * DIMc, ca_xn, RQ);
    ln_rows<<<RL / 4, 256, 0, stream>>>(latents, ca_lnc_w + l * DIMc, ca_lnc_b + l * DIMc, cn, RL);
    gemm64<0><<<dim3(CIc / 64, RQ / 64), 256, 0, stream>>>(ca_xn, wqT, nullptr, nullptr, qbuf, RQ, CIc, DIMc);
    gemm128x64<0><<<dim3(2 * CIc / 64, RL / 128), 256, 0, stream>>>(cn, wkvT, nullptr,
        nullptr, nullptr, kv, RL, 2 * CIc, DIMc);
    rope_apply<<<(RQ * CHc * 32) / 256, 256, 0, stream>>>(qbuf, bin_time, RQ, CIc, 0, CHc, 0.125f);
    rope_apply<<<(RL * CHc * 32) / 256, 256, 0, stream>>>(kv, lat_time, RL, 2 * CIc, 0, CHc, 1.f);
    vtrans<<<dim3(Nc / 32, CHc * 64 / 32, Bc), 256, 0, stream>>>(kv, vt_c, Nc, 2 * CIc, CIc);
    attn_mfma<0><<<dim3(Tc / 64, CHc, Bc), 256, 0, stream>>>(qbuf, kv, vt_c, ca_att,
        CIc, 2 * CIc, 0, CIc, Tc, Nc, CHc);
    gemm128x64<1><<<dim3(DIMc / 64, RQ / 128), 256, 0, stream>>>(ca_att, woT, ca_bo + l * DIMc,
        x, x, nullptr, RQ, DIMc, CIc);

    // ---- self attention (causal) ----
    ln_rows<<<RQ / 4, 256, 0, stream>>>(x, sa_ln_w + l * DIMc, sa_ln_b + l * DIMc, sa_xn, RQ);
    gemm128<0><<<dim3(3 * SIc / 128, RQ / 128), 256, 0, stream>>>(sa_xn, qkvT, nullptr,
        nullptr, nullptr, qkv, RQ, 3 * SIc, DIMc);
    rope_apply<<<(RQ * SHc * 32) / 256, 256, 0, stream>>>(qkv, bin_time, RQ, 3 * SIc, 0, SHc, 0.125f);
    rope_apply<<<(RQ * SHc * 32) / 256, 256, 0, stream>>>(qkv, bin_time, RQ, 3 * SIc, SIc, SHc, 1.f);
    vtrans<<<dim3(Tc / 32, SHc * 64 / 32, Bc), 256, 0, stream>>>(qkv, vt_s, Tc, 3 * SIc, 2 * SIc);
    attn_mfma<1><<<dim3(Tc / 64, SHc, Bc), 256, 0, stream>>>(qkv, qkv, vt_s, sa_att,
        3 * SIc, 3 * SIc, SIc, SIc, Tc, Tc, SHc);
    gemm128x64<1><<<dim3(DIMc / 64, RQ / 128), 256, 0, stream>>>(sa_att, swoT, sa_bo + l * DIMc,
        x, x, nullptr, RQ, DIMc, SIc);

    // ---- FFN (w1 with fused bias + a*gelu(g) epilogue) ----
    ln_rows<<<RQ / 4, 256, 0, stream>>>(x, ffn_ln_w + l * DIMc, ffn_ln_b + l * DIMc, hb, RQ);
    gemm128<2><<<dim3(2 * FFc / 128, RQ / 128), 256, 0, stream>>>(hb, w1T,
        ffn_b1 + (size_t)l * 2 * FFc, nullptr, nullptr, ag, RQ, 2 * FFc, DIMc);
    float* resOut = (l == 1) ? (float*)d_out : x;
    gemm128x64<1><<<dim3(DIMc / 64, RQ / 128), 256, 0, stream>>>(ag, w2T, ffn_b2 + l * DIMc,
        x, resOut, nullptr, RQ, DIMc, FFc);
  }
}

// Round 8
// 734.009 us; speedup vs baseline: 13.9719x; 1.0313x over previous
//
#include <hip/hip_runtime.h>
#include <cstdint>
#include <cstddef>

// ---------------- constants (match reference) ----------------
static constexpr int DIMc = 512;
static constexpr int DHc  = 64;
static constexpr int CHc  = 2;
static constexpr int SHc  = 8;
static constexpr int Bc   = 8;
static constexpr int Tc   = 1024;
static constexpr int Nc   = 2048;
static constexpr int CIc  = CHc * DHc;    // 128
static constexpr int SIc  = SHc * DHc;    // 512
static constexpr int FFc  = 4 * DIMc;     // 2048
static constexpr int RQ   = Bc * Tc;      // 8192 query rows
static constexpr int RL   = Bc * Nc;      // 16384 latent rows

typedef short bf16x8 __attribute__((ext_vector_type(8)));
typedef float f32x4  __attribute__((ext_vector_type(4)));

__device__ __forceinline__ ushort f2bf(float f) {
  uint32_t u = __builtin_bit_cast(uint32_t, f);
  u += 0x7fffu + ((u >> 16) & 1u);
  return (ushort)(u >> 16);
}
__device__ __forceinline__ float bf2f(ushort h) {
  uint32_t u = ((uint32_t)h) << 16;
  return __builtin_bit_cast(float, u);
}

__device__ __forceinline__ void gload_lds16(const ushort* g, ushort* lds) {
  __builtin_amdgcn_global_load_lds(
      (const __attribute__((address_space(1))) void*)g,
      (__attribute__((address_space(3))) void*)lds, 16, 0, 0);
}

// fast gelu: tanh form; |err| < 3e-3 abs, well under the bf16 tolerance.
__device__ __forceinline__ float gelu_fast(float g) {
  float u = g * (0.7978845608f + 0.0356774081f * g * g);   // 0.79788*(g+0.044715 g^3)
  float e = __expf(2.f * u);
  float th = 1.f - 2.f * __builtin_amdgcn_rcpf(1.f + e);
  return 0.5f * g * (1.f + th);
}

// ---------------- LayerNorm: one wave per 512-col row, fp32 in -> bf16 out ----
__global__ __launch_bounds__(256) void ln_rows(const float* __restrict__ X,
    const float* __restrict__ w, const float* __restrict__ b,
    ushort* __restrict__ out, int rows) {
  int gw = (int)((blockIdx.x * 256 + threadIdx.x) >> 6);
  int lane = threadIdx.x & 63;
  if (gw >= rows) return;
  const float* xr = X + (size_t)gw * DIMc;
  float4 v0 = *(const float4*)(xr + lane * 8);
  float4 v1 = *(const float4*)(xr + lane * 8 + 4);
  float xv[8] = {v0.x, v0.y, v0.z, v0.w, v1.x, v1.y, v1.z, v1.w};
  float s = 0.f, ss = 0.f;
#pragma unroll
  for (int i = 0; i < 8; i++) { s += xv[i]; ss += xv[i] * xv[i]; }
#pragma unroll
  for (int off = 32; off; off >>= 1) { s += __shfl_xor(s, off); ss += __shfl_xor(ss, off); }
  float mean = s * (1.f / DIMc);
  float var = ss * (1.f / DIMc) - mean * mean;
  float r = rsqrtf(var + 1e-5f);
  int c = lane * 8;
  ushort o[8] __attribute__((aligned(16)));
#pragma unroll
  for (int i = 0; i < 8; i++) o[i] = f2bf((xv[i] - mean) * r * w[c + i] + b[c + i]);
  *(uint4*)(out + (size_t)gw * DIMc + c) = *(const uint4*)o;
}

// ------------- ALL weight transposes for one layer, one launch ----------------
// wid 5 (ffn_w1): 16-col-granular interleave: original col n (a: n<2048,
// g: n>=2048), p = n & 2047 -> rowT = (p>>4)*32 + (n<2048 ? 0 : 16) + (p&15).
// So in the GEMM tile, nn-even 16-blocks are a-cols, nn-odd are the matching
// g-cols -> the fused-gelu epilogue needs NO cross-lane shuffle.
__global__ __launch_bounds__(256) void wtrans_all(
    const float* __restrict__ wq, const float* __restrict__ wkv,
    const float* __restrict__ wo, const float* __restrict__ qkv,
    const float* __restrict__ swo, const float* __restrict__ w1,
    const float* __restrict__ w2, ushort* __restrict__ dst, int layer) {
  constexpr int Ks[7]   = {512, 512, 128, 512, 512, 512, 2048};
  constexpr int Ns[7]   = {128, 256, 512, 1536, 512, 4096, 512};
  constexpr int pre[8]  = {0, 64, 192, 256, 1024, 1280, 3328, 4352};
  constexpr int dOff[7] = {0, 65536, 196608, 262144, 1048576, 1310720, 3407872};
  int bid = blockIdx.x;
  int wid = 0;
#pragma unroll
  for (int i = 1; i < 7; i++) wid += (bid >= pre[i]);
  int tileIdx = bid - pre[wid];
  int K = Ks[wid], N = Ns[wid];
  const float* srcs[7] = {wq, wkv, wo, qkv, swo, w1, w2};
  const float* W = srcs[wid] + (size_t)layer * K * N;
  ushort* Wt = dst + dOff[wid];
  int ntx = N / 32;
  int n0 = (tileIdx % ntx) * 32, k0 = (tileIdx / ntx) * 32;
  __shared__ float tile[32][33];
  int tx = threadIdx.x & 31, ty = threadIdx.x >> 5;
#pragma unroll
  for (int i = 0; i < 32; i += 8)
    tile[ty + i][tx] = W[(size_t)(k0 + ty + i) * N + n0 + tx];
  __syncthreads();
  if (wid == 5) {
#pragma unroll
    for (int i = 0; i < 32; i += 8) {
      int nrow = n0 + ty + i;
      int p = nrow & 2047;
      int rowT = ((p >> 4) << 5) + ((nrow < 2048) ? 0 : 16) + (p & 15);
      Wt[(size_t)rowT * K + k0 + tx] = f2bf(tile[tx][ty + i]);
    }
  } else {
#pragma unroll
    for (int i = 0; i < 32; i += 8)
      Wt[(size_t)(n0 + ty + i) * K + k0 + tx] = f2bf(tile[tx][ty + i]);
  }
}

// ---------------- bf16 V transpose: dst[b][hd][key] --------------------------
__global__ __launch_bounds__(256) void vtrans(const ushort* __restrict__ src,
    ushort* __restrict__ dst, int NK, int stride, int colOff) {
  __shared__ ushort tile[32][33];
  int b = blockIdx.z;
  int key0 = blockIdx.x * 32, hd0 = blockIdx.y * 32;
  int HD = gridDim.y * 32;
  int tx = threadIdx.x & 31, ty = threadIdx.x >> 5;
#pragma unroll
  for (int i = 0; i < 32; i += 8)
    tile[ty + i][tx] = src[(size_t)(b * NK + key0 + ty + i) * stride + colOff + hd0 + tx];
  __syncthreads();
#pragma unroll
  for (int i = 0; i < 32; i += 8)
    dst[((size_t)b * HD + hd0 + ty + i) * NK + key0 + tx] = tile[tx][ty + i];
}

// ------- 128x128 GEMM, BK=64, single-buffer (proven r3 structure) ------------
// A: M x K bf16 row-major.  Bt: N x K bf16 row-major.
// LDS: row stride 64 bf16; 16B chunk at slot s of row r holds k-chunk s^(r&7).
// MODE 0: outB = bf16(acc + bias)
// MODE 1: resOut = resIn + acc + bias   (fp32)
// MODE 2: fused FFN gate, 16-col interleave (see wtrans_all): nn even = a,
//         nn odd = g of the same outputs; write bf16(a * gelu(g)), N_out=N/2.
template<int MODE>
__global__ __launch_bounds__(256) void gemm128(const ushort* __restrict__ A,
    const ushort* __restrict__ Bt, const float* __restrict__ bias,
    const float* __restrict__ resIn, float* __restrict__ resOut,
    ushort* __restrict__ outB, int M, int N, int K) {
  __shared__ __align__(16) ushort As[128 * 64];
  __shared__ __align__(16) ushort Bs[128 * 64];
  int t = threadIdx.x, wv = t >> 6, lane = t & 63;
  int bm = blockIdx.y, bn = blockIdx.x;
  int fr = lane & 15, g = lane >> 4;
  int wr = (wv >> 1) * 64, wc = (wv & 1) * 64;
  int srow = wv * 32 + (lane >> 3);
  int sslot = lane & 7;
  const ushort* Abase = A + (size_t)(bm * 128) * K;
  const ushort* Bbase = Bt + (size_t)(bn * 128) * K;

  f32x4 acc[4][4] = {};
  for (int k0 = 0; k0 < K; k0 += 64) {
#pragma unroll
    for (int j = 0; j < 4; j++) {
      int r = srow + j * 8;
      int kc = sslot ^ (r & 7);
      gload_lds16(Abase + (size_t)r * K + k0 + kc * 8, As + (wv * 256 + j * 64) * 8);
      gload_lds16(Bbase + (size_t)r * K + k0 + kc * 8, Bs + (wv * 256 + j * 64) * 8);
    }
    __syncthreads();
#pragma unroll
    for (int ks = 0; ks < 2; ks++) {
      bf16x8 af[4], bf[4];
#pragma unroll
      for (int mm = 0; mm < 4; mm++) {
        int row = wr + mm * 16 + fr;
        af[mm] = *(const bf16x8*)(As + row * 64 + (((ks * 4 + g) ^ (row & 7)) * 8));
      }
#pragma unroll
      for (int nn = 0; nn < 4; nn++) {
        int row = wc + nn * 16 + fr;
        bf[nn] = *(const bf16x8*)(Bs + row * 64 + (((ks * 4 + g) ^ (row & 7)) * 8));
      }
#pragma unroll
      for (int mm = 0; mm < 4; mm++)
#pragma unroll
        for (int nn = 0; nn < 4; nn++)
          acc[mm][nn] = __builtin_amdgcn_mfma_f32_16x16x32_bf16(af[mm], bf[nn], acc[mm][nn], 0, 0, 0);
    }
    __syncthreads();
  }

  if (MODE == 2) {
    int NH = N >> 1;
#pragma unroll
    for (int mm = 0; mm < 4; mm++)
#pragma unroll
      for (int np = 0; np < 2; np++) {
        int ocol = bn * 64 + (wc >> 1) + np * 16 + fr;
        float ba = bias[ocol];
        float bg = bias[NH + ocol];
#pragma unroll
        for (int i = 0; i < 4; i++) {
          int gr = bm * 128 + wr + mm * 16 + g * 4 + i;
          float a = acc[mm][np * 2][i] + ba;
          float gv = acc[mm][np * 2 + 1][i] + bg;
          outB[(size_t)gr * NH + ocol] = f2bf(a * gelu_fast(gv));
        }
      }
  } else {
#pragma unroll
    for (int mm = 0; mm < 4; mm++)
#pragma unroll
      for (int nn = 0; nn < 4; nn++)
#pragma unroll
        for (int i = 0; i < 4; i++) {
          int gr = bm * 128 + wr + mm * 16 + g * 4 + i;
          int gc = bn * 128 + wc + nn * 16 + fr;
          float val = acc[mm][nn][i] + (bias ? bias[gc] : 0.f);
          if (MODE == 0) outB[(size_t)gr * N + gc] = f2bf(val);
          else resOut[(size_t)gr * N + gc] = resIn[(size_t)gr * N + gc] + val;
        }
  }
}

// ------- 128x64 GEMM, BK=64, single-buffer, 24 KB LDS (high occupancy) -------
template<int MODE>
__global__ __launch_bounds__(256) void gemm128x64(const ushort* __restrict__ A,
    const ushort* __restrict__ Bt, const float* __restrict__ bias,
    const float* __restrict__ resIn, float* __restrict__ resOut,
    ushort* __restrict__ outB, int M, int N, int K) {
  __shared__ __align__(16) ushort As[128 * 64];   // 16 KB
  __shared__ __align__(16) ushort Bs[64 * 64];    //  8 KB
  int t = threadIdx.x, wv = t >> 6, lane = t & 63;
  int bm = blockIdx.y, bn = blockIdx.x;
  int fr = lane & 15, g = lane >> 4;
  int wr = (wv >> 1) * 64, wc = (wv & 1) * 32;
  const ushort* Abase = A + (size_t)(bm * 128) * K;
  const ushort* Bbase = Bt + (size_t)(bn * 64) * K;

  f32x4 acc[4][2] = {};
  for (int k0 = 0; k0 < K; k0 += 64) {
#pragma unroll
    for (int j = 0; j < 4; j++) {
      int c = j * 256 + wv * 64 + lane;
      int r = c >> 3, s = c & 7;
      int kc = s ^ (r & 7);
      gload_lds16(Abase + (size_t)r * K + k0 + kc * 8, As + (j * 256 + wv * 64) * 8);
      if (j < 2)
        gload_lds16(Bbase + (size_t)r * K + k0 + kc * 8, Bs + (j * 256 + wv * 64) * 8);
    }
    __syncthreads();
#pragma unroll
    for (int ks = 0; ks < 2; ks++) {
      bf16x8 af[4], bf[2];
#pragma unroll
      for (int mm = 0; mm < 4; mm++) {
        int row = wr + mm * 16 + fr;
        af[mm] = *(const bf16x8*)(As + row * 64 + (((ks * 4 + g) ^ (row & 7)) * 8));
      }
#pragma unroll
      for (int nn = 0; nn < 2; nn++) {
        int row = wc + nn * 16 + fr;
        bf[nn] = *(const bf16x8*)(Bs + row * 64 + (((ks * 4 + g) ^ (row & 7)) * 8));
      }
#pragma unroll
      for (int mm = 0; mm < 4; mm++)
#pragma unroll
        for (int nn = 0; nn < 2; nn++)
          acc[mm][nn] = __builtin_amdgcn_mfma_f32_16x16x32_bf16(af[mm], bf[nn], acc[mm][nn], 0, 0, 0);
    }
    __syncthreads();
  }

#pragma unroll
  for (int mm = 0; mm < 4; mm++)
#pragma unroll
    for (int nn = 0; nn < 2; nn++)
#pragma unroll
      for (int i = 0; i < 4; i++) {
        int gr = bm * 128 + wr + mm * 16 + g * 4 + i;
        int gc = bn * 64 + wc + nn * 16 + fr;
        float val = acc[mm][nn][i] + (bias ? bias[gc] : 0.f);
        if (MODE == 0) outB[(size_t)gr * N + gc] = f2bf(val);
        else resOut[(size_t)gr * N + gc] = resIn[(size_t)gr * N + gc] + val;
      }
}

// ---------------- bf16 MFMA GEMM, 64x64 tile (q-proj only) -------------------
template<int MODE>
__global__ __launch_bounds__(256) void gemm64(const ushort* __restrict__ A,
    const ushort* __restrict__ Bt, const float* __restrict__ bias,
    float* __restrict__ resF, ushort* __restrict__ outB,
    int M, int N, int K) {
  __shared__ __align__(16) ushort As[64][40];
  __shared__ __align__(16) ushort Bs[64][40];
  int t = threadIdx.x;
  int bm = blockIdx.y, bn = blockIdx.x;
  int row = t >> 2, kc = (t & 3) << 3;
  const ushort* aG = A + (size_t)(bm * 64 + row) * K + kc;
  const ushort* bG = Bt + (size_t)(bn * 64 + row) * K + kc;
  int wv = t >> 6, lane = t & 63;
  int wr = (wv >> 1) * 32, wc = (wv & 1) * 32;
  int fr = lane & 15, fk = (lane >> 4) << 3;
  f32x4 acc[2][2] = {};
  for (int k0 = 0; k0 < K; k0 += 32) {
    *(uint4*)&As[row][kc] = *(const uint4*)(aG + k0);
    *(uint4*)&Bs[row][kc] = *(const uint4*)(bG + k0);
    __syncthreads();
    bf16x8 a0 = *(const bf16x8*)&As[wr + fr][fk];
    bf16x8 a1 = *(const bf16x8*)&As[wr + 16 + fr][fk];
    bf16x8 b0 = *(const bf16x8*)&Bs[wc + fr][fk];
    bf16x8 b1 = *(const bf16x8*)&Bs[wc + 16 + fr][fk];
    acc[0][0] = __builtin_amdgcn_mfma_f32_16x16x32_bf16(a0, b0, acc[0][0], 0, 0, 0);
    acc[0][1] = __builtin_amdgcn_mfma_f32_16x16x32_bf16(a0, b1, acc[0][1], 0, 0, 0);
    acc[1][0] = __builtin_amdgcn_mfma_f32_16x16x32_bf16(a1, b0, acc[1][0], 0, 0, 0);
    acc[1][1] = __builtin_amdgcn_mfma_f32_16x16x32_bf16(a1, b1, acc[1][1], 0, 0, 0);
    __syncthreads();
  }
  int cr0 = wr + ((lane >> 4) << 2);
  int cc0 = wc + fr;
#pragma unroll
  for (int mm = 0; mm < 2; mm++)
#pragma unroll
    for (int nn = 0; nn < 2; nn++)
#pragma unroll
      for (int i = 0; i < 4; i++) {
        int gr = bm * 64 + cr0 + mm * 16 + i;
        int gc = bn * 64 + cc0 + nn * 16;
        float val = acc[mm][nn][i] + (bias ? bias[gc] : 0.f);
        if (MODE == 0) outB[(size_t)gr * N + gc] = f2bf(val);
        else resF[(size_t)gr * N + gc] = resF[(size_t)gr * N + gc] + val;
      }
}

// ---------------- elementwise rotary (in place on bf16 buffer) ---------------
__global__ __launch_bounds__(256) void rope_apply(ushort* __restrict__ buf,
    const float* __restrict__ fr, int rows, int stride, int colOff, int H, float scale) {
  int idx = blockIdx.x * 256 + threadIdx.x;
  int total = rows * H * 32;
  if (idx >= total) return;
  int p = idx & 31;
  int h = (idx >> 5) % H;
  int r = idx / (32 * H);
  float f0 = fr[(size_t)r * DHc + 2 * p];
  float f1 = fr[(size_t)r * DHc + 2 * p + 1];
  ushort* bp = buf + (size_t)r * stride + colOff + h * DHc + 2 * p;
  float x0 = bf2f(bp[0]), x1 = bf2f(bp[1]);
  float o0 = (x0 * __cosf(f0) - x1 * __sinf(f0)) * scale;
  float o1 = (x1 * __cosf(f1) + x0 * __sinf(f1)) * scale;
  bp[0] = f2bf(o0); bp[1] = f2bf(o1);
}

// ---------------- MFMA flash attention ---------------------------------------
template<int CAUSAL>
__global__ __launch_bounds__(256) void attn_mfma(
    const ushort* __restrict__ Q, const ushort* __restrict__ K,
    const ushort* __restrict__ Vt, ushort* __restrict__ O,
    int qStride, int kStride, int kOff, int oStride,
    int Tq, int NK, int H) {
  __shared__ __align__(16) ushort Ks[64 * 64];
  __shared__ __align__(16) ushort Vs[64 * 64];
  __shared__ __align__(16) ushort Ps[4][16 * 72];
  int b = blockIdx.z, h = blockIdx.y, qt = blockIdx.x;
  int t = threadIdx.x, wv = t >> 6, lane = t & 63;
  int g = lane >> 4, fr = lane & 15;
  int qw = qt * 64 + wv * 16;
  int HD = H * 64;

  const ushort* qrow = Q + (size_t)(b * Tq + qw + fr) * qStride + h * 64;
  bf16x8 qlo = *(const bf16x8*)(qrow + g * 8);
  bf16x8 qhi = *(const bf16x8*)(qrow + 32 + g * 8);

  f32x4 o_acc[4] = {};
  float m_run[4], l_run[4];
#pragma unroll
  for (int i = 0; i < 4; i++) { m_run[i] = -1e30f; l_run[i] = 0.f; }

  ushort* Pw = &Ps[wv][0];
  int ntiles = CAUSAL ? (qt + 1) : (NK / 64);
  for (int kt = 0; kt < ntiles; kt++) {
    int k0 = kt * 64;
    __syncthreads();
#pragma unroll
    for (int i = 0; i < 2; i++) {
      int id = t + i * 256;
      int r = id >> 3, c = id & 7;
      uint4 kval = *(const uint4*)(K + (size_t)(b * NK + k0 + r) * kStride + kOff + h * 64 + c * 8);
      *(uint4*)(Ks + r * 64 + ((c ^ (r & 7)) * 8)) = kval;
      uint4 vval = *(const uint4*)(Vt + ((size_t)b * HD + h * 64 + r) * NK + k0 + c * 8);
      *(uint4*)(Vs + r * 64 + ((c ^ (r & 7)) * 8)) = vval;
    }
    __syncthreads();

    f32x4 s[4];
#pragma unroll
    for (int nn = 0; nn < 4; nn++) {
      int row = nn * 16 + fr;
      bf16x8 kf0 = *(const bf16x8*)(Ks + row * 64 + ((g ^ (fr & 7)) * 8));
      bf16x8 kf1 = *(const bf16x8*)(Ks + row * 64 + (((4 + g) ^ (fr & 7)) * 8));
      f32x4 z = {};
      z = __builtin_amdgcn_mfma_f32_16x16x32_bf16(qlo, kf0, z, 0, 0, 0);
      z = __builtin_amdgcn_mfma_f32_16x16x32_bf16(qhi, kf1, z, 0, 0, 0);
      s[nn] = z;
    }
    if (CAUSAL && (k0 + 63 > qw)) {
#pragma unroll
      for (int nn = 0; nn < 4; nn++)
#pragma unroll
        for (int i = 0; i < 4; i++)
          if (k0 + nn * 16 + fr > qw + g * 4 + i) s[nn][i] = -1e30f;
    }
#pragma unroll
    for (int i = 0; i < 4; i++) {
      float tm = fmaxf(fmaxf(s[0][i], s[1][i]), fmaxf(s[2][i], s[3][i]));
#pragma unroll
      for (int off = 8; off; off >>= 1) tm = fmaxf(tm, __shfl_xor(tm, off));
      float mnew = fmaxf(m_run[i], tm);
      float corr = __expf(m_run[i] - mnew);
      float ps = 0.f;
#pragma unroll
      for (int nn = 0; nn < 4; nn++) {
        float p = __expf(s[nn][i] - mnew);
        s[nn][i] = p;
        ps += p;
      }
#pragma unroll
      for (int off = 8; off; off >>= 1) ps += __shfl_xor(ps, off);
      l_run[i] = l_run[i] * corr + ps;
      m_run[i] = mnew;
#pragma unroll
      for (int dd = 0; dd < 4; dd++) o_acc[dd][i] *= corr;
    }
#pragma unroll
    for (int nn = 0; nn < 4; nn++)
#pragma unroll
      for (int i = 0; i < 4; i++)
        Pw[(g * 4 + i) * 72 + nn * 16 + fr] = f2bf(s[nn][i]);
    bf16x8 pa0 = *(const bf16x8*)(Pw + fr * 72 + g * 8);
    bf16x8 pa1 = *(const bf16x8*)(Pw + fr * 72 + 32 + g * 8);
#pragma unroll
    for (int dd = 0; dd < 4; dd++) {
      int row = dd * 16 + fr;
      bf16x8 vf0 = *(const bf16x8*)(Vs + row * 64 + ((g ^ (fr & 7)) * 8));
      bf16x8 vf1 = *(const bf16x8*)(Vs + row * 64 + (((4 + g) ^ (fr & 7)) * 8));
      o_acc[dd] = __builtin_amdgcn_mfma_f32_16x16x32_bf16(pa0, vf0, o_acc[dd], 0, 0, 0);
      o_acc[dd] = __builtin_amdgcn_mfma_f32_16x16x32_bf16(pa1, vf1, o_acc[dd], 0, 0, 0);
    }
  }
#pragma unroll
  for (int dd = 0; dd < 4; dd++)
#pragma unroll
    for (int i = 0; i < 4; i++) {
      size_t oidx = (size_t)(b * Tq + qw + g * 4 + i) * oStride + h * 64 + dd * 16 + fr;
      O[oidx] = f2bf(o_acc[dd][i] / l_run[i]);
    }
}

// ---------------- orchestration ----------------------------------------------
extern "C" void kernel_launch(void* const* d_in, const int* in_sizes, int n_in,
                              void* d_out, int out_size, void* d_ws, size_t ws_size,
                              hipStream_t stream) {
  const float* bin_queries = (const float*)d_in[0];
  const float* bin_time    = (const float*)d_in[1];
  const float* latents     = (const float*)d_in[2];
  const float* lat_time    = (const float*)d_in[3];
  const float* ca_lnq_w = (const float*)d_in[4];
  const float* ca_lnq_b = (const float*)d_in[5];
  const float* ca_lnc_w = (const float*)d_in[6];
  const float* ca_lnc_b = (const float*)d_in[7];
  const float* ca_wq  = (const float*)d_in[8];
  const float* ca_wkv = (const float*)d_in[9];
  const float* ca_wo  = (const float*)d_in[10];
  const float* ca_bo  = (const float*)d_in[11];
  const float* sa_ln_w = (const float*)d_in[12];
  const float* sa_ln_b = (const float*)d_in[13];
  const float* sa_wqkv = (const float*)d_in[14];
  const float* sa_wo   = (const float*)d_in[15];
  const float* sa_bo   = (const float*)d_in[16];
  const float* ffn_ln_w = (const float*)d_in[17];
  const float* ffn_ln_b = (const float*)d_in[18];
  const float* ffn_w1 = (const float*)d_in[19];
  const float* ffn_b1 = (const float*)d_in[20];
  const float* ffn_w2 = (const float*)d_in[21];
  const float* ffn_b2 = (const float*)d_in[22];

  constexpr size_t X_BYTES = (size_t)RQ * DIMc * 4;
  char* ws = (char*)d_ws;
  float* x = (float*)ws;
  char* A0 = ws + X_BYTES;
  // cross-attn phase
  ushort* cn     = (ushort*)(A0);
  ushort* ca_xn  = (ushort*)(A0 + 16777216);
  ushort* qbuf   = (ushort*)(A0 + 25165824);
  ushort* kv     = (ushort*)(A0 + 27262976);
  ushort* ca_att = (ushort*)(A0 + 35651584);
  ushort* vt_c   = (ushort*)(A0 + 37748736);
  // self-attn phase (reuses arena)
  ushort* sa_xn  = (ushort*)(A0);
  ushort* qkv    = (ushort*)(A0 + 8388608);
  ushort* sa_att = (ushort*)(A0 + 33554432);
  ushort* vt_s   = (ushort*)(A0 + 41943040);
  // ffn phase (reuses arena)
  ushort* hb     = (ushort*)(A0);
  ushort* ag     = (ushort*)(A0 + 8388608);   // 32 MB (fused gelu output)
  // bf16 transposed weights for the current layer
  char* W0 = A0 + 109051904;
  ushort* wbase = (ushort*)W0;
  ushort* wqT  = wbase;
  ushort* wkvT = wbase + 65536;
  ushort* woT  = wbase + 196608;
  ushort* qkvT = wbase + 262144;
  ushort* swoT = wbase + 1048576;
  ushort* w1T  = wbase + 1310720;
  ushort* w2T  = wbase + 3407872;

  hipMemcpyAsync(x, bin_queries, X_BYTES, hipMemcpyDeviceToDevice, stream);

  for (int l = 0; l < 2; l++) {
    wtrans_all<<<4352, 256, 0, stream>>>(ca_wq, ca_wkv, ca_wo, sa_wqkv, sa_wo,
                                         ffn_w1, ffn_w2, wbase, l);

    // ---- cross attention ----
    ln_rows<<<RQ / 4, 256, 0, stream>>>(x, ca_lnq_w + l * DIMc, ca_lnq_b + l * DIMc, ca_xn, RQ);
    ln_rows<<<RL / 4, 256, 0, stream>>>(latents, ca_lnc_w + l * DIMc, ca_lnc_b + l * DIMc, cn, RL);
    gemm64<0><<<dim3(CIc / 64, RQ / 64), 256, 0, stream>>>(ca_xn, wqT, nullptr, nullptr, qbuf, RQ, CIc, DIMc);
    gemm128x64<0><<<dim3(2 * CIc / 64, RL / 128), 256, 0, stream>>>(cn, wkvT, nullptr,
        nullptr, nullptr, kv, RL, 2 * CIc, DIMc);
    rope_apply<<<(RQ * CHc * 32) / 256, 256, 0, stream>>>(qbuf, bin_time, RQ, CIc, 0, CHc, 0.125f);
    rope_apply<<<(RL * CHc * 32) / 256, 256, 0, stream>>>(kv, lat_time, RL, 2 * CIc, 0, CHc, 1.f);
    vtrans<<<dim3(Nc / 32, CHc * 64 / 32, Bc), 256, 0, stream>>>(kv, vt_c, Nc, 2 * CIc, CIc);
    attn_mfma<0><<<dim3(Tc / 64, CHc, Bc), 256, 0, stream>>>(qbuf, kv, vt_c, ca_att,
        CIc, 2 * CIc, 0, CIc, Tc, Nc, CHc);
    gemm128x64<1><<<dim3(DIMc / 64, RQ / 128), 256, 0, stream>>>(ca_att, woT, ca_bo + l * DIMc,
        x, x, nullptr, RQ, DIMc, CIc);

    // ---- self attention (causal) ----
    ln_rows<<<RQ / 4, 256, 0, stream>>>(x, sa_ln_w + l * DIMc, sa_ln_b + l * DIMc, sa_xn, RQ);
    gemm128<0><<<dim3(3 * SIc / 128, RQ / 128), 256, 0, stream>>>(sa_xn, qkvT, nullptr,
        nullptr, nullptr, qkv, RQ, 3 * SIc, DIMc);
    rope_apply<<<(RQ * SHc * 32) / 256, 256, 0, stream>>>(qkv, bin_time, RQ, 3 * SIc, 0, SHc, 0.125f);
    rope_apply<<<(RQ * SHc * 32) / 256, 256, 0, stream>>>(qkv, bin_time, RQ, 3 * SIc, SIc, SHc, 1.f);
    vtrans<<<dim3(Tc / 32, SHc * 64 / 32, Bc), 256, 0, stream>>>(qkv, vt_s, Tc, 3 * SIc, 2 * SIc);
    attn_mfma<1><<<dim3(Tc / 64, SHc, Bc), 256, 0, stream>>>(qkv, qkv, vt_s, sa_att,
        3 * SIc, 3 * SIc, SIc, SIc, Tc, Tc, SHc);
    gemm128x64<1><<<dim3(DIMc / 64, RQ / 128), 256, 0, stream>>>(sa_att, swoT, sa_bo + l * DIMc,
        x, x, nullptr, RQ, DIMc, SIc);

    // ---- FFN (w1 with fused bias + a*gelu(g) epilogue, shuffle-free) ----
    ln_rows<<<RQ / 4, 256, 0, stream>>>(x, ffn_ln_w + l * DIMc, ffn_ln_b + l * DIMc, hb, RQ);
    gemm128<2><<<dim3(2 * FFc / 128, RQ / 128), 256, 0, stream>>>(hb, w1T,
        ffn_b1 + (size_t)l * 2 * FFc, nullptr, nullptr, ag, RQ, 2 * FFc, DIMc);
    float* resOut = (l == 1) ? (float*)d_out : x;
    gemm128x64<1><<<dim3(DIMc / 64, RQ / 128), 256, 0, stream>>>(ag, w2T, ffn_b2 + l * DIMc,
        x, resOut, nullptr, RQ, DIMc, FFc);
  }
}

// Round 9
// 685.737 us; speedup vs baseline: 14.9555x; 1.0704x over previous
//
#include <hip/hip_runtime.h>
#include <cstdint>
#include <cstddef>

// ---------------- constants (match reference) ----------------
static constexpr int DIMc = 512;
static constexpr int DHc  = 64;
static constexpr int CHc  = 2;
static constexpr int SHc  = 8;
static constexpr int Bc   = 8;
static constexpr int Tc   = 1024;
static constexpr int Nc   = 2048;
static constexpr int CIc  = CHc * DHc;    // 128
static constexpr int SIc  = SHc * DHc;    // 512
static constexpr int FFc  = 4 * DIMc;     // 2048
static constexpr int RQ   = Bc * Tc;      // 8192 query rows
static constexpr int RL   = Bc * Nc;      // 16384 latent rows

typedef short bf16x8 __attribute__((ext_vector_type(8)));
typedef float f32x4  __attribute__((ext_vector_type(4)));

__device__ __forceinline__ ushort f2bf(float f) {
  uint32_t u = __builtin_bit_cast(uint32_t, f);
  u += 0x7fffu + ((u >> 16) & 1u);
  return (ushort)(u >> 16);
}
__device__ __forceinline__ uint32_t packbf2(float a, float b) {
  return (uint32_t)f2bf(a) | ((uint32_t)f2bf(b) << 16);
}
__device__ __forceinline__ float bf2f(ushort h) {
  uint32_t u = ((uint32_t)h) << 16;
  return __builtin_bit_cast(float, u);
}

__device__ __forceinline__ void gload_lds16(const ushort* g, ushort* lds) {
  __builtin_amdgcn_global_load_lds(
      (const __attribute__((address_space(1))) void*)g,
      (__attribute__((address_space(3))) void*)lds, 16, 0, 0);
}

// fast gelu: tanh form; |err| < 3e-3 abs, well under the bf16 tolerance.
__device__ __forceinline__ float gelu_fast(float g) {
  float u = g * (0.7978845608f + 0.0356774081f * g * g);
  float e = __expf(2.f * u);
  float th = 1.f - 2.f * __builtin_amdgcn_rcpf(1.f + e);
  return 0.5f * g * (1.f + th);
}

// ---------------- LayerNorm: one wave per 512-col row, fp32 in -> bf16 out ----
__global__ __launch_bounds__(256) void ln_rows(const float* __restrict__ X,
    const float* __restrict__ w, const float* __restrict__ b,
    ushort* __restrict__ out, int rows) {
  int gw = (int)((blockIdx.x * 256 + threadIdx.x) >> 6);
  int lane = threadIdx.x & 63;
  if (gw >= rows) return;
  const float* xr = X + (size_t)gw * DIMc;
  float4 v0 = *(const float4*)(xr + lane * 8);
  float4 v1 = *(const float4*)(xr + lane * 8 + 4);
  float xv[8] = {v0.x, v0.y, v0.z, v0.w, v1.x, v1.y, v1.z, v1.w};
  float s = 0.f, ss = 0.f;
#pragma unroll
  for (int i = 0; i < 8; i++) { s += xv[i]; ss += xv[i] * xv[i]; }
#pragma unroll
  for (int off = 32; off; off >>= 1) { s += __shfl_xor(s, off); ss += __shfl_xor(ss, off); }
  float mean = s * (1.f / DIMc);
  float var = ss * (1.f / DIMc) - mean * mean;
  float r = rsqrtf(var + 1e-5f);
  int c = lane * 8;
  ushort o[8] __attribute__((aligned(16)));
#pragma unroll
  for (int i = 0; i < 8; i++) o[i] = f2bf((xv[i] - mean) * r * w[c + i] + b[c + i]);
  *(uint4*)(out + (size_t)gw * DIMc + c) = *(const uint4*)o;
}

// ------------- ALL weight transposes for one layer, one launch ----------------
// wid 5 (ffn_w1): 16-col-granular interleave for the shuffle-free gelu epilogue.
__global__ __launch_bounds__(256) void wtrans_all(
    const float* __restrict__ wq, const float* __restrict__ wkv,
    const float* __restrict__ wo, const float* __restrict__ qkv,
    const float* __restrict__ swo, const float* __restrict__ w1,
    const float* __restrict__ w2, ushort* __restrict__ dst, int layer) {
  constexpr int Ks[7]   = {512, 512, 128, 512, 512, 512, 2048};
  constexpr int Ns[7]   = {128, 256, 512, 1536, 512, 4096, 512};
  constexpr int pre[8]  = {0, 64, 192, 256, 1024, 1280, 3328, 4352};
  constexpr int dOff[7] = {0, 65536, 196608, 262144, 1048576, 1310720, 3407872};
  int bid = blockIdx.x;
  int wid = 0;
#pragma unroll
  for (int i = 1; i < 7; i++) wid += (bid >= pre[i]);
  int tileIdx = bid - pre[wid];
  int K = Ks[wid], N = Ns[wid];
  const float* srcs[7] = {wq, wkv, wo, qkv, swo, w1, w2};
  const float* W = srcs[wid] + (size_t)layer * K * N;
  ushort* Wt = dst + dOff[wid];
  int ntx = N / 32;
  int n0 = (tileIdx % ntx) * 32, k0 = (tileIdx / ntx) * 32;
  __shared__ float tile[32][33];
  int tx = threadIdx.x & 31, ty = threadIdx.x >> 5;
#pragma unroll
  for (int i = 0; i < 32; i += 8)
    tile[ty + i][tx] = W[(size_t)(k0 + ty + i) * N + n0 + tx];
  __syncthreads();
  if (wid == 5) {
#pragma unroll
    for (int i = 0; i < 32; i += 8) {
      int nrow = n0 + ty + i;
      int p = nrow & 2047;
      int rowT = ((p >> 4) << 5) + ((nrow < 2048) ? 0 : 16) + (p & 15);
      Wt[(size_t)rowT * K + k0 + tx] = f2bf(tile[tx][ty + i]);
    }
  } else {
#pragma unroll
    for (int i = 0; i < 32; i += 8)
      Wt[(size_t)(n0 + ty + i) * K + k0 + tx] = f2bf(tile[tx][ty + i]);
  }
}

// ---------------- bf16 V transpose: dst[b][hd][key] --------------------------
__global__ __launch_bounds__(256) void vtrans(const ushort* __restrict__ src,
    ushort* __restrict__ dst, int NK, int stride, int colOff) {
  __shared__ ushort tile[32][33];
  int b = blockIdx.z;
  int key0 = blockIdx.x * 32, hd0 = blockIdx.y * 32;
  int HD = gridDim.y * 32;
  int tx = threadIdx.x & 31, ty = threadIdx.x >> 5;
#pragma unroll
  for (int i = 0; i < 32; i += 8)
    tile[ty + i][tx] = src[(size_t)(b * NK + key0 + ty + i) * stride + colOff + hd0 + tx];
  __syncthreads();
#pragma unroll
  for (int i = 0; i < 32; i += 8)
    dst[((size_t)b * HD + hd0 + ty + i) * NK + key0 + tx] = tile[tx][ty + i];
}

// ------- 128x128 GEMM, BK=64, single-buffer (proven r3 structure) ------------
template<int MODE>
__global__ __launch_bounds__(256) void gemm128(const ushort* __restrict__ A,
    const ushort* __restrict__ Bt, const float* __restrict__ bias,
    const float* __restrict__ resIn, float* __restrict__ resOut,
    ushort* __restrict__ outB, int M, int N, int K) {
  __shared__ __align__(16) ushort As[128 * 64];
  __shared__ __align__(16) ushort Bs[128 * 64];
  int t = threadIdx.x, wv = t >> 6, lane = t & 63;
  int bm = blockIdx.y, bn = blockIdx.x;
  int fr = lane & 15, g = lane >> 4;
  int wr = (wv >> 1) * 64, wc = (wv & 1) * 64;
  int srow = wv * 32 + (lane >> 3);
  int sslot = lane & 7;
  const ushort* Abase = A + (size_t)(bm * 128) * K;
  const ushort* Bbase = Bt + (size_t)(bn * 128) * K;

  f32x4 acc[4][4] = {};
  for (int k0 = 0; k0 < K; k0 += 64) {
#pragma unroll
    for (int j = 0; j < 4; j++) {
      int r = srow + j * 8;
      int kc = sslot ^ (r & 7);
      gload_lds16(Abase + (size_t)r * K + k0 + kc * 8, As + (wv * 256 + j * 64) * 8);
      gload_lds16(Bbase + (size_t)r * K + k0 + kc * 8, Bs + (wv * 256 + j * 64) * 8);
    }
    __syncthreads();
#pragma unroll
    for (int ks = 0; ks < 2; ks++) {
      bf16x8 af[4], bf[4];
#pragma unroll
      for (int mm = 0; mm < 4; mm++) {
        int row = wr + mm * 16 + fr;
        af[mm] = *(const bf16x8*)(As + row * 64 + (((ks * 4 + g) ^ (row & 7)) * 8));
      }
#pragma unroll
      for (int nn = 0; nn < 4; nn++) {
        int row = wc + nn * 16 + fr;
        bf[nn] = *(const bf16x8*)(Bs + row * 64 + (((ks * 4 + g) ^ (row & 7)) * 8));
      }
#pragma unroll
      for (int mm = 0; mm < 4; mm++)
#pragma unroll
        for (int nn = 0; nn < 4; nn++)
          acc[mm][nn] = __builtin_amdgcn_mfma_f32_16x16x32_bf16(af[mm], bf[nn], acc[mm][nn], 0, 0, 0);
    }
    __syncthreads();
  }

  if (MODE == 2) {
    int NH = N >> 1;
#pragma unroll
    for (int mm = 0; mm < 4; mm++)
#pragma unroll
      for (int np = 0; np < 2; np++) {
        int ocol = bn * 64 + (wc >> 1) + np * 16 + fr;
        float ba = bias[ocol];
        float bg = bias[NH + ocol];
#pragma unroll
        for (int i = 0; i < 4; i++) {
          int gr = bm * 128 + wr + mm * 16 + g * 4 + i;
          float a = acc[mm][np * 2][i] + ba;
          float gv = acc[mm][np * 2 + 1][i] + bg;
          outB[(size_t)gr * NH + ocol] = f2bf(a * gelu_fast(gv));
        }
      }
  } else {
#pragma unroll
    for (int mm = 0; mm < 4; mm++)
#pragma unroll
      for (int nn = 0; nn < 4; nn++)
#pragma unroll
        for (int i = 0; i < 4; i++) {
          int gr = bm * 128 + wr + mm * 16 + g * 4 + i;
          int gc = bn * 128 + wc + nn * 16 + fr;
          float val = acc[mm][nn][i] + (bias ? bias[gc] : 0.f);
          if (MODE == 0) outB[(size_t)gr * N + gc] = f2bf(val);
          else resOut[(size_t)gr * N + gc] = resIn[(size_t)gr * N + gc] + val;
        }
  }
}

// ------- 128x64 GEMM, BK=64, single-buffer, 24 KB LDS (high occupancy) -------
template<int MODE>
__global__ __launch_bounds__(256) void gemm128x64(const ushort* __restrict__ A,
    const ushort* __restrict__ Bt, const float* __restrict__ bias,
    const float* __restrict__ resIn, float* __restrict__ resOut,
    ushort* __restrict__ outB, int M, int N, int K) {
  __shared__ __align__(16) ushort As[128 * 64];   // 16 KB
  __shared__ __align__(16) ushort Bs[64 * 64];    //  8 KB
  int t = threadIdx.x, wv = t >> 6, lane = t & 63;
  int bm = blockIdx.y, bn = blockIdx.x;
  int fr = lane & 15, g = lane >> 4;
  int wr = (wv >> 1) * 64, wc = (wv & 1) * 32;
  const ushort* Abase = A + (size_t)(bm * 128) * K;
  const ushort* Bbase = Bt + (size_t)(bn * 64) * K;

  f32x4 acc[4][2] = {};
  for (int k0 = 0; k0 < K; k0 += 64) {
#pragma unroll
    for (int j = 0; j < 4; j++) {
      int c = j * 256 + wv * 64 + lane;
      int r = c >> 3, s = c & 7;
      int kc = s ^ (r & 7);
      gload_lds16(Abase + (size_t)r * K + k0 + kc * 8, As + (j * 256 + wv * 64) * 8);
      if (j < 2)
        gload_lds16(Bbase + (size_t)r * K + k0 + kc * 8, Bs + (j * 256 + wv * 64) * 8);
    }
    __syncthreads();
#pragma unroll
    for (int ks = 0; ks < 2; ks++) {
      bf16x8 af[4], bf[2];
#pragma unroll
      for (int mm = 0; mm < 4; mm++) {
        int row = wr + mm * 16 + fr;
        af[mm] = *(const bf16x8*)(As + row * 64 + (((ks * 4 + g) ^ (row & 7)) * 8));
      }
#pragma unroll
      for (int nn = 0; nn < 2; nn++) {
        int row = wc + nn * 16 + fr;
        bf[nn] = *(const bf16x8*)(Bs + row * 64 + (((ks * 4 + g) ^ (row & 7)) * 8));
      }
#pragma unroll
      for (int mm = 0; mm < 4; mm++)
#pragma unroll
        for (int nn = 0; nn < 2; nn++)
          acc[mm][nn] = __builtin_amdgcn_mfma_f32_16x16x32_bf16(af[mm], bf[nn], acc[mm][nn], 0, 0, 0);
    }
    __syncthreads();
  }

#pragma unroll
  for (int mm = 0; mm < 4; mm++)
#pragma unroll
    for (int nn = 0; nn < 2; nn++)
#pragma unroll
      for (int i = 0; i < 4; i++) {
        int gr = bm * 128 + wr + mm * 16 + g * 4 + i;
        int gc = bn * 64 + wc + nn * 16 + fr;
        float val = acc[mm][nn][i] + (bias ? bias[gc] : 0.f);
        if (MODE == 0) outB[(size_t)gr * N + gc] = f2bf(val);
        else resOut[(size_t)gr * N + gc] = resIn[(size_t)gr * N + gc] + val;
      }
}

// ---------------- bf16 MFMA GEMM, 64x64 tile (q-proj only) -------------------
template<int MODE>
__global__ __launch_bounds__(256) void gemm64(const ushort* __restrict__ A,
    const ushort* __restrict__ Bt, const float* __restrict__ bias,
    float* __restrict__ resF, ushort* __restrict__ outB,
    int M, int N, int K) {
  __shared__ __align__(16) ushort As[64][40];
  __shared__ __align__(16) ushort Bs[64][40];
  int t = threadIdx.x;
  int bm = blockIdx.y, bn = blockIdx.x;
  int row = t >> 2, kc = (t & 3) << 3;
  const ushort* aG = A + (size_t)(bm * 64 + row) * K + kc;
  const ushort* bG = Bt + (size_t)(bn * 64 + row) * K + kc;
  int wv = t >> 6, lane = t & 63;
  int wr = (wv >> 1) * 32, wc = (wv & 1) * 32;
  int fr = lane & 15, fk = (lane >> 4) << 3;
  f32x4 acc[2][2] = {};
  for (int k0 = 0; k0 < K; k0 += 32) {
    *(uint4*)&As[row][kc] = *(const uint4*)(aG + k0);
    *(uint4*)&Bs[row][kc] = *(const uint4*)(bG + k0);
    __syncthreads();
    bf16x8 a0 = *(const bf16x8*)&As[wr + fr][fk];
    bf16x8 a1 = *(const bf16x8*)&As[wr + 16 + fr][fk];
    bf16x8 b0 = *(const bf16x8*)&Bs[wc + fr][fk];
    bf16x8 b1 = *(const bf16x8*)&Bs[wc + 16 + fr][fk];
    acc[0][0] = __builtin_amdgcn_mfma_f32_16x16x32_bf16(a0, b0, acc[0][0], 0, 0, 0);
    acc[0][1] = __builtin_amdgcn_mfma_f32_16x16x32_bf16(a0, b1, acc[0][1], 0, 0, 0);
    acc[1][0] = __builtin_amdgcn_mfma_f32_16x16x32_bf16(a1, b0, acc[1][0], 0, 0, 0);
    acc[1][1] = __builtin_amdgcn_mfma_f32_16x16x32_bf16(a1, b1, acc[1][1], 0, 0, 0);
    __syncthreads();
  }
  int cr0 = wr + ((lane >> 4) << 2);
  int cc0 = wc + fr;
#pragma unroll
  for (int mm = 0; mm < 2; mm++)
#pragma unroll
    for (int nn = 0; nn < 2; nn++)
#pragma unroll
      for (int i = 0; i < 4; i++) {
        int gr = bm * 64 + cr0 + mm * 16 + i;
        int gc = bn * 64 + cc0 + nn * 16;
        float val = acc[mm][nn][i] + (bias ? bias[gc] : 0.f);
        if (MODE == 0) outB[(size_t)gr * N + gc] = f2bf(val);
        else resF[(size_t)gr * N + gc] = resF[(size_t)gr * N + gc] + val;
      }
}

// ---------------- elementwise rotary (in place on bf16 buffer) ---------------
__global__ __launch_bounds__(256) void rope_apply(ushort* __restrict__ buf,
    const float* __restrict__ fr, int rows, int stride, int colOff, int H, float scale) {
  int idx = blockIdx.x * 256 + threadIdx.x;
  int total = rows * H * 32;
  if (idx >= total) return;
  int p = idx & 31;
  int h = (idx >> 5) % H;
  int r = idx / (32 * H);
  float f0 = fr[(size_t)r * DHc + 2 * p];
  float f1 = fr[(size_t)r * DHc + 2 * p + 1];
  ushort* bp = buf + (size_t)r * stride + colOff + h * DHc + 2 * p;
  float x0 = bf2f(bp[0]), x1 = bf2f(bp[1]);
  float o0 = (x0 * __cosf(f0) - x1 * __sinf(f0)) * scale;
  float o1 = (x1 * __cosf(f1) + x0 * __sinf(f1)) * scale;
  bp[0] = f2bf(o0); bp[1] = f2bf(o1);
}

// ---------------- MFMA flash attention, swapped operands ---------------------
// QK^T computed as mfma(K, Q) -> lane (fr,g) holds S[q=qw+fr][key=k0+nn*16+g*4+i]:
// softmax row is LANE-LOCAL (16 vals) + 2-shfl cross-g reduce; m,l are scalars.
// PV computed as mfma(Vt, P) -> lane holds O[q=qw+fr][d=dd*16+g*4+i]; rescale
// and 1/l use the lane's own m,l.  P round-trips per-wave LDS as packed dwords.
template<int CAUSAL>
__global__ __launch_bounds__(256) void attn_mfma(
    const ushort* __restrict__ Q, const ushort* __restrict__ K,
    const ushort* __restrict__ Vt, ushort* __restrict__ O,
    int qStride, int kStride, int kOff, int oStride,
    int Tq, int NK, int H) {
  __shared__ __align__(16) ushort Ks[64 * 64];
  __shared__ __align__(16) ushort Vs[64 * 64];
  __shared__ __align__(16) ushort Ps[4][16 * 72];
  int b = blockIdx.z, h = blockIdx.y;
  int qt = CAUSAL ? ((int)gridDim.x - 1 - (int)blockIdx.x) : blockIdx.x;  // big blocks first
  int t = threadIdx.x, wv = t >> 6, lane = t & 63;
  int g = lane >> 4, fr = lane & 15;
  int qw = qt * 64 + wv * 16;
  int HD = H * 64;

  const ushort* qrow = Q + (size_t)(b * Tq + qw + fr) * qStride + h * 64;
  bf16x8 qlo = *(const bf16x8*)(qrow + g * 8);        // Q[qw+fr][g*8..+7]
  bf16x8 qhi = *(const bf16x8*)(qrow + 32 + g * 8);   // Q[qw+fr][32+g*8..+7]

  f32x4 o_acc[4] = {};
  float m_run = -1e30f, l_run = 0.f;

  uint32_t* Pw = (uint32_t*)&Ps[wv][0];   // dword view, row stride 36 dwords
  int ntiles = CAUSAL ? (qt + 1) : (NK / 64);
  for (int kt = 0; kt < ntiles; kt++) {
    int k0 = kt * 64;
    __syncthreads();
#pragma unroll
    for (int i = 0; i < 2; i++) {
      int id = t + i * 256;
      int r = id >> 3, c = id & 7;
      uint4 kval = *(const uint4*)(K + (size_t)(b * NK + k0 + r) * kStride + kOff + h * 64 + c * 8);
      *(uint4*)(Ks + r * 64 + ((c ^ (r & 7)) * 8)) = kval;
      uint4 vval = *(const uint4*)(Vt + ((size_t)b * HD + h * 64 + r) * NK + k0 + c * 8);
      *(uint4*)(Vs + r * 64 + ((c ^ (r & 7)) * 8)) = vval;
    }
    __syncthreads();

    // S^T = K Q^T : lane (fr,g) gets S[qw+fr][k0 + nn*16 + g*4 + i]
    f32x4 s[4];
#pragma unroll
    for (int nn = 0; nn < 4; nn++) {
      int row = nn * 16 + fr;
      bf16x8 kf0 = *(const bf16x8*)(Ks + row * 64 + ((g ^ (fr & 7)) * 8));
      bf16x8 kf1 = *(const bf16x8*)(Ks + row * 64 + (((4 + g) ^ (fr & 7)) * 8));
      f32x4 z = {};
      z = __builtin_amdgcn_mfma_f32_16x16x32_bf16(kf0, qlo, z, 0, 0, 0);
      z = __builtin_amdgcn_mfma_f32_16x16x32_bf16(kf1, qhi, z, 0, 0, 0);
      s[nn] = z;
    }
    if (CAUSAL && (k0 + 63 > qw)) {
#pragma unroll
      for (int nn = 0; nn < 4; nn++)
#pragma unroll
        for (int i = 0; i < 4; i++)
          if (k0 + nn * 16 + g * 4 + i > qw + fr) s[nn][i] = -1e30f;
    }
    // in-register softmax for row fr (16 local vals + 4-lane cross-g reduce)
    float tm = s[0][0];
#pragma unroll
    for (int nn = 0; nn < 4; nn++)
#pragma unroll
      for (int i = 0; i < 4; i++) tm = fmaxf(tm, s[nn][i]);
    tm = fmaxf(tm, __shfl_xor(tm, 16));
    tm = fmaxf(tm, __shfl_xor(tm, 32));
    float mnew = fmaxf(m_run, tm);
    float corr = __expf(m_run - mnew);
    float ps = 0.f;
#pragma unroll
    for (int nn = 0; nn < 4; nn++)
#pragma unroll
      for (int i = 0; i < 4; i++) {
        float p = __expf(s[nn][i] - mnew);
        s[nn][i] = p;
        ps += p;
      }
    ps += __shfl_xor(ps, 16);
    ps += __shfl_xor(ps, 32);
    l_run = l_run * corr + ps;
    m_run = mnew;
#pragma unroll
    for (int dd = 0; dd < 4; dd++) o_acc[dd] *= corr;
    // pack P -> per-wave LDS: key pair (16nn+4g+2p, +1) at dword 8nn+2g+p
#pragma unroll
    for (int nn = 0; nn < 4; nn++)
#pragma unroll
      for (int p = 0; p < 2; p++)
        Pw[fr * 36 + 8 * nn + 2 * g + p] = packbf2(s[nn][2 * p], s[nn][2 * p + 1]);
    bf16x8 pa0 = *(const bf16x8*)(&Ps[wv][fr * 72 + g * 8]);        // P[fr][g*8..+7]
    bf16x8 pa1 = *(const bf16x8*)(&Ps[wv][fr * 72 + 32 + g * 8]);   // P[fr][32+g*8..+7]
    // O^T += V^T P^T : lane (fr,g) accumulates O[qw+fr][dd*16+g*4+i]
#pragma unroll
    for (int dd = 0; dd < 4; dd++) {
      int row = dd * 16 + fr;
      bf16x8 vf0 = *(const bf16x8*)(Vs + row * 64 + ((g ^ (fr & 7)) * 8));
      bf16x8 vf1 = *(const bf16x8*)(Vs + row * 64 + (((4 + g) ^ (fr & 7)) * 8));
      o_acc[dd] = __builtin_amdgcn_mfma_f32_16x16x32_bf16(vf0, pa0, o_acc[dd], 0, 0, 0);
      o_acc[dd] = __builtin_amdgcn_mfma_f32_16x16x32_bf16(vf1, pa1, o_acc[dd], 0, 0, 0);
    }
  }
  float rl = 1.f / l_run;
  ushort* obase = O + (size_t)(b * Tq + qw + fr) * oStride + h * 64;
#pragma unroll
  for (int dd = 0; dd < 4; dd++) {
    uint2 w;
    w.x = packbf2(o_acc[dd][0] * rl, o_acc[dd][1] * rl);
    w.y = packbf2(o_acc[dd][2] * rl, o_acc[dd][3] * rl);
    *(uint2*)(obase + dd * 16 + g * 4) = w;
  }
}

// ---------------- orchestration ----------------------------------------------
extern "C" void kernel_launch(void* const* d_in, const int* in_sizes, int n_in,
                              void* d_out, int out_size, void* d_ws, size_t ws_size,
                              hipStream_t stream) {
  const float* bin_queries = (const float*)d_in[0];
  const float* bin_time    = (const float*)d_in[1];
  const float* latents     = (const float*)d_in[2];
  const float* lat_time    = (const float*)d_in[3];
  const float* ca_lnq_w = (const float*)d_in[4];
  const float* ca_lnq_b = (const float*)d_in[5];
  const float* ca_lnc_w = (const float*)d_in[6];
  const float* ca_lnc_b = (const float*)d_in[7];
  const float* ca_wq  = (const float*)d_in[8];
  const float* ca_wkv = (const float*)d_in[9];
  const float* ca_wo  = (const float*)d_in[10];
  const float* ca_bo  = (const float*)d_in[11];
  const float* sa_ln_w = (const float*)d_in[12];
  const float* sa_ln_b = (const float*)d_in[13];
  const float* sa_wqkv = (const float*)d_in[14];
  const float* sa_wo   = (const float*)d_in[15];
  const float* sa_bo   = (const float*)d_in[16];
  const float* ffn_ln_w = (const float*)d_in[17];
  const float* ffn_ln_b = (const float*)d_in[18];
  const float* ffn_w1 = (const float*)d_in[19];
  const float* ffn_b1 = (const float*)d_in[20];
  const float* ffn_w2 = (const float*)d_in[21];
  const float* ffn_b2 = (const float*)d_in[22];

  constexpr size_t X_BYTES = (size_t)RQ * DIMc * 4;
  char* ws = (char*)d_ws;
  float* x = (float*)ws;
  char* A0 = ws + X_BYTES;
  // cross-attn phase
  ushort* cn     = (ushort*)(A0);
  ushort* ca_xn  = (ushort*)(A0 + 16777216);
  ushort* qbuf   = (ushort*)(A0 + 25165824);
  ushort* kv     = (ushort*)(A0 + 27262976);
  ushort* ca_att = (ushort*)(A0 + 35651584);
  ushort* vt_c   = (ushort*)(A0 + 37748736);
  // self-attn phase (reuses arena)
  ushort* sa_xn  = (ushort*)(A0);
  ushort* qkv    = (ushort*)(A0 + 8388608);
  ushort* sa_att = (ushort*)(A0 + 33554432);
  ushort* vt_s   = (ushort*)(A0 + 41943040);
  // ffn phase (reuses arena)
  ushort* hb     = (ushort*)(A0);
  ushort* ag     = (ushort*)(A0 + 8388608);
  // bf16 transposed weights for the current layer
  char* W0 = A0 + 109051904;
  ushort* wbase = (ushort*)W0;
  ushort* wqT  = wbase;
  ushort* wkvT = wbase + 65536;
  ushort* woT  = wbase + 196608;
  ushort* qkvT = wbase + 262144;
  ushort* swoT = wbase + 1048576;
  ushort* w1T  = wbase + 1310720;
  ushort* w2T  = wbase + 3407872;

  hipMemcpyAsync(x, bin_queries, X_BYTES, hipMemcpyDeviceToDevice, stream);

  for (int l = 0; l < 2; l++) {
    wtrans_all<<<4352, 256, 0, stream>>>(ca_wq, ca_wkv, ca_wo, sa_wqkv, sa_wo,
                                         ffn_w1, ffn_w2, wbase, l);

    // ---- cross attention ----
    ln_rows<<<RQ / 4, 256, 0, stream>>>(x, ca_lnq_w + l * DIMc, ca_lnq_b + l * DIMc, ca_xn, RQ);
    ln_rows<<<RL / 4, 256, 0, stream>>>(latents, ca_lnc_w + l * DIMc, ca_lnc_b + l * DIMc, cn, RL);
    gemm64<0><<<dim3(CIc / 64, RQ / 64), 256, 0, stream>>>(ca_xn, wqT, nullptr, nullptr, qbuf, RQ, CIc, DIMc);
    gemm128x64<0><<<dim3(2 * CIc / 64, RL / 128), 256, 0, stream>>>(cn, wkvT, nullptr,
        nullptr, nullptr, kv, RL, 2 * CIc, DIMc);
    rope_apply<<<(RQ * CHc * 32) / 256, 256, 0, stream>>>(qbuf, bin_time, RQ, CIc, 0, CHc, 0.125f);
    rope_apply<<<(RL * CHc * 32) / 256, 256, 0, stream>>>(kv, lat_time, RL, 2 * CIc, 0, CHc, 1.f);
    vtrans<<<dim3(Nc / 32, CHc * 64 / 32, Bc), 256, 0, stream>>>(kv, vt_c, Nc, 2 * CIc, CIc);
    attn_mfma<0><<<dim3(Tc / 64, CHc, Bc), 256, 0, stream>>>(qbuf, kv, vt_c, ca_att,
        CIc, 2 * CIc, 0, CIc, Tc, Nc, CHc);
    gemm128x64<1><<<dim3(DIMc / 64, RQ / 128), 256, 0, stream>>>(ca_att, woT, ca_bo + l * DIMc,
        x, x, nullptr, RQ, DIMc, CIc);

    // ---- self attention (causal) ----
    ln_rows<<<RQ / 4, 256, 0, stream>>>(x, sa_ln_w + l * DIMc, sa_ln_b + l * DIMc, sa_xn, RQ);
    gemm128<0><<<dim3(3 * SIc / 128, RQ / 128), 256, 0, stream>>>(sa_xn, qkvT, nullptr,
        nullptr, nullptr, qkv, RQ, 3 * SIc, DIMc);
    rope_apply<<<(RQ * SHc * 32) / 256, 256, 0, stream>>>(qkv, bin_time, RQ, 3 * SIc, 0, SHc, 0.125f);
    rope_apply<<<(RQ * SHc * 32) / 256, 256, 0, stream>>>(qkv, bin_time, RQ, 3 * SIc, SIc, SHc, 1.f);
    vtrans<<<dim3(Tc / 32, SHc * 64 / 32, Bc), 256, 0, stream>>>(qkv, vt_s, Tc, 3 * SIc, 2 * SIc);
    attn_mfma<1><<<dim3(Tc / 64, SHc, Bc), 256, 0, stream>>>(qkv, qkv, vt_s, sa_att,
        3 * SIc, 3 * SIc, SIc, SIc, Tc, Tc, SHc);
    gemm128x64<1><<<dim3(DIMc / 64, RQ / 128), 256, 0, stream>>>(sa_att, swoT, sa_bo + l * DIMc,
        x, x, nullptr, RQ, DIMc, SIc);

    // ---- FFN (w1 with fused bias + a*gelu(g) epilogue, shuffle-free) ----
    ln_rows<<<RQ / 4, 256, 0, stream>>>(x, ffn_ln_w + l * DIMc, ffn_ln_b + l * DIMc, hb, RQ);
    gemm128<2><<<dim3(2 * FFc / 128, RQ / 128), 256, 0, stream>>>(hb, w1T,
        ffn_b1 + (size_t)l * 2 * FFc, nullptr, nullptr, ag, RQ, 2 * FFc, DIMc);
    float* resOut = (l == 1) ? (float*)d_out : x;
    gemm128x64<1><<<dim3(DIMc / 64, RQ / 128), 256, 0, stream>>>(ag, w2T, ffn_b2 + l * DIMc,
        x, resOut, nullptr, RQ, DIMc, FFc);
  }
}

// Round 10
// 634.051 us; speedup vs baseline: 16.1746x; 1.0815x over previous
//
#include <hip/hip_runtime.h>
#include <cstdint>
#include <cstddef>

// ---------------- constants (match reference) ----------------
static constexpr int DIMc = 512;
static constexpr int DHc  = 64;
static constexpr int CHc  = 2;
static constexpr int SHc  = 8;
static constexpr int Bc   = 8;
static constexpr int Tc   = 1024;
static constexpr int Nc   = 2048;
static constexpr int CIc  = CHc * DHc;    // 128
static constexpr int SIc  = SHc * DHc;    // 512
static constexpr int FFc  = 4 * DIMc;     // 2048
static constexpr int RQ   = Bc * Tc;      // 8192 query rows
static constexpr int RL   = Bc * Nc;      // 16384 latent rows

typedef short bf16x8 __attribute__((ext_vector_type(8)));
typedef float f32x4  __attribute__((ext_vector_type(4)));

__device__ __forceinline__ ushort f2bf(float f) {
  uint32_t u = __builtin_bit_cast(uint32_t, f);
  u += 0x7fffu + ((u >> 16) & 1u);
  return (ushort)(u >> 16);
}
__device__ __forceinline__ uint32_t packbf2(float a, float b) {
  return (uint32_t)f2bf(a) | ((uint32_t)f2bf(b) << 16);
}
__device__ __forceinline__ float bf2f(ushort h) {
  uint32_t u = ((uint32_t)h) << 16;
  return __builtin_bit_cast(float, u);
}

__device__ __forceinline__ void gload_lds16(const ushort* g, ushort* lds) {
  __builtin_amdgcn_global_load_lds(
      (const __attribute__((address_space(1))) void*)g,
      (__attribute__((address_space(3))) void*)lds, 16, 0, 0);
}

// fast gelu: tanh form; |err| < 3e-3 abs, well under the bf16 tolerance.
__device__ __forceinline__ float gelu_fast(float g) {
  float u = g * (0.7978845608f + 0.0356774081f * g * g);
  float e = __expf(2.f * u);
  float th = 1.f - 2.f * __builtin_amdgcn_rcpf(1.f + e);
  return 0.5f * g * (1.f + th);
}

// rope rotate: even d: v*c - p*s ; odd d: v*c + p*s  (p = partner lane value)
__device__ __forceinline__ float rope_rot(int odd, float v, float p, float2 cs) {
  return odd ? (v * cs.x + p * cs.y) : (v * cs.x - p * cs.y);
}

// ---------------- cos/sin table prep: dst[i] = (cos(src[i]), sin(src[i])) ----
__global__ __launch_bounds__(256) void trig_prep(const float* __restrict__ src,
    float2* __restrict__ dst, int n) {
  int i = blockIdx.x * 256 + threadIdx.x;
  if (i >= n) return;
  float s, c;
  __sincosf(src[i], &s, &c);
  dst[i] = make_float2(c, s);
}

// ---------------- LayerNorm: one wave per 512-col row, fp32 in -> bf16 out ----
__global__ __launch_bounds__(256) void ln_rows(const float* __restrict__ X,
    const float* __restrict__ w, const float* __restrict__ b,
    ushort* __restrict__ out, int rows) {
  int gw = (int)((blockIdx.x * 256 + threadIdx.x) >> 6);
  int lane = threadIdx.x & 63;
  if (gw >= rows) return;
  const float* xr = X + (size_t)gw * DIMc;
  float4 v0 = *(const float4*)(xr + lane * 8);
  float4 v1 = *(const float4*)(xr + lane * 8 + 4);
  float xv[8] = {v0.x, v0.y, v0.z, v0.w, v1.x, v1.y, v1.z, v1.w};
  float s = 0.f, ss = 0.f;
#pragma unroll
  for (int i = 0; i < 8; i++) { s += xv[i]; ss += xv[i] * xv[i]; }
#pragma unroll
  for (int off = 32; off; off >>= 1) { s += __shfl_xor(s, off); ss += __shfl_xor(ss, off); }
  float mean = s * (1.f / DIMc);
  float var = ss * (1.f / DIMc) - mean * mean;
  float r = rsqrtf(var + 1e-5f);
  int c = lane * 8;
  ushort o[8] __attribute__((aligned(16)));
#pragma unroll
  for (int i = 0; i < 8; i++) o[i] = f2bf((xv[i] - mean) * r * w[c + i] + b[c + i]);
  *(uint4*)(out + (size_t)gw * DIMc + c) = *(const uint4*)o;
}

// ------------- ALL weight transposes for one layer, one launch ----------------
// wid 5 (ffn_w1): 16-col-granular interleave for the shuffle-free gelu epilogue.
__global__ __launch_bounds__(256) void wtrans_all(
    const float* __restrict__ wq, const float* __restrict__ wkv,
    const float* __restrict__ wo, const float* __restrict__ qkv,
    const float* __restrict__ swo, const float* __restrict__ w1,
    const float* __restrict__ w2, ushort* __restrict__ dst, int layer) {
  constexpr int Ks[7]   = {512, 512, 128, 512, 512, 512, 2048};
  constexpr int Ns[7]   = {128, 256, 512, 1536, 512, 4096, 512};
  constexpr int pre[8]  = {0, 64, 192, 256, 1024, 1280, 3328, 4352};
  constexpr int dOff[7] = {0, 65536, 196608, 262144, 1048576, 1310720, 3407872};
  int bid = blockIdx.x;
  int wid = 0;
#pragma unroll
  for (int i = 1; i < 7; i++) wid += (bid >= pre[i]);
  int tileIdx = bid - pre[wid];
  int K = Ks[wid], N = Ns[wid];
  const float* srcs[7] = {wq, wkv, wo, qkv, swo, w1, w2};
  const float* W = srcs[wid] + (size_t)layer * K * N;
  ushort* Wt = dst + dOff[wid];
  int ntx = N / 32;
  int n0 = (tileIdx % ntx) * 32, k0 = (tileIdx / ntx) * 32;
  __shared__ float tile[32][33];
  int tx = threadIdx.x & 31, ty = threadIdx.x >> 5;
#pragma unroll
  for (int i = 0; i < 32; i += 8)
    tile[ty + i][tx] = W[(size_t)(k0 + ty + i) * N + n0 + tx];
  __syncthreads();
  if (wid == 5) {
#pragma unroll
    for (int i = 0; i < 32; i += 8) {
      int nrow = n0 + ty + i;
      int p = nrow & 2047;
      int rowT = ((p >> 4) << 5) + ((nrow < 2048) ? 0 : 16) + (p & 15);
      Wt[(size_t)rowT * K + k0 + tx] = f2bf(tile[tx][ty + i]);
    }
  } else {
#pragma unroll
    for (int i = 0; i < 32; i += 8)
      Wt[(size_t)(n0 + ty + i) * K + k0 + tx] = f2bf(tile[tx][ty + i]);
  }
}

// ------- 128x128 GEMM, BK=64, single-buffer (proven r3 structure) ------------
// MODE 0: outB = bf16(acc + bias)
// MODE 1: resOut = resIn + acc + bias   (fp32)
// MODE 2: fused FFN gate (16-col interleaved w1T): write bf16(a*gelu(g)), N/2.
// MODE 3: self-qkv fused rope+vt: cols [0,512)=q rope*0.125, [512,1024)=k rope,
//         [1024,1536)=v -> transposed store vt[b][ch][t] (b-split at 1024 rows).
template<int MODE>
__global__ __launch_bounds__(256) void gemm128(const ushort* __restrict__ A,
    const ushort* __restrict__ Bt, const float* __restrict__ bias,
    const float* __restrict__ resIn, float* __restrict__ resOut,
    ushort* __restrict__ outB, int M, int N, int K,
    const float2* __restrict__ cs, ushort* __restrict__ vt) {
  __shared__ __align__(16) ushort As[128 * 64];
  __shared__ __align__(16) ushort Bs[128 * 64];
  int t = threadIdx.x, wv = t >> 6, lane = t & 63;
  int bm = blockIdx.y, bn = blockIdx.x;
  int fr = lane & 15, g = lane >> 4;
  int wr = (wv >> 1) * 64, wc = (wv & 1) * 64;
  int srow = wv * 32 + (lane >> 3);
  int sslot = lane & 7;
  const ushort* Abase = A + (size_t)(bm * 128) * K;
  const ushort* Bbase = Bt + (size_t)(bn * 128) * K;

  f32x4 acc[4][4] = {};
  for (int k0 = 0; k0 < K; k0 += 64) {
#pragma unroll
    for (int j = 0; j < 4; j++) {
      int r = srow + j * 8;
      int kc = sslot ^ (r & 7);
      gload_lds16(Abase + (size_t)r * K + k0 + kc * 8, As + (wv * 256 + j * 64) * 8);
      gload_lds16(Bbase + (size_t)r * K + k0 + kc * 8, Bs + (wv * 256 + j * 64) * 8);
    }
    __syncthreads();
#pragma unroll
    for (int ks = 0; ks < 2; ks++) {
      bf16x8 af[4], bf[4];
#pragma unroll
      for (int mm = 0; mm < 4; mm++) {
        int row = wr + mm * 16 + fr;
        af[mm] = *(const bf16x8*)(As + row * 64 + (((ks * 4 + g) ^ (row & 7)) * 8));
      }
#pragma unroll
      for (int nn = 0; nn < 4; nn++) {
        int row = wc + nn * 16 + fr;
        bf[nn] = *(const bf16x8*)(Bs + row * 64 + (((ks * 4 + g) ^ (row & 7)) * 8));
      }
#pragma unroll
      for (int mm = 0; mm < 4; mm++)
#pragma unroll
        for (int nn = 0; nn < 4; nn++)
          acc[mm][nn] = __builtin_amdgcn_mfma_f32_16x16x32_bf16(af[mm], bf[nn], acc[mm][nn], 0, 0, 0);
    }
    __syncthreads();
  }

  if (MODE == 2) {
    int NH = N >> 1;
#pragma unroll
    for (int mm = 0; mm < 4; mm++)
#pragma unroll
      for (int np = 0; np < 2; np++) {
        int ocol = bn * 64 + (wc >> 1) + np * 16 + fr;
        float ba = bias[ocol];
        float bg = bias[NH + ocol];
#pragma unroll
        for (int i = 0; i < 4; i++) {
          int gr = bm * 128 + wr + mm * 16 + g * 4 + i;
          float a = acc[mm][np * 2][i] + ba;
          float gv = acc[mm][np * 2 + 1][i] + bg;
          outB[(size_t)gr * NH + ocol] = f2bf(a * gelu_fast(gv));
        }
      }
  } else if (MODE == 3) {
    if (bn * 128 < 1024) {   // q/k block: fused rope (+0.125 scale on q)
#pragma unroll
      for (int mm = 0; mm < 4; mm++)
#pragma unroll
        for (int nn = 0; nn < 4; nn++) {
          int gc = bn * 128 + wc + nn * 16 + fr;
          int d = gc & 63;
          float sc = (gc < 512) ? 0.125f : 1.f;
#pragma unroll
          for (int i = 0; i < 4; i++) {
            int gr = bm * 128 + wr + mm * 16 + g * 4 + i;
            float val = acc[mm][nn][i];
            float prt = __shfl_xor(val, 1);
            float2 csv = cs[(size_t)gr * 64 + d];
            outB[(size_t)gr * N + gc] = f2bf(rope_rot(fr & 1, val, prt, csv) * sc);
          }
        }
    } else {                 // v block: transposed store to vt[b][ch][t]
#pragma unroll
      for (int mm = 0; mm < 4; mm++)
#pragma unroll
        for (int nn = 0; nn < 4; nn++) {
          int gc = bn * 128 + wc + nn * 16 + fr;
          int ch = gc - 1024;
          int gr0 = bm * 128 + wr + mm * 16 + g * 4;
          int bb = gr0 >> 10, t0 = gr0 & 1023;
          uint2 w;
          w.x = packbf2(acc[mm][nn][0], acc[mm][nn][1]);
          w.y = packbf2(acc[mm][nn][2], acc[mm][nn][3]);
          *(uint2*)(vt + ((size_t)bb * 512 + ch) * 1024 + t0) = w;
        }
    }
  } else {
#pragma unroll
    for (int mm = 0; mm < 4; mm++)
#pragma unroll
      for (int nn = 0; nn < 4; nn++)
#pragma unroll
        for (int i = 0; i < 4; i++) {
          int gr = bm * 128 + wr + mm * 16 + g * 4 + i;
          int gc = bn * 128 + wc + nn * 16 + fr;
          float val = acc[mm][nn][i] + (bias ? bias[gc] : 0.f);
          if (MODE == 0) outB[(size_t)gr * N + gc] = f2bf(val);
          else resOut[(size_t)gr * N + gc] = resIn[(size_t)gr * N + gc] + val;
        }
  }
}

// ------- 128x64 GEMM, BK=64, single-buffer, 24 KB LDS (high occupancy) -------
// MODE 0/1 as above.  MODE 3: cross-kv fused: cols [0,128)=k rope (csL),
// [128,256)=v -> vt_c[b][ch][t] (b-split at 2048 rows).
template<int MODE>
__global__ __launch_bounds__(256) void gemm128x64(const ushort* __restrict__ A,
    const ushort* __restrict__ Bt, const float* __restrict__ bias,
    const float* __restrict__ resIn, float* __restrict__ resOut,
    ushort* __restrict__ outB, int M, int N, int K,
    const float2* __restrict__ cs, ushort* __restrict__ vt) {
  __shared__ __align__(16) ushort As[128 * 64];   // 16 KB
  __shared__ __align__(16) ushort Bs[64 * 64];    //  8 KB
  int t = threadIdx.x, wv = t >> 6, lane = t & 63;
  int bm = blockIdx.y, bn = blockIdx.x;
  int fr = lane & 15, g = lane >> 4;
  int wr = (wv >> 1) * 64, wc = (wv & 1) * 32;
  const ushort* Abase = A + (size_t)(bm * 128) * K;
  const ushort* Bbase = Bt + (size_t)(bn * 64) * K;

  f32x4 acc[4][2] = {};
  for (int k0 = 0; k0 < K; k0 += 64) {
#pragma unroll
    for (int j = 0; j < 4; j++) {
      int c = j * 256 + wv * 64 + lane;
      int r = c >> 3, s = c & 7;
      int kc = s ^ (r & 7);
      gload_lds16(Abase + (size_t)r * K + k0 + kc * 8, As + (j * 256 + wv * 64) * 8);
      if (j < 2)
        gload_lds16(Bbase + (size_t)r * K + k0 + kc * 8, Bs + (j * 256 + wv * 64) * 8);
    }
    __syncthreads();
#pragma unroll
    for (int ks = 0; ks < 2; ks++) {
      bf16x8 af[4], bf[2];
#pragma unroll
      for (int mm = 0; mm < 4; mm++) {
        int row = wr + mm * 16 + fr;
        af[mm] = *(const bf16x8*)(As + row * 64 + (((ks * 4 + g) ^ (row & 7)) * 8));
      }
#pragma unroll
      for (int nn = 0; nn < 2; nn++) {
        int row = wc + nn * 16 + fr;
        bf[nn] = *(const bf16x8*)(Bs + row * 64 + (((ks * 4 + g) ^ (row & 7)) * 8));
      }
#pragma unroll
      for (int mm = 0; mm < 4; mm++)
#pragma unroll
        for (int nn = 0; nn < 2; nn++)
          acc[mm][nn] = __builtin_amdgcn_mfma_f32_16x16x32_bf16(af[mm], bf[nn], acc[mm][nn], 0, 0, 0);
    }
    __syncthreads();
  }

  if (MODE == 3) {
    if (bn * 64 < 128) {     // k block: fused rope (lat table)
#pragma unroll
      for (int mm = 0; mm < 4; mm++)
#pragma unroll
        for (int nn = 0; nn < 2; nn++) {
          int gc = bn * 64 + wc + nn * 16 + fr;
          int d = gc & 63;
#pragma unroll
          for (int i = 0; i < 4; i++) {
            int gr = bm * 128 + wr + mm * 16 + g * 4 + i;
            float val = acc[mm][nn][i];
            float prt = __shfl_xor(val, 1);
            float2 csv = cs[(size_t)gr * 64 + d];
            outB[(size_t)gr * N + gc] = f2bf(rope_rot(fr & 1, val, prt, csv));
          }
        }
    } else {                 // v block: transposed store
#pragma unroll
      for (int mm = 0; mm < 4; mm++)
#pragma unroll
        for (int nn = 0; nn < 2; nn++) {
          int gc = bn * 64 + wc + nn * 16 + fr;
          int ch = gc - 128;
          int gr0 = bm * 128 + wr + mm * 16 + g * 4;
          int bb = gr0 >> 11, t0 = gr0 & 2047;
          uint2 w;
          w.x = packbf2(acc[mm][nn][0], acc[mm][nn][1]);
          w.y = packbf2(acc[mm][nn][2], acc[mm][nn][3]);
          *(uint2*)(vt + ((size_t)bb * 128 + ch) * 2048 + t0) = w;
        }
    }
  } else {
#pragma unroll
    for (int mm = 0; mm < 4; mm++)
#pragma unroll
      for (int nn = 0; nn < 2; nn++)
#pragma unroll
        for (int i = 0; i < 4; i++) {
          int gr = bm * 128 + wr + mm * 16 + g * 4 + i;
          int gc = bn * 64 + wc + nn * 16 + fr;
          float val = acc[mm][nn][i] + (bias ? bias[gc] : 0.f);
          if (MODE == 0) outB[(size_t)gr * N + gc] = f2bf(val);
          else resOut[(size_t)gr * N + gc] = resIn[(size_t)gr * N + gc] + val;
        }
  }
}

// ------- 64x64 GEMM with fused rope (+0.125) epilogue (cross-q only) ---------
__global__ __launch_bounds__(256) void gemm64_rope(const ushort* __restrict__ A,
    const ushort* __restrict__ Bt, ushort* __restrict__ outB,
    const float2* __restrict__ cs, int M, int N, int K) {
  __shared__ __align__(16) ushort As[64][40];
  __shared__ __align__(16) ushort Bs[64][40];
  int t = threadIdx.x;
  int bm = blockIdx.y, bn = blockIdx.x;
  int row = t >> 2, kc = (t & 3) << 3;
  const ushort* aG = A + (size_t)(bm * 64 + row) * K + kc;
  const ushort* bG = Bt + (size_t)(bn * 64 + row) * K + kc;
  int wv = t >> 6, lane = t & 63;
  int wr = (wv >> 1) * 32, wc = (wv & 1) * 32;
  int fr = lane & 15, fk = (lane >> 4) << 3;
  f32x4 acc[2][2] = {};
  for (int k0 = 0; k0 < K; k0 += 32) {
    *(uint4*)&As[row][kc] = *(const uint4*)(aG + k0);
    *(uint4*)&Bs[row][kc] = *(const uint4*)(bG + k0);
    __syncthreads();
    bf16x8 a0 = *(const bf16x8*)&As[wr + fr][fk];
    bf16x8 a1 = *(const bf16x8*)&As[wr + 16 + fr][fk];
    bf16x8 b0 = *(const bf16x8*)&Bs[wc + fr][fk];
    bf16x8 b1 = *(const bf16x8*)&Bs[wc + 16 + fr][fk];
    acc[0][0] = __builtin_amdgcn_mfma_f32_16x16x32_bf16(a0, b0, acc[0][0], 0, 0, 0);
    acc[0][1] = __builtin_amdgcn_mfma_f32_16x16x32_bf16(a0, b1, acc[0][1], 0, 0, 0);
    acc[1][0] = __builtin_amdgcn_mfma_f32_16x16x32_bf16(a1, b0, acc[1][0], 0, 0, 0);
    acc[1][1] = __builtin_amdgcn_mfma_f32_16x16x32_bf16(a1, b1, acc[1][1], 0, 0, 0);
    __syncthreads();
  }
  int cr0 = wr + ((lane >> 4) << 2);
  int cc0 = wc + fr;
#pragma unroll
  for (int mm = 0; mm < 2; mm++)
#pragma unroll
    for (int nn = 0; nn < 2; nn++) {
      int gc = bn * 64 + cc0 + nn * 16;
      int d = gc & 63;
#pragma unroll
      for (int i = 0; i < 4; i++) {
        int gr = bm * 64 + cr0 + mm * 16 + i;
        float val = acc[mm][nn][i];
        float prt = __shfl_xor(val, 1);
        float2 csv = cs[(size_t)gr * 64 + d];
        outB[(size_t)gr * N + gc] = f2bf(rope_rot(fr & 1, val, prt, csv) * 0.125f);
      }
    }
}

// ---------------- MFMA flash attention, swapped operands ---------------------
template<int CAUSAL>
__global__ __launch_bounds__(256) void attn_mfma(
    const ushort* __restrict__ Q, const ushort* __restrict__ K,
    const ushort* __restrict__ Vt, ushort* __restrict__ O,
    int qStride, int kStride, int kOff, int oStride,
    int Tq, int NK, int H) {
  __shared__ __align__(16) ushort Ks[64 * 64];
  __shared__ __align__(16) ushort Vs[64 * 64];
  __shared__ __align__(16) ushort Ps[4][16 * 72];
  int b = blockIdx.z, h = blockIdx.y;
  int qt = CAUSAL ? ((int)gridDim.x - 1 - (int)blockIdx.x) : blockIdx.x;
  int t = threadIdx.x, wv = t >> 6, lane = t & 63;
  int g = lane >> 4, fr = lane & 15;
  int qw = qt * 64 + wv * 16;
  int HD = H * 64;

  const ushort* qrow = Q + (size_t)(b * Tq + qw + fr) * qStride + h * 64;
  bf16x8 qlo = *(const bf16x8*)(qrow + g * 8);
  bf16x8 qhi = *(const bf16x8*)(qrow + 32 + g * 8);

  f32x4 o_acc[4] = {};
  float m_run = -1e30f, l_run = 0.f;

  uint32_t* Pw = (uint32_t*)&Ps[wv][0];
  int ntiles = CAUSAL ? (qt + 1) : (NK / 64);
  for (int kt = 0; kt < ntiles; kt++) {
    int k0 = kt * 64;
    __syncthreads();
#pragma unroll
    for (int i = 0; i < 2; i++) {
      int id = t + i * 256;
      int r = id >> 3, c = id & 7;
      uint4 kval = *(const uint4*)(K + (size_t)(b * NK + k0 + r) * kStride + kOff + h * 64 + c * 8);
      *(uint4*)(Ks + r * 64 + ((c ^ (r & 7)) * 8)) = kval;
      uint4 vval = *(const uint4*)(Vt + ((size_t)b * HD + h * 64 + r) * NK + k0 + c * 8);
      *(uint4*)(Vs + r * 64 + ((c ^ (r & 7)) * 8)) = vval;
    }
    __syncthreads();

    f32x4 s[4];
#pragma unroll
    for (int nn = 0; nn < 4; nn++) {
      int row = nn * 16 + fr;
      bf16x8 kf0 = *(const bf16x8*)(Ks + row * 64 + ((g ^ (fr & 7)) * 8));
      bf16x8 kf1 = *(const bf16x8*)(Ks + row * 64 + (((4 + g) ^ (fr & 7)) * 8));
      f32x4 z = {};
      z = __builtin_amdgcn_mfma_f32_16x16x32_bf16(kf0, qlo, z, 0, 0, 0);
      z = __builtin_amdgcn_mfma_f32_16x16x32_bf16(kf1, qhi, z, 0, 0, 0);
      s[nn] = z;
    }
    if (CAUSAL && (k0 + 63 > qw)) {
#pragma unroll
      for (int nn = 0; nn < 4; nn++)
#pragma unroll
        for (int i = 0; i < 4; i++)
          if (k0 + nn * 16 + g * 4 + i > qw + fr) s[nn][i] = -1e30f;
    }
    float tm = s[0][0];
#pragma unroll
    for (int nn = 0; nn < 4; nn++)
#pragma unroll
      for (int i = 0; i < 4; i++) tm = fmaxf(tm, s[nn][i]);
    tm = fmaxf(tm, __shfl_xor(tm, 16));
    tm = fmaxf(tm, __shfl_xor(tm, 32));
    float mnew = fmaxf(m_run, tm);
    float corr = __expf(m_run - mnew);
    float ps = 0.f;
#pragma unroll
    for (int nn = 0; nn < 4; nn++)
#pragma unroll
      for (int i = 0; i < 4; i++) {
        float p = __expf(s[nn][i] - mnew);
        s[nn][i] = p;
        ps += p;
      }
    ps += __shfl_xor(ps, 16);
    ps += __shfl_xor(ps, 32);
    l_run = l_run * corr + ps;
    m_run = mnew;
#pragma unroll
    for (int dd = 0; dd < 4; dd++) o_acc[dd] *= corr;
#pragma unroll
    for (int nn = 0; nn < 4; nn++)
#pragma unroll
      for (int p = 0; p < 2; p++)
        Pw[fr * 36 + 8 * nn + 2 * g + p] = packbf2(s[nn][2 * p], s[nn][2 * p + 1]);
    bf16x8 pa0 = *(const bf16x8*)(&Ps[wv][fr * 72 + g * 8]);
    bf16x8 pa1 = *(const bf16x8*)(&Ps[wv][fr * 72 + 32 + g * 8]);
#pragma unroll
    for (int dd = 0; dd < 4; dd++) {
      int row = dd * 16 + fr;
      bf16x8 vf0 = *(const bf16x8*)(Vs + row * 64 + ((g ^ (fr & 7)) * 8));
      bf16x8 vf1 = *(const bf16x8*)(Vs + row * 64 + (((4 + g) ^ (fr & 7)) * 8));
      o_acc[dd] = __builtin_amdgcn_mfma_f32_16x16x32_bf16(vf0, pa0, o_acc[dd], 0, 0, 0);
      o_acc[dd] = __builtin_amdgcn_mfma_f32_16x16x32_bf16(vf1, pa1, o_acc[dd], 0, 0, 0);
    }
  }
  float rl = 1.f / l_run;
  ushort* obase = O + (size_t)(b * Tq + qw + fr) * oStride + h * 64;
#pragma unroll
  for (int dd = 0; dd < 4; dd++) {
    uint2 w;
    w.x = packbf2(o_acc[dd][0] * rl, o_acc[dd][1] * rl);
    w.y = packbf2(o_acc[dd][2] * rl, o_acc[dd][3] * rl);
    *(uint2*)(obase + dd * 16 + g * 4) = w;
  }
}

// ---------------- orchestration ----------------------------------------------
extern "C" void kernel_launch(void* const* d_in, const int* in_sizes, int n_in,
                              void* d_out, int out_size, void* d_ws, size_t ws_size,
                              hipStream_t stream) {
  const float* bin_queries = (const float*)d_in[0];
  const float* bin_time    = (const float*)d_in[1];
  const float* latents     = (const float*)d_in[2];
  const float* lat_time    = (const float*)d_in[3];
  const float* ca_lnq_w = (const float*)d_in[4];
  const float* ca_lnq_b = (const float*)d_in[5];
  const float* ca_lnc_w = (const float*)d_in[6];
  const float* ca_lnc_b = (const float*)d_in[7];
  const float* ca_wq  = (const float*)d_in[8];
  const float* ca_wkv = (const float*)d_in[9];
  const float* ca_wo  = (const float*)d_in[10];
  const float* ca_bo  = (const float*)d_in[11];
  const float* sa_ln_w = (const float*)d_in[12];
  const float* sa_ln_b = (const float*)d_in[13];
  const float* sa_wqkv = (const float*)d_in[14];
  const float* sa_wo   = (const float*)d_in[15];
  const float* sa_bo   = (const float*)d_in[16];
  const float* ffn_ln_w = (const float*)d_in[17];
  const float* ffn_ln_b = (const float*)d_in[18];
  const float* ffn_w1 = (const float*)d_in[19];
  const float* ffn_b1 = (const float*)d_in[20];
  const float* ffn_w2 = (const float*)d_in[21];
  const float* ffn_b2 = (const float*)d_in[22];

  constexpr size_t X_BYTES = (size_t)RQ * DIMc * 4;
  char* ws = (char*)d_ws;
  float* x = (float*)ws;
  char* A0 = ws + X_BYTES;
  // cross-attn phase
  ushort* cn     = (ushort*)(A0);
  ushort* ca_xn  = (ushort*)(A0 + 16777216);
  ushort* qbuf   = (ushort*)(A0 + 25165824);
  ushort* kv     = (ushort*)(A0 + 27262976);
  ushort* ca_att = (ushort*)(A0 + 35651584);
  ushort* vt_c   = (ushort*)(A0 + 37748736);
  // self-attn phase (reuses arena)
  ushort* sa_xn  = (ushort*)(A0);
  ushort* qkv    = (ushort*)(A0 + 8388608);
  ushort* sa_att = (ushort*)(A0 + 33554432);
  ushort* vt_s   = (ushort*)(A0 + 41943040);
  // ffn phase (reuses arena)
  ushort* hb     = (ushort*)(A0);
  ushort* ag     = (ushort*)(A0 + 8388608);
  // persistent cos/sin tables (gap between arena peak ~50MB and weights)
  float2* csQ = (float2*)(A0 + 62914560);   // 4 MB  (RQ*64)
  float2* csL = (float2*)(A0 + 67108864);   // 8 MB  (RL*64)
  // bf16 transposed weights for the current layer
  char* W0 = A0 + 109051904;
  ushort* wbase = (ushort*)W0;
  ushort* wqT  = wbase;
  ushort* wkvT = wbase + 65536;
  ushort* woT  = wbase + 196608;
  ushort* qkvT = wbase + 262144;
  ushort* swoT = wbase + 1048576;
  ushort* w1T  = wbase + 1310720;
  ushort* w2T  = wbase + 3407872;

  trig_prep<<<(RQ * 64) / 256, 256, 0, stream>>>(bin_time, csQ, RQ * 64);
  trig_prep<<<(RL * 64) / 256, 256, 0, stream>>>(lat_time, csL, RL * 64);

  for (int l = 0; l < 2; l++) {
    wtrans_all<<<4352, 256, 0, stream>>>(ca_wq, ca_wkv, ca_wo, sa_wqkv, sa_wo,
                                         ffn_w1, ffn_w2, wbase, l);

    // ---- cross attention ----
    const float* xin = (l == 0) ? bin_queries : x;
    ln_rows<<<RQ / 4, 256, 0, stream>>>(xin, ca_lnq_w + l * DIMc, ca_lnq_b + l * DIMc, ca_xn, RQ);
    ln_rows<<<RL / 4, 256, 0, stream>>>(latents, ca_lnc_w + l * DIMc, ca_lnc_b + l * DIMc, cn, RL);
    gemm64_rope<<<dim3(CIc / 64, RQ / 64), 256, 0, stream>>>(ca_xn, wqT, qbuf, csQ, RQ, CIc, DIMc);
    gemm128x64<3><<<dim3(2 * CIc / 64, RL / 128), 256, 0, stream>>>(cn, wkvT, nullptr,
        nullptr, nullptr, kv, RL, 2 * CIc, DIMc, csL, vt_c);
    attn_mfma<0><<<dim3(Tc / 64, CHc, Bc), 256, 0, stream>>>(qbuf, kv, vt_c, ca_att,
        CIc, 2 * CIc, 0, CIc, Tc, Nc, CHc);
    gemm128x64<1><<<dim3(DIMc / 64, RQ / 128), 256, 0, stream>>>(ca_att, woT, ca_bo + l * DIMc,
        xin, x, nullptr, RQ, DIMc, CIc, nullptr, nullptr);

    // ---- self attention (causal) ----
    ln_rows<<<RQ / 4, 256, 0, stream>>>(x, sa_ln_w + l * DIMc, sa_ln_b + l * DIMc, sa_xn, RQ);
    gemm128<3><<<dim3(3 * SIc / 128, RQ / 128), 256, 0, stream>>>(sa_xn, qkvT, nullptr,
        nullptr, nullptr, qkv, RQ, 3 * SIc, DIMc, csQ, vt_s);
    attn_mfma<1><<<dim3(Tc / 64, SHc, Bc), 256, 0, stream>>>(qkv, qkv, vt_s, sa_att,
        3 * SIc, 3 * SIc, SIc, SIc, Tc, Tc, SHc);
    gemm128x64<1><<<dim3(DIMc / 64, RQ / 128), 256, 0, stream>>>(sa_att, swoT, sa_bo + l * DIMc,
        x, x, nullptr, RQ, DIMc, SIc, nullptr, nullptr);

    // ---- FFN (w1 with fused bias + a*gelu(g) epilogue, shuffle-free) ----
    ln_rows<<<RQ / 4, 256, 0, stream>>>(x, ffn_ln_w + l * DIMc, ffn_ln_b + l * DIMc, hb, RQ);
    gemm128<2><<<dim3(2 * FFc / 128, RQ / 128), 256, 0, stream>>>(hb, w1T,
        ffn_b1 + (size_t)l * 2 * FFc, nullptr, nullptr, ag, RQ, 2 * FFc, DIMc, nullptr, nullptr);
    float* resOut = (l == 1) ? (float*)d_out : x;
    gemm128x64<1><<<dim3(DIMc / 64, RQ / 128), 256, 0, stream>>>(ag, w2T, ffn_b2 + l * DIMc,
        x, resOut, nullptr, RQ, DIMc, FFc, nullptr, nullptr);
  }
}

// Round 11
// 628.359 us; speedup vs baseline: 16.3211x; 1.0091x over previous
//
#include <hip/hip_runtime.h>
#include <cstdint>
#include <cstddef>

// ---------------- constants (match reference) ----------------
static constexpr int DIMc = 512;
static constexpr int DHc  = 64;
static constexpr int CHc  = 2;
static constexpr int SHc  = 8;
static constexpr int Bc   = 8;
static constexpr int Tc   = 1024;
static constexpr int Nc   = 2048;
static constexpr int CIc  = CHc * DHc;    // 128
static constexpr int SIc  = SHc * DHc;    // 512
static constexpr int FFc  = 4 * DIMc;     // 2048
static constexpr int RQ   = Bc * Tc;      // 8192 query rows
static constexpr int RL   = Bc * Nc;      // 16384 latent rows

typedef short bf16x8 __attribute__((ext_vector_type(8)));
typedef float f32x4  __attribute__((ext_vector_type(4)));

__device__ __forceinline__ ushort f2bf(float f) {
  uint32_t u = __builtin_bit_cast(uint32_t, f);
  u += 0x7fffu + ((u >> 16) & 1u);
  return (ushort)(u >> 16);
}
__device__ __forceinline__ uint32_t packbf2(float a, float b) {
  return (uint32_t)f2bf(a) | ((uint32_t)f2bf(b) << 16);
}
__device__ __forceinline__ float bf2f(ushort h) {
  uint32_t u = ((uint32_t)h) << 16;
  return __builtin_bit_cast(float, u);
}

__device__ __forceinline__ void gload_lds16(const ushort* g, ushort* lds) {
  __builtin_amdgcn_global_load_lds(
      (const __attribute__((address_space(1))) void*)g,
      (__attribute__((address_space(3))) void*)lds, 16, 0, 0);
}

// asm ds_read_b128: invisible to compiler's lgkm/vmcnt tracking (manual waits)
__device__ __forceinline__ bf16x8 ds_read8(const ushort* p) {
  bf16x8 d;
  asm volatile("ds_read_b128 %0, %1"
               : "=v"(d)
               : "v"((const __attribute__((address_space(3))) ushort*)p));
  return d;
}

// fast gelu: tanh form; |err| < 3e-3 abs, well under the bf16 tolerance.
__device__ __forceinline__ float gelu_fast(float g) {
  float u = g * (0.7978845608f + 0.0356774081f * g * g);
  float e = __expf(2.f * u);
  float th = 1.f - 2.f * __builtin_amdgcn_rcpf(1.f + e);
  return 0.5f * g * (1.f + th);
}

// rope rotate: even d: v*c - p*s ; odd d: v*c + p*s  (p = partner lane value)
__device__ __forceinline__ float rope_rot(int odd, float v, float p, float2 cs) {
  return odd ? (v * cs.x + p * cs.y) : (v * cs.x - p * cs.y);
}

// ---------------- cos/sin table prep: dst[i] = (cos(src[i]), sin(src[i])) ----
__global__ __launch_bounds__(256) void trig_prep(const float* __restrict__ src,
    float2* __restrict__ dst, int n) {
  int i = blockIdx.x * 256 + threadIdx.x;
  if (i >= n) return;
  float s, c;
  __sincosf(src[i], &s, &c);
  dst[i] = make_float2(c, s);
}

// ---------------- LayerNorm: one wave per 512-col row, fp32 in -> bf16 out ----
__global__ __launch_bounds__(256) void ln_rows(const float* __restrict__ X,
    const float* __restrict__ w, const float* __restrict__ b,
    ushort* __restrict__ out, int rows) {
  int gw = (int)((blockIdx.x * 256 + threadIdx.x) >> 6);
  int lane = threadIdx.x & 63;
  if (gw >= rows) return;
  const float* xr = X + (size_t)gw * DIMc;
  float4 v0 = *(const float4*)(xr + lane * 8);
  float4 v1 = *(const float4*)(xr + lane * 8 + 4);
  float xv[8] = {v0.x, v0.y, v0.z, v0.w, v1.x, v1.y, v1.z, v1.w};
  float s = 0.f, ss = 0.f;
#pragma unroll
  for (int i = 0; i < 8; i++) { s += xv[i]; ss += xv[i] * xv[i]; }
#pragma unroll
  for (int off = 32; off; off >>= 1) { s += __shfl_xor(s, off); ss += __shfl_xor(ss, off); }
  float mean = s * (1.f / DIMc);
  float var = ss * (1.f / DIMc) - mean * mean;
  float r = rsqrtf(var + 1e-5f);
  int c = lane * 8;
  ushort o[8] __attribute__((aligned(16)));
#pragma unroll
  for (int i = 0; i < 8; i++) o[i] = f2bf((xv[i] - mean) * r * w[c + i] + b[c + i]);
  *(uint4*)(out + (size_t)gw * DIMc + c) = *(const uint4*)o;
}

// ------------- ALL weight transposes for one layer, one launch ----------------
// wid 5 (ffn_w1): 16-col-granular interleave for the shuffle-free gelu epilogue.
__global__ __launch_bounds__(256) void wtrans_all(
    const float* __restrict__ wq, const float* __restrict__ wkv,
    const float* __restrict__ wo, const float* __restrict__ qkv,
    const float* __restrict__ swo, const float* __restrict__ w1,
    const float* __restrict__ w2, ushort* __restrict__ dst, int layer) {
  constexpr int Ks[7]   = {512, 512, 128, 512, 512, 512, 2048};
  constexpr int Ns[7]   = {128, 256, 512, 1536, 512, 4096, 512};
  constexpr int pre[8]  = {0, 64, 192, 256, 1024, 1280, 3328, 4352};
  constexpr int dOff[7] = {0, 65536, 196608, 262144, 1048576, 1310720, 3407872};
  int bid = blockIdx.x;
  int wid = 0;
#pragma unroll
  for (int i = 1; i < 7; i++) wid += (bid >= pre[i]);
  int tileIdx = bid - pre[wid];
  int K = Ks[wid], N = Ns[wid];
  const float* srcs[7] = {wq, wkv, wo, qkv, swo, w1, w2};
  const float* W = srcs[wid] + (size_t)layer * K * N;
  ushort* Wt = dst + dOff[wid];
  int ntx = N / 32;
  int n0 = (tileIdx % ntx) * 32, k0 = (tileIdx / ntx) * 32;
  __shared__ float tile[32][33];
  int tx = threadIdx.x & 31, ty = threadIdx.x >> 5;
#pragma unroll
  for (int i = 0; i < 32; i += 8)
    tile[ty + i][tx] = W[(size_t)(k0 + ty + i) * N + n0 + tx];
  __syncthreads();
  if (wid == 5) {
#pragma unroll
    for (int i = 0; i < 32; i += 8) {
      int nrow = n0 + ty + i;
      int p = nrow & 2047;
      int rowT = ((p >> 4) << 5) + ((nrow < 2048) ? 0 : 16) + (p & 15);
      Wt[(size_t)rowT * K + k0 + tx] = f2bf(tile[tx][ty + i]);
    }
  } else {
#pragma unroll
    for (int i = 0; i < 32; i += 8)
      Wt[(size_t)(n0 + ty + i) * K + k0 + tx] = f2bf(tile[tx][ty + i]);
  }
}

// ------- 128x128 GEMM, BK=64, single-buffer (proven r3 structure) ------------
// MODE 0: outB = bf16(acc + bias)
// MODE 1: resOut = resIn + acc + bias   (fp32)
// MODE 2: fused FFN gate (16-col interleaved w1T): write bf16(a*gelu(g)), N/2.
// MODE 3: self-qkv fused rope+vt.
template<int MODE>
__global__ __launch_bounds__(256) void gemm128(const ushort* __restrict__ A,
    const ushort* __restrict__ Bt, const float* __restrict__ bias,
    const float* __restrict__ resIn, float* __restrict__ resOut,
    ushort* __restrict__ outB, int M, int N, int K,
    const float2* __restrict__ cs, ushort* __restrict__ vt) {
  __shared__ __align__(16) ushort As[128 * 64];
  __shared__ __align__(16) ushort Bs[128 * 64];
  int t = threadIdx.x, wv = t >> 6, lane = t & 63;
  int bm = blockIdx.y, bn = blockIdx.x;
  int fr = lane & 15, g = lane >> 4;
  int wr = (wv >> 1) * 64, wc = (wv & 1) * 64;
  int srow = wv * 32 + (lane >> 3);
  int sslot = lane & 7;
  const ushort* Abase = A + (size_t)(bm * 128) * K;
  const ushort* Bbase = Bt + (size_t)(bn * 128) * K;

  f32x4 acc[4][4] = {};
  for (int k0 = 0; k0 < K; k0 += 64) {
#pragma unroll
    for (int j = 0; j < 4; j++) {
      int r = srow + j * 8;
      int kc = sslot ^ (r & 7);
      gload_lds16(Abase + (size_t)r * K + k0 + kc * 8, As + (wv * 256 + j * 64) * 8);
      gload_lds16(Bbase + (size_t)r * K + k0 + kc * 8, Bs + (wv * 256 + j * 64) * 8);
    }
    __syncthreads();
#pragma unroll
    for (int ks = 0; ks < 2; ks++) {
      bf16x8 af[4], bf[4];
#pragma unroll
      for (int mm = 0; mm < 4; mm++) {
        int row = wr + mm * 16 + fr;
        af[mm] = *(const bf16x8*)(As + row * 64 + (((ks * 4 + g) ^ (row & 7)) * 8));
      }
#pragma unroll
      for (int nn = 0; nn < 4; nn++) {
        int row = wc + nn * 16 + fr;
        bf[nn] = *(const bf16x8*)(Bs + row * 64 + (((ks * 4 + g) ^ (row & 7)) * 8));
      }
#pragma unroll
      for (int mm = 0; mm < 4; mm++)
#pragma unroll
        for (int nn = 0; nn < 4; nn++)
          acc[mm][nn] = __builtin_amdgcn_mfma_f32_16x16x32_bf16(af[mm], bf[nn], acc[mm][nn], 0, 0, 0);
    }
    __syncthreads();
  }

  if (MODE == 2) {
    int NH = N >> 1;
#pragma unroll
    for (int mm = 0; mm < 4; mm++)
#pragma unroll
      for (int np = 0; np < 2; np++) {
        int ocol = bn * 64 + (wc >> 1) + np * 16 + fr;
        float ba = bias[ocol];
        float bg = bias[NH + ocol];
#pragma unroll
        for (int i = 0; i < 4; i++) {
          int gr = bm * 128 + wr + mm * 16 + g * 4 + i;
          float a = acc[mm][np * 2][i] + ba;
          float gv = acc[mm][np * 2 + 1][i] + bg;
          outB[(size_t)gr * NH + ocol] = f2bf(a * gelu_fast(gv));
        }
      }
  } else if (MODE == 3) {
    if (bn * 128 < 1024) {   // q/k block: fused rope (+0.125 scale on q)
#pragma unroll
      for (int mm = 0; mm < 4; mm++)
#pragma unroll
        for (int nn = 0; nn < 4; nn++) {
          int gc = bn * 128 + wc + nn * 16 + fr;
          int d = gc & 63;
          float sc = (gc < 512) ? 0.125f : 1.f;
#pragma unroll
          for (int i = 0; i < 4; i++) {
            int gr = bm * 128 + wr + mm * 16 + g * 4 + i;
            float val = acc[mm][nn][i];
            float prt = __shfl_xor(val, 1);
            float2 csv = cs[(size_t)gr * 64 + d];
            outB[(size_t)gr * N + gc] = f2bf(rope_rot(fr & 1, val, prt, csv) * sc);
          }
        }
    } else {                 // v block: transposed store to vt[b][ch][t]
#pragma unroll
      for (int mm = 0; mm < 4; mm++)
#pragma unroll
        for (int nn = 0; nn < 4; nn++) {
          int gc = bn * 128 + wc + nn * 16 + fr;
          int ch = gc - 1024;
          int gr0 = bm * 128 + wr + mm * 16 + g * 4;
          int bb = gr0 >> 10, t0 = gr0 & 1023;
          uint2 w;
          w.x = packbf2(acc[mm][nn][0], acc[mm][nn][1]);
          w.y = packbf2(acc[mm][nn][2], acc[mm][nn][3]);
          *(uint2*)(vt + ((size_t)bb * 512 + ch) * 1024 + t0) = w;
        }
    }
  } else {
#pragma unroll
    for (int mm = 0; mm < 4; mm++)
#pragma unroll
      for (int nn = 0; nn < 4; nn++)
#pragma unroll
        for (int i = 0; i < 4; i++) {
          int gr = bm * 128 + wr + mm * 16 + g * 4 + i;
          int gc = bn * 128 + wc + nn * 16 + fr;
          float val = acc[mm][nn][i] + (bias ? bias[gc] : 0.f);
          if (MODE == 0) outB[(size_t)gr * N + gc] = f2bf(val);
          else resOut[(size_t)gr * N + gc] = resIn[(size_t)gr * N + gc] + val;
        }
  }
}

// ------- 256x256 GEMM, BK=64, 8-wave 4-phase COUNTED-vmcnt pipeline ----------
// T3+T4 structure (m201-class): dbuf 128 KB LDS, per iter: vmcnt(8) keeps the
// NEXT tile's 8 loads in flight; 4 phases of {24 asm ds_read -> lgkmcnt(0) ->
// setprio(1) 16 MFMA setprio(0) -> barrier}; stage tile tt+2 after last phase.
// Fused 16-col-interleaved a*gelu(g) epilogue (w1 only).
__global__ __launch_bounds__(512, 2) void gemm256_gelu(
    const ushort* __restrict__ A, const ushort* __restrict__ Bt,
    const float* __restrict__ bias, ushort* __restrict__ outB,
    int M, int N, int K) {
  __shared__ __align__(16) ushort As[2][256 * 64];   // 64 KB
  __shared__ __align__(16) ushort Bs[2][256 * 64];   // 64 KB
  int t = threadIdx.x, wv = t >> 6, lane = t & 63;
  int bm = blockIdx.y, bn = blockIdx.x;
  int fr = lane & 15, g = lane >> 4;
  int wr = (wv >> 2) * 128, wc = (wv & 3) * 64;      // 2M x 4N wave grid
  int srow = wv * 32 + (lane >> 3);
  int sslot = lane & 7;
  const ushort* Abase = A + (size_t)(bm * 256) * K;
  const ushort* Bbase = Bt + (size_t)(bn * 256) * K;

  f32x4 acc[8][4] = {};
  int nt = K >> 6;   // 8 for K=512

#define STG256(buf, kt)                                                       \
  {                                                                           \
    _Pragma("unroll")                                                         \
    for (int j = 0; j < 4; j++) {                                             \
      int r = srow + j * 8;                                                   \
      int kc = sslot ^ (r & 7);                                               \
      gload_lds16(Abase + (size_t)r * K + (kt) * 64 + kc * 8,                 \
                  &As[buf][(wv * 256 + j * 64) * 8]);                         \
      gload_lds16(Bbase + (size_t)r * K + (kt) * 64 + kc * 8,                 \
                  &Bs[buf][(wv * 256 + j * 64) * 8]);                         \
    }                                                                         \
  }

  STG256(0, 0);
  STG256(1, 1);

  for (int tt = 0; tt < nt; tt++) {
    int cur = tt & 1;
    // tile tt's 8 loads (oldest) done; tile tt+1's 8 may stay in flight (T4)
    if (tt + 1 < nt) asm volatile("s_waitcnt vmcnt(8)" ::: "memory");
    else             asm volatile("s_waitcnt vmcnt(0)" ::: "memory");
    __builtin_amdgcn_s_barrier();
    const ushort* Ac = As[cur];
    const ushort* Bc = Bs[cur];
#pragma unroll
    for (int ph = 0; ph < 4; ph++) {
      const int mh = ph >> 1, nh = ph & 1;
      bf16x8 af[2][4], bf[2][2];
#pragma unroll
      for (int ks = 0; ks < 2; ks++) {
#pragma unroll
        for (int mi = 0; mi < 4; mi++) {
          int row = wr + (mh * 4 + mi) * 16 + fr;
          af[ks][mi] = ds_read8(Ac + row * 64 + (((ks * 4 + g) ^ (row & 7)) * 8));
        }
#pragma unroll
        for (int ni = 0; ni < 2; ni++) {
          int row = wc + (nh * 2 + ni) * 16 + fr;
          bf[ks][ni] = ds_read8(Bc + row * 64 + (((ks * 4 + g) ^ (row & 7)) * 8));
        }
      }
      asm volatile("s_waitcnt lgkmcnt(0)" ::: "memory");
      __builtin_amdgcn_sched_barrier(0);           // rule 18: pin MFMA after wait
      __builtin_amdgcn_s_setprio(1);
#pragma unroll
      for (int ks = 0; ks < 2; ks++)
#pragma unroll
        for (int mi = 0; mi < 4; mi++)
#pragma unroll
          for (int ni = 0; ni < 2; ni++)
            acc[mh * 4 + mi][nh * 2 + ni] = __builtin_amdgcn_mfma_f32_16x16x32_bf16(
                af[ks][mi], bf[ks][ni], acc[mh * 4 + mi][nh * 2 + ni], 0, 0, 0);
      __builtin_amdgcn_s_setprio(0);
      __builtin_amdgcn_s_barrier();                // all waves done reading this phase
    }
    // buf[cur] fully consumed by all waves (last phase barrier) -> refill it
    if (tt + 2 < nt) STG256(cur, tt + 2);
  }
#undef STG256

  int NH = N >> 1;
#pragma unroll
  for (int mf = 0; mf < 8; mf++)
#pragma unroll
    for (int np = 0; np < 2; np++) {
      int ocol = bn * 128 + (wc >> 1) + np * 16 + fr;
      float ba = bias[ocol];
      float bg = bias[NH + ocol];
#pragma unroll
      for (int i = 0; i < 4; i++) {
        int gr = bm * 256 + wr + mf * 16 + g * 4 + i;
        float a = acc[mf][np * 2][i] + ba;
        float gv = acc[mf][np * 2 + 1][i] + bg;
        outB[(size_t)gr * NH + ocol] = f2bf(a * gelu_fast(gv));
      }
    }
}

// ------- 128x64 GEMM, BK=64, single-buffer, 24 KB LDS (high occupancy) -------
template<int MODE>
__global__ __launch_bounds__(256) void gemm128x64(const ushort* __restrict__ A,
    const ushort* __restrict__ Bt, const float* __restrict__ bias,
    const float* __restrict__ resIn, float* __restrict__ resOut,
    ushort* __restrict__ outB, int M, int N, int K,
    const float2* __restrict__ cs, ushort* __restrict__ vt) {
  __shared__ __align__(16) ushort As[128 * 64];   // 16 KB
  __shared__ __align__(16) ushort Bs[64 * 64];    //  8 KB
  int t = threadIdx.x, wv = t >> 6, lane = t & 63;
  int bm = blockIdx.y, bn = blockIdx.x;
  int fr = lane & 15, g = lane >> 4;
  int wr = (wv >> 1) * 64, wc = (wv & 1) * 32;
  const ushort* Abase = A + (size_t)(bm * 128) * K;
  const ushort* Bbase = Bt + (size_t)(bn * 64) * K;

  f32x4 acc[4][2] = {};
  for (int k0 = 0; k0 < K; k0 += 64) {
#pragma unroll
    for (int j = 0; j < 4; j++) {
      int c = j * 256 + wv * 64 + lane;
      int r = c >> 3, s = c & 7;
      int kc = s ^ (r & 7);
      gload_lds16(Abase + (size_t)r * K + k0 + kc * 8, As + (j * 256 + wv * 64) * 8);
      if (j < 2)
        gload_lds16(Bbase + (size_t)r * K + k0 + kc * 8, Bs + (j * 256 + wv * 64) * 8);
    }
    __syncthreads();
#pragma unroll
    for (int ks = 0; ks < 2; ks++) {
      bf16x8 af[4], bf[2];
#pragma unroll
      for (int mm = 0; mm < 4; mm++) {
        int row = wr + mm * 16 + fr;
        af[mm] = *(const bf16x8*)(As + row * 64 + (((ks * 4 + g) ^ (row & 7)) * 8));
      }
#pragma unroll
      for (int nn = 0; nn < 2; nn++) {
        int row = wc + nn * 16 + fr;
        bf[nn] = *(const bf16x8*)(Bs + row * 64 + (((ks * 4 + g) ^ (row & 7)) * 8));
      }
#pragma unroll
      for (int mm = 0; mm < 4; mm++)
#pragma unroll
        for (int nn = 0; nn < 2; nn++)
          acc[mm][nn] = __builtin_amdgcn_mfma_f32_16x16x32_bf16(af[mm], bf[nn], acc[mm][nn], 0, 0, 0);
    }
    __syncthreads();
  }

  if (MODE == 3) {
    if (bn * 64 < 128) {     // k block: fused rope (lat table)
#pragma unroll
      for (int mm = 0; mm < 4; mm++)
#pragma unroll
        for (int nn = 0; nn < 2; nn++) {
          int gc = bn * 64 + wc + nn * 16 + fr;
          int d = gc & 63;
#pragma unroll
          for (int i = 0; i < 4; i++) {
            int gr = bm * 128 + wr + mm * 16 + g * 4 + i;
            float val = acc[mm][nn][i];
            float prt = __shfl_xor(val, 1);
            float2 csv = cs[(size_t)gr * 64 + d];
            outB[(size_t)gr * N + gc] = f2bf(rope_rot(fr & 1, val, prt, csv));
          }
        }
    } else {                 // v block: transposed store
#pragma unroll
      for (int mm = 0; mm < 4; mm++)
#pragma unroll
        for (int nn = 0; nn < 2; nn++) {
          int gc = bn * 64 + wc + nn * 16 + fr;
          int ch = gc - 128;
          int gr0 = bm * 128 + wr + mm * 16 + g * 4;
          int bb = gr0 >> 11, t0 = gr0 & 2047;
          uint2 w;
          w.x = packbf2(acc[mm][nn][0], acc[mm][nn][1]);
          w.y = packbf2(acc[mm][nn][2], acc[mm][nn][3]);
          *(uint2*)(vt + ((size_t)bb * 128 + ch) * 2048 + t0) = w;
        }
    }
  } else {
#pragma unroll
    for (int mm = 0; mm < 4; mm++)
#pragma unroll
      for (int nn = 0; nn < 2; nn++)
#pragma unroll
        for (int i = 0; i < 4; i++) {
          int gr = bm * 128 + wr + mm * 16 + g * 4 + i;
          int gc = bn * 64 + wc + nn * 16 + fr;
          float val = acc[mm][nn][i] + (bias ? bias[gc] : 0.f);
          if (MODE == 0) outB[(size_t)gr * N + gc] = f2bf(val);
          else resOut[(size_t)gr * N + gc] = resIn[(size_t)gr * N + gc] + val;
        }
  }
}

// ------- 64x64 GEMM with fused rope (+0.125) epilogue (cross-q only) ---------
__global__ __launch_bounds__(256) void gemm64_rope(const ushort* __restrict__ A,
    const ushort* __restrict__ Bt, ushort* __restrict__ outB,
    const float2* __restrict__ cs, int M, int N, int K) {
  __shared__ __align__(16) ushort As[64][40];
  __shared__ __align__(16) ushort Bs[64][40];
  int t = threadIdx.x;
  int bm = blockIdx.y, bn = blockIdx.x;
  int row = t >> 2, kc = (t & 3) << 3;
  const ushort* aG = A + (size_t)(bm * 64 + row) * K + kc;
  const ushort* bG = Bt + (size_t)(bn * 64 + row) * K + kc;
  int wv = t >> 6, lane = t & 63;
  int wr = (wv >> 1) * 32, wc = (wv & 1) * 32;
  int fr = lane & 15, fk = (lane >> 4) << 3;
  f32x4 acc[2][2] = {};
  for (int k0 = 0; k0 < K; k0 += 32) {
    *(uint4*)&As[row][kc] = *(const uint4*)(aG + k0);
    *(uint4*)&Bs[row][kc] = *(const uint4*)(bG + k0);
    __syncthreads();
    bf16x8 a0 = *(const bf16x8*)&As[wr + fr][fk];
    bf16x8 a1 = *(const bf16x8*)&As[wr + 16 + fr][fk];
    bf16x8 b0 = *(const bf16x8*)&Bs[wc + fr][fk];
    bf16x8 b1 = *(const bf16x8*)&Bs[wc + 16 + fr][fk];
    acc[0][0] = __builtin_amdgcn_mfma_f32_16x16x32_bf16(a0, b0, acc[0][0], 0, 0, 0);
    acc[0][1] = __builtin_amdgcn_mfma_f32_16x16x32_bf16(a0, b1, acc[0][1], 0, 0, 0);
    acc[1][0] = __builtin_amdgcn_mfma_f32_16x16x32_bf16(a1, b0, acc[1][0], 0, 0, 0);
    acc[1][1] = __builtin_amdgcn_mfma_f32_16x16x32_bf16(a1, b1, acc[1][1], 0, 0, 0);
    __syncthreads();
  }
  int cr0 = wr + ((lane >> 4) << 2);
  int cc0 = wc + fr;
#pragma unroll
  for (int mm = 0; mm < 2; mm++)
#pragma unroll
    for (int nn = 0; nn < 2; nn++) {
      int gc = bn * 64 + cc0 + nn * 16;
      int d = gc & 63;
#pragma unroll
      for (int i = 0; i < 4; i++) {
        int gr = bm * 64 + cr0 + mm * 16 + i;
        float val = acc[mm][nn][i];
        float prt = __shfl_xor(val, 1);
        float2 csv = cs[(size_t)gr * 64 + d];
        outB[(size_t)gr * N + gc] = f2bf(rope_rot(fr & 1, val, prt, csv) * 0.125f);
      }
    }
}

// ---------------- MFMA flash attention, swapped operands ---------------------
template<int CAUSAL>
__global__ __launch_bounds__(256) void attn_mfma(
    const ushort* __restrict__ Q, const ushort* __restrict__ K,
    const ushort* __restrict__ Vt, ushort* __restrict__ O,
    int qStride, int kStride, int kOff, int oStride,
    int Tq, int NK, int H) {
  __shared__ __align__(16) ushort Ks[64 * 64];
  __shared__ __align__(16) ushort Vs[64 * 64];
  __shared__ __align__(16) ushort Ps[4][16 * 72];
  int b = blockIdx.z, h = blockIdx.y;
  int qt = CAUSAL ? ((int)gridDim.x - 1 - (int)blockIdx.x) : blockIdx.x;
  int t = threadIdx.x, wv = t >> 6, lane = t & 63;
  int g = lane >> 4, fr = lane & 15;
  int qw = qt * 64 + wv * 16;
  int HD = H * 64;

  const ushort* qrow = Q + (size_t)(b * Tq + qw + fr) * qStride + h * 64;
  bf16x8 qlo = *(const bf16x8*)(qrow + g * 8);
  bf16x8 qhi = *(const bf16x8*)(qrow + 32 + g * 8);

  f32x4 o_acc[4] = {};
  float m_run = -1e30f, l_run = 0.f;

  uint32_t* Pw = (uint32_t*)&Ps[wv][0];
  int ntiles = CAUSAL ? (qt + 1) : (NK / 64);
  for (int kt = 0; kt < ntiles; kt++) {
    int k0 = kt * 64;
    __syncthreads();
#pragma unroll
    for (int i = 0; i < 2; i++) {
      int id = t + i * 256;
      int r = id >> 3, c = id & 7;
      uint4 kval = *(const uint4*)(K + (size_t)(b * NK + k0 + r) * kStride + kOff + h * 64 + c * 8);
      *(uint4*)(Ks + r * 64 + ((c ^ (r & 7)) * 8)) = kval;
      uint4 vval = *(const uint4*)(Vt + ((size_t)b * HD + h * 64 + r) * NK + k0 + c * 8);
      *(uint4*)(Vs + r * 64 + ((c ^ (r & 7)) * 8)) = vval;
    }
    __syncthreads();

    f32x4 s[4];
#pragma unroll
    for (int nn = 0; nn < 4; nn++) {
      int row = nn * 16 + fr;
      bf16x8 kf0 = *(const bf16x8*)(Ks + row * 64 + ((g ^ (fr & 7)) * 8));
      bf16x8 kf1 = *(const bf16x8*)(Ks + row * 64 + (((4 + g) ^ (fr & 7)) * 8));
      f32x4 z = {};
      z = __builtin_amdgcn_mfma_f32_16x16x32_bf16(kf0, qlo, z, 0, 0, 0);
      z = __builtin_amdgcn_mfma_f32_16x16x32_bf16(kf1, qhi, z, 0, 0, 0);
      s[nn] = z;
    }
    if (CAUSAL && (k0 + 63 > qw)) {
#pragma unroll
      for (int nn = 0; nn < 4; nn++)
#pragma unroll
        for (int i = 0; i < 4; i++)
          if (k0 + nn * 16 + g * 4 + i > qw + fr) s[nn][i] = -1e30f;
    }
    float tm = s[0][0];
#pragma unroll
    for (int nn = 0; nn < 4; nn++)
#pragma unroll
      for (int i = 0; i < 4; i++) tm = fmaxf(tm, s[nn][i]);
    tm = fmaxf(tm, __shfl_xor(tm, 16));
    tm = fmaxf(tm, __shfl_xor(tm, 32));
    float mnew = fmaxf(m_run, tm);
    float corr = __expf(m_run - mnew);
    float ps = 0.f;
#pragma unroll
    for (int nn = 0; nn < 4; nn++)
#pragma unroll
      for (int i = 0; i < 4; i++) {
        float p = __expf(s[nn][i] - mnew);
        s[nn][i] = p;
        ps += p;
      }
    ps += __shfl_xor(ps, 16);
    ps += __shfl_xor(ps, 32);
    l_run = l_run * corr + ps;
    m_run = mnew;
#pragma unroll
    for (int dd = 0; dd < 4; dd++) o_acc[dd] *= corr;
#pragma unroll
    for (int nn = 0; nn < 4; nn++)
#pragma unroll
      for (int p = 0; p < 2; p++)
        Pw[fr * 36 + 8 * nn + 2 * g + p] = packbf2(s[nn][2 * p], s[nn][2 * p + 1]);
    bf16x8 pa0 = *(const bf16x8*)(&Ps[wv][fr * 72 + g * 8]);
    bf16x8 pa1 = *(const bf16x8*)(&Ps[wv][fr * 72 + 32 + g * 8]);
#pragma unroll
    for (int dd = 0; dd < 4; dd++) {
      int row = dd * 16 + fr;
      bf16x8 vf0 = *(const bf16x8*)(Vs + row * 64 + ((g ^ (fr & 7)) * 8));
      bf16x8 vf1 = *(const bf16x8*)(Vs + row * 64 + (((4 + g) ^ (fr & 7)) * 8));
      o_acc[dd] = __builtin_amdgcn_mfma_f32_16x16x32_bf16(vf0, pa0, o_acc[dd], 0, 0, 0);
      o_acc[dd] = __builtin_amdgcn_mfma_f32_16x16x32_bf16(vf1, pa1, o_acc[dd], 0, 0, 0);
    }
  }
  float rl = 1.f / l_run;
  ushort* obase = O + (size_t)(b * Tq + qw + fr) * oStride + h * 64;
#pragma unroll
  for (int dd = 0; dd < 4; dd++) {
    uint2 w;
    w.x = packbf2(o_acc[dd][0] * rl, o_acc[dd][1] * rl);
    w.y = packbf2(o_acc[dd][2] * rl, o_acc[dd][3] * rl);
    *(uint2*)(obase + dd * 16 + g * 4) = w;
  }
}

// ---------------- orchestration ----------------------------------------------
extern "C" void kernel_launch(void* const* d_in, const int* in_sizes, int n_in,
                              void* d_out, int out_size, void* d_ws, size_t ws_size,
                              hipStream_t stream) {
  const float* bin_queries = (const float*)d_in[0];
  const float* bin_time    = (const float*)d_in[1];
  const float* latents     = (const float*)d_in[2];
  const float* lat_time    = (const float*)d_in[3];
  const float* ca_lnq_w = (const float*)d_in[4];
  const float* ca_lnq_b = (const float*)d_in[5];
  const float* ca_lnc_w = (const float*)d_in[6];
  const float* ca_lnc_b = (const float*)d_in[7];
  const float* ca_wq  = (const float*)d_in[8];
  const float* ca_wkv = (const float*)d_in[9];
  const float* ca_wo  = (const float*)d_in[10];
  const float* ca_bo  = (const float*)d_in[11];
  const float* sa_ln_w = (const float*)d_in[12];
  const float* sa_ln_b = (const float*)d_in[13];
  const float* sa_wqkv = (const float*)d_in[14];
  const float* sa_wo   = (const float*)d_in[15];
  const float* sa_bo   = (const float*)d_in[16];
  const float* ffn_ln_w = (const float*)d_in[17];
  const float* ffn_ln_b = (const float*)d_in[18];
  const float* ffn_w1 = (const float*)d_in[19];
  const float* ffn_b1 = (const float*)d_in[20];
  const float* ffn_w2 = (const float*)d_in[21];
  const float* ffn_b2 = (const float*)d_in[22];

  constexpr size_t X_BYTES = (size_t)RQ * DIMc * 4;
  char* ws = (char*)d_ws;
  float* x = (float*)ws;
  char* A0 = ws + X_BYTES;
  // cross-attn phase
  ushort* cn     = (ushort*)(A0);
  ushort* ca_xn  = (ushort*)(A0 + 16777216);
  ushort* qbuf   = (ushort*)(A0 + 25165824);
  ushort* kv     = (ushort*)(A0 + 27262976);
  ushort* ca_att = (ushort*)(A0 + 35651584);
  ushort* vt_c   = (ushort*)(A0 + 37748736);
  // self-attn phase (reuses arena)
  ushort* sa_xn  = (ushort*)(A0);
  ushort* qkv    = (ushort*)(A0 + 8388608);
  ushort* sa_att = (ushort*)(A0 + 33554432);
  ushort* vt_s   = (ushort*)(A0 + 41943040);
  // ffn phase (reuses arena)
  ushort* hb     = (ushort*)(A0);
  ushort* ag     = (ushort*)(A0 + 8388608);
  // persistent cos/sin tables
  float2* csQ = (float2*)(A0 + 62914560);   // 4 MB  (RQ*64)
  float2* csL = (float2*)(A0 + 67108864);   // 8 MB  (RL*64)
  // bf16 transposed weights for the current layer
  char* W0 = A0 + 109051904;
  ushort* wbase = (ushort*)W0;
  ushort* wqT  = wbase;
  ushort* wkvT = wbase + 65536;
  ushort* woT  = wbase + 196608;
  ushort* qkvT = wbase + 262144;
  ushort* swoT = wbase + 1048576;
  ushort* w1T  = wbase + 1310720;
  ushort* w2T  = wbase + 3407872;

  trig_prep<<<(RQ * 64) / 256, 256, 0, stream>>>(bin_time, csQ, RQ * 64);
  trig_prep<<<(RL * 64) / 256, 256, 0, stream>>>(lat_time, csL, RL * 64);

  for (int l = 0; l < 2; l++) {
    wtrans_all<<<4352, 256, 0, stream>>>(ca_wq, ca_wkv, ca_wo, sa_wqkv, sa_wo,
                                         ffn_w1, ffn_w2, wbase, l);

    // ---- cross attention ----
    const float* xin = (l == 0) ? bin_queries : x;
    ln_rows<<<RQ / 4, 256, 0, stream>>>(xin, ca_lnq_w + l * DIMc, ca_lnq_b + l * DIMc, ca_xn, RQ);
    ln_rows<<<RL / 4, 256, 0, stream>>>(latents, ca_lnc_w + l * DIMc, ca_lnc_b + l * DIMc, cn, RL);
    gemm64_rope<<<dim3(CIc / 64, RQ / 64), 256, 0, stream>>>(ca_xn, wqT, qbuf, csQ, RQ, CIc, DIMc);
    gemm128x64<3><<<dim3(2 * CIc / 64, RL / 128), 256, 0, stream>>>(cn, wkvT, nullptr,
        nullptr, nullptr, kv, RL, 2 * CIc, DIMc, csL, vt_c);
    attn_mfma<0><<<dim3(Tc / 64, CHc, Bc), 256, 0, stream>>>(qbuf, kv, vt_c, ca_att,
        CIc, 2 * CIc, 0, CIc, Tc, Nc, CHc);
    gemm128x64<1><<<dim3(DIMc / 64, RQ / 128), 256, 0, stream>>>(ca_att, woT, ca_bo + l * DIMc,
        xin, x, nullptr, RQ, DIMc, CIc, nullptr, nullptr);

    // ---- self attention (causal) ----
    ln_rows<<<RQ / 4, 256, 0, stream>>>(x, sa_ln_w + l * DIMc, sa_ln_b + l * DIMc, sa_xn, RQ);
    gemm128<3><<<dim3(3 * SIc / 128, RQ / 128), 256, 0, stream>>>(sa_xn, qkvT, nullptr,
        nullptr, nullptr, qkv, RQ, 3 * SIc, DIMc, csQ, vt_s);
    attn_mfma<1><<<dim3(Tc / 64, SHc, Bc), 256, 0, stream>>>(qkv, qkv, vt_s, sa_att,
        3 * SIc, 3 * SIc, SIc, SIc, Tc, Tc, SHc);
    gemm128x64<1><<<dim3(DIMc / 64, RQ / 128), 256, 0, stream>>>(sa_att, swoT, sa_bo + l * DIMc,
        x, x, nullptr, RQ, DIMc, SIc, nullptr, nullptr);

    // ---- FFN: w1 on the 8-wave counted-vmcnt 256x256 pipeline ----
    ln_rows<<<RQ / 4, 256, 0, stream>>>(x, ffn_ln_w + l * DIMc, ffn_ln_b + l * DIMc, hb, RQ);
    gemm256_gelu<<<dim3(2 * FFc / 256, RQ / 256), 512, 0, stream>>>(hb, w1T,
        ffn_b1 + (size_t)l * 2 * FFc, ag, RQ, 2 * FFc, DIMc);
    float* resOut = (l == 1) ? (float*)d_out : x;
    gemm128x64<1><<<dim3(DIMc / 64, RQ / 128), 256, 0, stream>>>(ag, w2T, ffn_b2 + l * DIMc,
        x, resOut, nullptr, RQ, DIMc, FFc, nullptr, nullptr);
  }
}